// Round 14
// baseline (282.139 us; speedup 1.0000x reference)
//
#include <hip/hip_runtime.h>
#include <hip/hip_bf16.h>
#include <math.h>

typedef unsigned int u32;

#define LRELU(a) ((a) > 0.f ? (a) : 0.2f * (a))

#define FIX_SCALE 67108864.0f          // 2^26 fixed-point for attr sums
#define FIX_INV   (1.0f / 67108864.0f)
#define CNT_SHIFT 40
#define SUM_MASK  0xFFFFFFFFFFULL

// round-to-nearest-even f32 -> bf16 bits
__device__ __forceinline__ u32 f2bf(float f) {
    u32 u = __float_as_uint(f);
    return (u + 0x7fffu + ((u >> 16) & 1u)) >> 16;
}
__device__ __forceinline__ float bfl(u32 w) { return __uint_as_float(w << 16); }
__device__ __forceinline__ float bfh(u32 w) { return __uint_as_float(w & 0xffff0000u); }

#define RED(x) _Pragma("unroll") for (int m_ = 32; m_ >= 1; m_ >>= 1) x += __shfl_xor(x, m_);
#define REDMAX(x) _Pragma("unroll") for (int m_ = 32; m_ >= 1; m_ >>= 1) x = fmaxf(x, __shfl_xor(x, m_));

// ---------------- CSR build (unchanged from R8; passed) ----------------

__global__ void hist_pos_kernel(const int* __restrict__ dst, const float* __restrict__ eattr,
                                unsigned long long* __restrict__ hist, int* __restrict__ pos, int E) {
    int e = blockIdx.x * blockDim.x + threadIdx.x;
    if (e < E) {
        int d = dst[e];
        unsigned long long v = (1ULL << CNT_SHIFT) |
                               (unsigned long long)(eattr[e] * FIX_SCALE + 0.5f);
        unsigned long long old = atomicAdd(&hist[d], v);
        pos[e] = (int)(old >> CNT_SHIFT);
    }
}

__global__ __launch_bounds__(256) void scan_phase1(const unsigned long long* __restrict__ hist,
                                                   int* __restrict__ block_sum, int N) {
    int t = threadIdx.x;
    int n = blockIdx.x * 256 + t;
    int v = (n < N) ? (int)(hist[n] >> CNT_SHIFT) + 1 : 0;  // +1 self loop
    RED(v)
    __shared__ int ws[4];
    if ((t & 63) == 0) ws[t >> 6] = v;
    __syncthreads();
    if (t == 0) block_sum[blockIdx.x] = ws[0] + ws[1] + ws[2] + ws[3];
}

__global__ __launch_bounds__(1024) void scan_phase2(const int* __restrict__ block_sum,
                                                    int* __restrict__ block_off,
                                                    int* __restrict__ row_ptr, int B, int N) {
    __shared__ int s[1024];
    int t = threadIdx.x;
    int v = (t < B) ? block_sum[t] : 0;
    s[t] = v;
    __syncthreads();
    for (int off = 1; off < 1024; off <<= 1) {
        int u = (t >= off) ? s[t - off] : 0;
        __syncthreads();
        s[t] += u;
        __syncthreads();
    }
    if (t < B) block_off[t] = s[t] - v;
    if (t == 1023) row_ptr[N] = s[1023];
}

__global__ __launch_bounds__(256) void scan_phase3(const unsigned long long* __restrict__ hist,
                                                   const int* __restrict__ block_off,
                                                   int* __restrict__ row_ptr,
                                                   int2* __restrict__ col, int N) {
    int t = threadIdx.x;
    int lane = t & 63;
    int n = blockIdx.x * 256 + t;
    unsigned long long hv = (n < N) ? hist[n] : 0ULL;
    int c = (n < N) ? (int)(hv >> CNT_SHIFT) + 1 : 0;
    int v = c;
#pragma unroll
    for (int m = 1; m < 64; m <<= 1) {
        int u = __shfl_up(v, m);
        if (lane >= m) v += u;
    }
    __shared__ int wsum[4];
    if (lane == 63) wsum[t >> 6] = v;
    __syncthreads();
    int w = t >> 6;
    int wadd = 0;
#pragma unroll
    for (int i = 0; i < 3; i++) wadd += (i < w) ? wsum[i] : 0;
    int base = block_off[blockIdx.x] + wadd + v - c;
    if (n < N) {
        row_ptr[n] = base;
        float asum = (float)(hv & SUM_MASK) * FIX_INV;
        float la = asum / fmaxf((float)(c - 1), 1.f);
        col[base] = make_int2(n, __float_as_int(la));   // self loop first in row
    }
}

__global__ void place_kernel(const int* __restrict__ src, const int* __restrict__ dst,
                             const float* __restrict__ eattr, const int* __restrict__ row_ptr,
                             const int* __restrict__ pos, int2* __restrict__ col, int E) {
    int e = blockIdx.x * blockDim.x + threadIdx.x;
    if (e < E) {
        int d = dst[e];
        col[row_ptr[d] + 1 + pos[e]] = make_int2(src[e], __float_as_int(eattr[e]));
    }
}

// ---------------- prep: we_dot scalars + folded attention vectors w_a = W^T a ----------------
// wp layout: [0..3] we_dot(layer,h); [4..13] w_as1[h][k]; [14..23] w_ad1;
//            [24..151] w_as2[h][k] (2x64); [152..279] w_ad2.

__global__ __launch_bounds__(256) void prep2_kernel(
        const float* __restrict__ W1, const float* __restrict__ as1, const float* __restrict__ ad1,
        const float* __restrict__ We1, const float* __restrict__ ae1,
        const float* __restrict__ W2, const float* __restrict__ as2, const float* __restrict__ ad2,
        const float* __restrict__ We2, const float* __restrict__ ae2,
        float* __restrict__ wp) {
    int t = threadIdx.x;
    int g = t >> 6, lane = t & 63;          // g = layer*2 + h
    const float* We = (g & 2) ? We2 : We1;
    const float* ae = (g & 2) ? ae2 : ae1;
    int h = g & 1;
    float v = We[h * 64 + lane] * ae[h * 64 + lane];
    RED(v)
    if (lane == 0) wp[g] = v;
    if (t < 20) {                            // layer-1 folded vectors (2 heads x 5)
        int dd = t / 10;
        int hh = (t % 10) / 5, k = t % 5;
        const float* a = dd ? ad1 : as1;
        float s = 0.f;
        for (int c = 0; c < 64; c++) s += W1[k * 128 + hh * 64 + c] * a[hh * 64 + c];
        wp[4 + dd * 10 + hh * 5 + k] = s;
    }
    {                                        // layer-2 folded vectors (2 heads x 64) x {s,d}
        int dd = t >> 7;
        int hh = (t >> 6) & 1, k = t & 63;
        const float* a = dd ? ad2 : as2;
        float s = 0.f;
        for (int c = 0; c < 64; c++) s += W2[k * 128 + hh * 64 + c] * a[hh * 64 + c];
        wp[24 + dd * 128 + hh * 64 + k] = s;
    }
}

// ---------------- layer-1 node pre-pass: logits + bf16-packed raw features ----------------

__global__ __launch_bounds__(256) void node_pre1(
        const float* __restrict__ x, const float* __restrict__ wp,
        float2* __restrict__ al_s, float2* __restrict__ al_d, uint4* __restrict__ xb1, int N) {
    int n = blockIdx.x * 256 + threadIdx.x;
    if (n >= N) return;
    float f[5];
#pragma unroll
    for (int k = 0; k < 5; k++) f[k] = x[(size_t)n * 5 + k];
    float s0 = 0.f, s1 = 0.f, d0 = 0.f, d1 = 0.f;
#pragma unroll
    for (int k = 0; k < 5; k++) {
        s0 += f[k] * wp[4 + k];   s1 += f[k] * wp[9 + k];
        d0 += f[k] * wp[14 + k];  d1 += f[k] * wp[19 + k];
    }
    al_s[n] = make_float2(s0, s1);
    al_d[n] = make_float2(d0, d1);
    uint4 p;
    p.x = (f2bf(f[1]) << 16) | f2bf(f[0]);
    p.y = (f2bf(f[3]) << 16) | f2bf(f[2]);
    p.z = f2bf(f[4]);
    p.w = 0;
    xb1[n] = p;
}

// ---------------- layer-1 edge aggregation: gather 16B raw-feature rows ----------------
// agg1[n][0..4] = sum_e att0*f_src, [5..9] = head1. Wave per dst, lane = edge.

__global__ __launch_bounds__(256) void edge_aggr_L1(
        const int* __restrict__ row_ptr, const int2* __restrict__ col,
        const float2* __restrict__ al_s, const float2* __restrict__ al_d,
        const uint4* __restrict__ xb1, const float* __restrict__ wp,
        float* __restrict__ agg1, int N) {
    int lane = threadIdx.x & 63;
    int n = blockIdx.x * 4 + (threadIdx.x >> 6);
    if (n >= N) return;
    int start = row_ptr[n], end = row_ptr[n + 1];
    int cnt = end - start;
    float we0 = wp[0], we1 = wp[1];
    float2 ald = al_d[n];
    float a00 = 0.f, a01 = 0.f, a02 = 0.f, a03 = 0.f, a04 = 0.f;
    float a10 = 0.f, a11 = 0.f, a12 = 0.f, a13 = 0.f, a14 = 0.f;
    float den0 = 0.f, den1 = 0.f;

    if (cnt <= 64) {
        float v0 = -INFINITY, v1 = -INFINITY;
        int sc = 0;
        if (lane < cnt) {
            int2 ce = col[start + lane];
            sc = ce.x;
            float at = __int_as_float(ce.y);
            float2 als = al_s[sc];
            v0 = LRELU(als.x + ald.x + we0 * at);
            v1 = LRELU(als.y + ald.y + we1 * at);
        }
        float m0 = v0, m1 = v1;
        REDMAX(m0) REDMAX(m1)
        if (lane < cnt) {
            float e0 = __expf(v0 - m0), e1 = __expf(v1 - m1);
            uint4 p = xb1[sc];
            float f0 = bfl(p.x), f1 = bfh(p.x), f2 = bfl(p.y), f3 = bfh(p.y), f4 = bfl(p.z);
            a00 = e0 * f0; a01 = e0 * f1; a02 = e0 * f2; a03 = e0 * f3; a04 = e0 * f4;
            a10 = e1 * f0; a11 = e1 * f1; a12 = e1 * f2; a13 = e1 * f3; a14 = e1 * f4;
            den0 = e0; den1 = e1;
        }
    } else {
        float m0 = -INFINITY, m1 = -INFINITY;
        for (int i = start + lane; i < end; i += 64) {
            int2 ce = col[i];
            float at = __int_as_float(ce.y);
            float2 als = al_s[ce.x];
            m0 = fmaxf(m0, LRELU(als.x + ald.x + we0 * at));
            m1 = fmaxf(m1, LRELU(als.y + ald.y + we1 * at));
        }
        REDMAX(m0) REDMAX(m1)
        for (int i = start + lane; i < end; i += 64) {
            int2 ce = col[i];
            float at = __int_as_float(ce.y);
            float2 als = al_s[ce.x];
            float e0 = __expf(LRELU(als.x + ald.x + we0 * at) - m0);
            float e1 = __expf(LRELU(als.y + ald.y + we1 * at) - m1);
            uint4 p = xb1[ce.x];
            float f0 = bfl(p.x), f1 = bfh(p.x), f2 = bfl(p.y), f3 = bfh(p.y), f4 = bfl(p.z);
            a00 += e0 * f0; a01 += e0 * f1; a02 += e0 * f2; a03 += e0 * f3; a04 += e0 * f4;
            a10 += e1 * f0; a11 += e1 * f1; a12 += e1 * f2; a13 += e1 * f3; a14 += e1 * f4;
            den0 += e0; den1 += e1;
        }
    }
    RED(a00) RED(a01) RED(a02) RED(a03) RED(a04)
    RED(a10) RED(a11) RED(a12) RED(a13) RED(a14)
    RED(den0) RED(den1)
    if (lane == 0) {
        float i0 = 1.f / (den0 + 1e-16f), i1 = 1.f / (den1 + 1e-16f);
        float* o = agg1 + (size_t)n * 10;
        o[0] = a00 * i0; o[1] = a01 * i0; o[2] = a02 * i0; o[3] = a03 * i0; o[4] = a04 * i0;
        o[5] = a10 * i1; o[6] = a11 * i1; o[7] = a12 * i1; o[8] = a13 * i1; o[9] = a14 * i1;
    }
}

// ---------------- layer-1 projection (post-aggregation) + layer-2 logits + packing ----------
// feat1[c] = relu(0.5*(agg0@W1[:,c] + agg1@W1[:,64+c]) + b1[c]); wave = node, lane = c.

__global__ __launch_bounds__(256) void proj1_kernel(
        const float* __restrict__ agg1, const float* __restrict__ W1, const float* __restrict__ b1,
        const float* __restrict__ wp,
        float2* __restrict__ al_s2, float2* __restrict__ al_d2, u32* __restrict__ xb2, int N) {
    int lane = threadIdx.x & 63;
    int n = blockIdx.x * 4 + (threadIdx.x >> 6);
    if (n >= N) return;
    const float* ag = agg1 + (size_t)n * 10;
    float s0 = 0.f, s1 = 0.f;
#pragma unroll
    for (int k = 0; k < 5; k++) {
        s0 += ag[k] * W1[k * 128 + lane];
        s1 += ag[5 + k] * W1[k * 128 + 64 + lane];
    }
    float h = fmaxf(0.5f * (s0 + s1) + b1[lane], 0.f);
    float r0 = h * wp[24 + lane], r1 = h * wp[88 + lane];
    float r2 = h * wp[152 + lane], r3 = h * wp[216 + lane];
    RED(r0) RED(r1) RED(r2) RED(r3)
    if (lane == 0) {
        al_s2[n] = make_float2(r0, r1);
        al_d2[n] = make_float2(r2, r3);
    }
    float hi = __shfl_down(h, 1);
    if (!(lane & 1)) xb2[(size_t)n * 32 + (lane >> 1)] = (f2bf(hi) << 16) | f2bf(h);
}

// ---------------- layer-2 edge aggregation: gather 128B bf16 feature rows ----------------
// Row = 32 u32 words (64 ch). lanes<32: head0 weights, lanes>=32: head1; both read same words.

__global__ __launch_bounds__(256) void edge_aggr_L2(
        const int* __restrict__ row_ptr, const int2* __restrict__ col,
        const float2* __restrict__ al_s, const float2* __restrict__ al_d,
        const u32* __restrict__ xb2, const float* __restrict__ wp,
        float* __restrict__ agg2, int N) {
    __shared__ float s_e0[4][64], s_e1[4][64];
    __shared__ int s_src[4][64];
    int wid = threadIdx.x >> 6;
    int lane = threadIdx.x & 63;
    int n = blockIdx.x * 4 + wid;
    if (n >= N) return;
    int start = row_ptr[n], end = row_ptr[n + 1];
    int cnt = end - start;
    float we0 = wp[2], we1 = wp[3];
    float2 ald = al_d[n];
    bool lo = lane < 32;
    int word = lane & 31;
    float accx = 0.f, accy = 0.f, den0 = 0.f, den1 = 0.f;

    if (cnt <= 64) {
        float v0 = -INFINITY, v1 = -INFINITY;
        int sc = 0;
        if (lane < cnt) {
            int2 ce = col[start + lane];
            sc = ce.x;
            float at = __int_as_float(ce.y);
            float2 als = al_s[sc];
            v0 = LRELU(als.x + ald.x + we0 * at);
            v1 = LRELU(als.y + ald.y + we1 * at);
        }
        float m0 = v0, m1 = v1;
        REDMAX(m0) REDMAX(m1)
        float e0 = 0.f, e1 = 0.f;
        if (lane < cnt) {
            e0 = __expf(v0 - m0);
            e1 = __expf(v1 - m1);
        }
        den0 = e0; den1 = e1;
        s_e0[wid][lane] = e0; s_e1[wid][lane] = e1; s_src[wid][lane] = sc;
        // no barrier: same-wave LDS write->read

        const float* s_w = lo ? s_e0[wid] : s_e1[wid];
#pragma unroll 4
        for (int j = 0; j < cnt; j++) {
            float w = s_w[j];
            u32 v = xb2[(size_t)s_src[wid][j] * 32 + word];
            accx += w * bfl(v);
            accy += w * bfh(v);
        }
    } else {
        float m0 = -INFINITY, m1 = -INFINITY;
        for (int i = start + lane; i < end; i += 64) {
            int2 ce = col[i];
            float at = __int_as_float(ce.y);
            float2 als = al_s[ce.x];
            m0 = fmaxf(m0, LRELU(als.x + ald.x + we0 * at));
            m1 = fmaxf(m1, LRELU(als.y + ald.y + we1 * at));
        }
        REDMAX(m0) REDMAX(m1)
        const float* s_w = lo ? s_e0[wid] : s_e1[wid];
        for (int cs = start; cs < end; cs += 64) {
            int i = cs + lane;
            float e0 = 0.f, e1 = 0.f;
            int sc = 0;
            if (i < end) {
                int2 ce = col[i];
                sc = ce.x;
                float at = __int_as_float(ce.y);
                float2 als = al_s[sc];
                e0 = __expf(LRELU(als.x + ald.x + we0 * at) - m0);
                e1 = __expf(LRELU(als.y + ald.y + we1 * at) - m1);
            }
            den0 += e0; den1 += e1;
            s_e0[wid][lane] = e0; s_e1[wid][lane] = e1; s_src[wid][lane] = sc;
            int c2 = min(64, end - cs);
#pragma unroll 4
            for (int j = 0; j < c2; j++) {
                float w = s_w[j];
                u32 v = xb2[(size_t)s_src[wid][j] * 32 + word];
                accx += w * bfl(v);
                accy += w * bfh(v);
            }
        }
    }
    RED(den0) RED(den1)
    float inv = lo ? 1.f / (den0 + 1e-16f) : 1.f / (den1 + 1e-16f);
    float2* o = (float2*)(agg2 + (size_t)n * 128 + (lo ? 0 : 64));
    o[word] = make_float2(accx * inv, accy * inv);
}

// ---------------- layer-2 projection + relu + pooling (fused) ----------------
// out[c] = relu(0.5*(agg0@W2[:,c] + agg1@W2[:,64+c]) + b2[c]); pooled dot with Wlin.

__global__ __launch_bounds__(256) void proj2_pool(
        const float* __restrict__ agg2, const float* __restrict__ W2, const float* __restrict__ b2,
        const float* __restrict__ Wlin, const int* __restrict__ batch,
        float* __restrict__ pool_sum, int* __restrict__ pool_cnt, int N) {
    __shared__ float s_sum[64];
    __shared__ int s_cnt[64];
    int t = threadIdx.x;
    if (t < 64) { s_sum[t] = 0.f; s_cnt[t] = 0; }
    __syncthreads();
    int wid = t >> 6, lane = t & 63;
    float wl = Wlin[lane];
    float bb = b2[lane];
    for (int n = blockIdx.x * 4 + wid; n < N; n += gridDim.x * 4) {
        const float* ag = agg2 + (size_t)n * 128;
        float s0 = 0.f, s1 = 0.f;
#pragma unroll 8
        for (int k = 0; k < 64; k++) {
            s0 += ag[k] * W2[k * 128 + lane];
            s1 += ag[64 + k] * W2[k * 128 + 64 + lane];
        }
        float v = fmaxf(0.5f * (s0 + s1) + bb, 0.f) * wl;
        RED(v)
        if (lane == 0) {
            int g = batch[n];
            atomicAdd(&s_sum[g], v);
            atomicAdd(&s_cnt[g], 1);
        }
    }
    __syncthreads();
    if (t < 64 && s_cnt[t] > 0) {
        atomicAdd(&pool_sum[t], s_sum[t]);
        atomicAdd(&pool_cnt[t], s_cnt[t]);
    }
}

__global__ void final_kernel(const float* __restrict__ pool_sum, const int* __restrict__ pool_cnt,
                             const float* __restrict__ blin, float* __restrict__ out) {
    int g = threadIdx.x;
    if (g < 64) out[g] = pool_sum[g] / fmaxf((float)pool_cnt[g], 1.f) + blin[0];
}

// ---------------- launch ----------------

extern "C" void kernel_launch(void* const* d_in, const int* in_sizes, int n_in,
                              void* d_out, int out_size, void* d_ws, size_t ws_size,
                              hipStream_t stream) {
    const float* x     = (const float*)d_in[0];
    const int*   ei    = (const int*)d_in[1];
    const float* eattr = (const float*)d_in[2];
    const int*   batch = (const int*)d_in[3];
    const float* W1  = (const float*)d_in[4];
    const float* as1 = (const float*)d_in[5];
    const float* ad1 = (const float*)d_in[6];
    const float* We1 = (const float*)d_in[7];
    const float* ae1 = (const float*)d_in[8];
    const float* b1  = (const float*)d_in[9];
    const float* W2  = (const float*)d_in[10];
    const float* as2 = (const float*)d_in[11];
    const float* ad2 = (const float*)d_in[12];
    const float* We2 = (const float*)d_in[13];
    const float* ae2 = (const float*)d_in[14];
    const float* b2  = (const float*)d_in[15];
    const float* Wlin = (const float*)d_in[16];
    const float* blin = (const float*)d_in[17];
    float* out = (float*)d_out;

    int N = in_sizes[0] / 5;
    int E = in_sizes[1] / 2;
    size_t EP = (size_t)E + N;
    const int* src0 = ei;
    const int* dst0 = ei + E;
    int B = (N + 255) / 256;

    char* ws = (char*)d_ws;
    size_t off = 0;
    auto alloc = [&](size_t bytes) {
        void* p = ws + off;
        off = (off + bytes + 255) & ~(size_t)255;
        return p;
    };
    unsigned long long* hist = (unsigned long long*)alloc((size_t)N * 8);
    int*    row_ptr  = (int*)   alloc((size_t)(N + 1) * 4);
    int*    pos      = (int*)   alloc((size_t)E * 4);
    int2*   col      = (int2*)  alloc(EP * 8);
    int*    block_sum= (int*)   alloc((size_t)1024 * 4);
    int*    block_off= (int*)   alloc((size_t)1024 * 4);
    float*  wp       = (float*) alloc(280 * 4);
    float2* al_s1    = (float2*)alloc((size_t)N * 8);
    float2* al_d1    = (float2*)alloc((size_t)N * 8);
    uint4*  xb1      = (uint4*) alloc((size_t)N * 16);
    float*  agg1     = (float*) alloc((size_t)N * 10 * 4);
    float2* al_s2    = (float2*)alloc((size_t)N * 8);
    float2* al_d2    = (float2*)alloc((size_t)N * 8);
    u32*    xb2      = (u32*)   alloc((size_t)N * 32 * 4);
    float*  agg2     = (float*) alloc((size_t)N * 128 * 4);
    float*  pool_sum = (float*) alloc(64 * 4);
    int*    pool_cnt = (int*)   alloc(64 * 4);

    hipMemsetAsync(hist, 0, (size_t)N * 8, stream);
    hipMemsetAsync(block_sum, 0, (size_t)1024 * 4, stream);
    hipMemsetAsync(pool_sum, 0, 64 * 4, stream);
    hipMemsetAsync(pool_cnt, 0, 64 * 4, stream);

    hist_pos_kernel<<<(E + 255) / 256, 256, 0, stream>>>(dst0, eattr, hist, pos, E);
    scan_phase1<<<B, 256, 0, stream>>>(hist, block_sum, N);
    scan_phase2<<<1, 1024, 0, stream>>>(block_sum, block_off, row_ptr, B, N);
    scan_phase3<<<B, 256, 0, stream>>>(hist, block_off, row_ptr, col, N);
    place_kernel<<<(E + 255) / 256, 256, 0, stream>>>(src0, dst0, eattr, row_ptr, pos, col, E);
    prep2_kernel<<<1, 256, 0, stream>>>(W1, as1, ad1, We1, ae1, W2, as2, ad2, We2, ae2, wp);

    int eab = (N + 3) / 4;                  // 4 waves per block, wave per node

    // layer 1: aggregate raw 5-dim features, then project
    node_pre1<<<B, 256, 0, stream>>>(x, wp, al_s1, al_d1, xb1, N);
    edge_aggr_L1<<<eab, 256, 0, stream>>>(row_ptr, col, al_s1, al_d1, xb1, wp, agg1, N);
    proj1_kernel<<<eab, 256, 0, stream>>>(agg1, W1, b1, wp, al_s2, al_d2, xb2, N);
    // layer 2: aggregate 64-dim feat1, then project + pool (fused)
    edge_aggr_L2<<<eab, 256, 0, stream>>>(row_ptr, col, al_s2, al_d2, xb2, wp, agg2, N);
    proj2_pool<<<512, 256, 0, stream>>>(agg2, W2, b2, Wlin, batch, pool_sum, pool_cnt, N);
    final_kernel<<<1, 64, 0, stream>>>(pool_sum, pool_cnt, blin, out);
}

// Round 15
// 251.149 us; speedup vs baseline: 1.1234x; 1.1234x over previous
//
#include <hip/hip_runtime.h>
#include <hip/hip_bf16.h>
#include <math.h>

typedef unsigned int u32;

#define LRELU(a) ((a) > 0.f ? (a) : 0.2f * (a))

#define FIX_SCALE 67108864.0f          // 2^26 fixed-point for attr sums
#define FIX_INV   (1.0f / 67108864.0f)
#define CNT_SHIFT 40
#define SUM_MASK  0xFFFFFFFFFFULL

// round-to-nearest-even f32 -> bf16 bits
__device__ __forceinline__ u32 f2bf(float f) {
    u32 u = __float_as_uint(f);
    return (u + 0x7fffu + ((u >> 16) & 1u)) >> 16;
}
__device__ __forceinline__ float bfl(u32 w) { return __uint_as_float(w << 16); }
__device__ __forceinline__ float bfh(u32 w) { return __uint_as_float(w & 0xffff0000u); }

#define RED(x) _Pragma("unroll") for (int m_ = 32; m_ >= 1; m_ >>= 1) x += __shfl_xor(x, m_);
#define REDMAX(x) _Pragma("unroll") for (int m_ = 32; m_ >= 1; m_ >>= 1) x = fmaxf(x, __shfl_xor(x, m_));

// ---------------- CSR build (unchanged; passed) ----------------

__global__ void hist_pos_kernel(const int* __restrict__ dst, const float* __restrict__ eattr,
                                unsigned long long* __restrict__ hist, int* __restrict__ pos, int E) {
    int e = blockIdx.x * blockDim.x + threadIdx.x;
    if (e < E) {
        int d = dst[e];
        unsigned long long v = (1ULL << CNT_SHIFT) |
                               (unsigned long long)(eattr[e] * FIX_SCALE + 0.5f);
        unsigned long long old = atomicAdd(&hist[d], v);
        pos[e] = (int)(old >> CNT_SHIFT);
    }
}

__global__ __launch_bounds__(256) void scan_phase1(const unsigned long long* __restrict__ hist,
                                                   int* __restrict__ block_sum, int N) {
    int t = threadIdx.x;
    int n = blockIdx.x * 256 + t;
    int v = (n < N) ? (int)(hist[n] >> CNT_SHIFT) + 1 : 0;  // +1 self loop
    RED(v)
    __shared__ int ws[4];
    if ((t & 63) == 0) ws[t >> 6] = v;
    __syncthreads();
    if (t == 0) block_sum[blockIdx.x] = ws[0] + ws[1] + ws[2] + ws[3];
}

__global__ __launch_bounds__(1024) void scan_phase2(const int* __restrict__ block_sum,
                                                    int* __restrict__ block_off,
                                                    int* __restrict__ row_ptr, int B, int N) {
    __shared__ int s[1024];
    int t = threadIdx.x;
    int v = (t < B) ? block_sum[t] : 0;
    s[t] = v;
    __syncthreads();
    for (int off = 1; off < 1024; off <<= 1) {
        int u = (t >= off) ? s[t - off] : 0;
        __syncthreads();
        s[t] += u;
        __syncthreads();
    }
    if (t < B) block_off[t] = s[t] - v;
    if (t == 1023) row_ptr[N] = s[1023];
}

__global__ __launch_bounds__(256) void scan_phase3(const unsigned long long* __restrict__ hist,
                                                   const int* __restrict__ block_off,
                                                   int* __restrict__ row_ptr,
                                                   int2* __restrict__ col, int N) {
    int t = threadIdx.x;
    int lane = t & 63;
    int n = blockIdx.x * 256 + t;
    unsigned long long hv = (n < N) ? hist[n] : 0ULL;
    int c = (n < N) ? (int)(hv >> CNT_SHIFT) + 1 : 0;
    int v = c;
#pragma unroll
    for (int m = 1; m < 64; m <<= 1) {
        int u = __shfl_up(v, m);
        if (lane >= m) v += u;
    }
    __shared__ int wsum[4];
    if (lane == 63) wsum[t >> 6] = v;
    __syncthreads();
    int w = t >> 6;
    int wadd = 0;
#pragma unroll
    for (int i = 0; i < 3; i++) wadd += (i < w) ? wsum[i] : 0;
    int base = block_off[blockIdx.x] + wadd + v - c;
    if (n < N) {
        row_ptr[n] = base;
        float asum = (float)(hv & SUM_MASK) * FIX_INV;
        float la = asum / fmaxf((float)(c - 1), 1.f);
        col[base] = make_int2(n, __float_as_int(la));   // self loop first in row
    }
}

__global__ void place_kernel(const int* __restrict__ src, const int* __restrict__ dst,
                             const float* __restrict__ eattr, const int* __restrict__ row_ptr,
                             const int* __restrict__ pos, int2* __restrict__ col, int E) {
    int e = blockIdx.x * blockDim.x + threadIdx.x;
    if (e < E) {
        int d = dst[e];
        col[row_ptr[d] + 1 + pos[e]] = make_int2(src[e], __float_as_int(eattr[e]));
    }
}

// ---------------- prep: we_dot scalars + folded attention vectors w_a = W^T a ----------------
// wp layout: [0..3] we_dot(layer,h); [4..13] w_as1[h][k]; [14..23] w_ad1;
//            [24..151] w_as2[h][k] (2x64); [152..279] w_ad2.

__global__ __launch_bounds__(256) void prep2_kernel(
        const float* __restrict__ W1, const float* __restrict__ as1, const float* __restrict__ ad1,
        const float* __restrict__ We1, const float* __restrict__ ae1,
        const float* __restrict__ W2, const float* __restrict__ as2, const float* __restrict__ ad2,
        const float* __restrict__ We2, const float* __restrict__ ae2,
        float* __restrict__ wp) {
    int t = threadIdx.x;
    int g = t >> 6, lane = t & 63;          // g = layer*2 + h
    const float* We = (g & 2) ? We2 : We1;
    const float* ae = (g & 2) ? ae2 : ae1;
    int h = g & 1;
    float v = We[h * 64 + lane] * ae[h * 64 + lane];
    RED(v)
    if (lane == 0) wp[g] = v;
    if (t < 20) {                            // layer-1 folded vectors (2 heads x 5)
        int dd = t / 10;
        int hh = (t % 10) / 5, k = t % 5;
        const float* a = dd ? ad1 : as1;
        float s = 0.f;
        for (int c = 0; c < 64; c++) s += W1[k * 128 + hh * 64 + c] * a[hh * 64 + c];
        wp[4 + dd * 10 + hh * 5 + k] = s;
    }
    {                                        // layer-2 folded vectors (2 heads x 64) x {s,d}
        int dd = t >> 7;
        int hh = (t >> 6) & 1, k = t & 63;
        const float* a = dd ? ad2 : as2;
        float s = 0.f;
        for (int c = 0; c < 64; c++) s += W2[k * 128 + hh * 64 + c] * a[hh * 64 + c];
        wp[24 + dd * 128 + hh * 64 + k] = s;
    }
}

// ---------------- layer-1 node pre-pass: logits + bf16-packed raw features ----------------

__global__ __launch_bounds__(256) void node_pre1(
        const float* __restrict__ x, const float* __restrict__ wp,
        float2* __restrict__ al_s, float2* __restrict__ al_d, uint4* __restrict__ xb1, int N) {
    int n = blockIdx.x * 256 + threadIdx.x;
    if (n >= N) return;
    float f[5];
#pragma unroll
    for (int k = 0; k < 5; k++) f[k] = x[(size_t)n * 5 + k];
    float s0 = 0.f, s1 = 0.f, d0 = 0.f, d1 = 0.f;
#pragma unroll
    for (int k = 0; k < 5; k++) {
        s0 += f[k] * wp[4 + k];   s1 += f[k] * wp[9 + k];
        d0 += f[k] * wp[14 + k];  d1 += f[k] * wp[19 + k];
    }
    al_s[n] = make_float2(s0, s1);
    al_d[n] = make_float2(d0, d1);
    uint4 p;
    p.x = (f2bf(f[1]) << 16) | f2bf(f[0]);
    p.y = (f2bf(f[3]) << 16) | f2bf(f[2]);
    p.z = f2bf(f[4]);
    p.w = 0;
    xb1[n] = p;
}

// ---------------- layer-1 edge aggregation: gather 16B raw-feature rows ----------------

__global__ __launch_bounds__(256) void edge_aggr_L1(
        const int* __restrict__ row_ptr, const int2* __restrict__ col,
        const float2* __restrict__ al_s, const float2* __restrict__ al_d,
        const uint4* __restrict__ xb1, const float* __restrict__ wp,
        float* __restrict__ agg1, int N) {
    int lane = threadIdx.x & 63;
    int n = blockIdx.x * 4 + (threadIdx.x >> 6);
    if (n >= N) return;
    int start = row_ptr[n], end = row_ptr[n + 1];
    int cnt = end - start;
    float we0 = wp[0], we1 = wp[1];
    float2 ald = al_d[n];
    float a00 = 0.f, a01 = 0.f, a02 = 0.f, a03 = 0.f, a04 = 0.f;
    float a10 = 0.f, a11 = 0.f, a12 = 0.f, a13 = 0.f, a14 = 0.f;
    float den0 = 0.f, den1 = 0.f;

    if (cnt <= 64) {
        float v0 = -INFINITY, v1 = -INFINITY;
        int sc = 0;
        if (lane < cnt) {
            int2 ce = col[start + lane];
            sc = ce.x;
            float at = __int_as_float(ce.y);
            float2 als = al_s[sc];
            v0 = LRELU(als.x + ald.x + we0 * at);
            v1 = LRELU(als.y + ald.y + we1 * at);
        }
        float m0 = v0, m1 = v1;
        REDMAX(m0) REDMAX(m1)
        if (lane < cnt) {
            float e0 = __expf(v0 - m0), e1 = __expf(v1 - m1);
            uint4 p = xb1[sc];
            float f0 = bfl(p.x), f1 = bfh(p.x), f2 = bfl(p.y), f3 = bfh(p.y), f4 = bfl(p.z);
            a00 = e0 * f0; a01 = e0 * f1; a02 = e0 * f2; a03 = e0 * f3; a04 = e0 * f4;
            a10 = e1 * f0; a11 = e1 * f1; a12 = e1 * f2; a13 = e1 * f3; a14 = e1 * f4;
            den0 = e0; den1 = e1;
        }
    } else {
        float m0 = -INFINITY, m1 = -INFINITY;
        for (int i = start + lane; i < end; i += 64) {
            int2 ce = col[i];
            float at = __int_as_float(ce.y);
            float2 als = al_s[ce.x];
            m0 = fmaxf(m0, LRELU(als.x + ald.x + we0 * at));
            m1 = fmaxf(m1, LRELU(als.y + ald.y + we1 * at));
        }
        REDMAX(m0) REDMAX(m1)
        for (int i = start + lane; i < end; i += 64) {
            int2 ce = col[i];
            float at = __int_as_float(ce.y);
            float2 als = al_s[ce.x];
            float e0 = __expf(LRELU(als.x + ald.x + we0 * at) - m0);
            float e1 = __expf(LRELU(als.y + ald.y + we1 * at) - m1);
            uint4 p = xb1[ce.x];
            float f0 = bfl(p.x), f1 = bfh(p.x), f2 = bfl(p.y), f3 = bfh(p.y), f4 = bfl(p.z);
            a00 += e0 * f0; a01 += e0 * f1; a02 += e0 * f2; a03 += e0 * f3; a04 += e0 * f4;
            a10 += e1 * f0; a11 += e1 * f1; a12 += e1 * f2; a13 += e1 * f3; a14 += e1 * f4;
            den0 += e0; den1 += e1;
        }
    }
    RED(a00) RED(a01) RED(a02) RED(a03) RED(a04)
    RED(a10) RED(a11) RED(a12) RED(a13) RED(a14)
    RED(den0) RED(den1)
    if (lane == 0) {
        float i0 = 1.f / (den0 + 1e-16f), i1 = 1.f / (den1 + 1e-16f);
        float* o = agg1 + (size_t)n * 10;
        o[0] = a00 * i0; o[1] = a01 * i0; o[2] = a02 * i0; o[3] = a03 * i0; o[4] = a04 * i0;
        o[5] = a10 * i1; o[6] = a11 * i1; o[7] = a12 * i1; o[8] = a13 * i1; o[9] = a14 * i1;
    }
}

// ---------------- layer-1 projection (post-aggregation) + layer-2 logits + packing ----------

__global__ __launch_bounds__(256) void proj1_kernel(
        const float* __restrict__ agg1, const float* __restrict__ W1, const float* __restrict__ b1,
        const float* __restrict__ wp,
        float2* __restrict__ al_s2, float2* __restrict__ al_d2, u32* __restrict__ xb2, int N) {
    int lane = threadIdx.x & 63;
    int n = blockIdx.x * 4 + (threadIdx.x >> 6);
    if (n >= N) return;
    const float* ag = agg1 + (size_t)n * 10;
    float s0 = 0.f, s1 = 0.f;
#pragma unroll
    for (int k = 0; k < 5; k++) {
        s0 += ag[k] * W1[k * 128 + lane];
        s1 += ag[5 + k] * W1[k * 128 + 64 + lane];
    }
    float h = fmaxf(0.5f * (s0 + s1) + b1[lane], 0.f);
    float r0 = h * wp[24 + lane], r1 = h * wp[88 + lane];
    float r2 = h * wp[152 + lane], r3 = h * wp[216 + lane];
    RED(r0) RED(r1) RED(r2) RED(r3)
    if (lane == 0) {
        al_s2[n] = make_float2(r0, r1);
        al_d2[n] = make_float2(r2, r3);
    }
    float hi = __shfl_down(h, 1);
    if (!(lane & 1)) xb2[(size_t)n * 32 + (lane >> 1)] = (f2bf(hi) << 16) | f2bf(h);
}

// ---------------- layer-2 edge aggregation: gather 128B bf16 feature rows ----------------

__global__ __launch_bounds__(256) void edge_aggr_L2(
        const int* __restrict__ row_ptr, const int2* __restrict__ col,
        const float2* __restrict__ al_s, const float2* __restrict__ al_d,
        const u32* __restrict__ xb2, const float* __restrict__ wp,
        float* __restrict__ agg2, int N) {
    __shared__ float s_e0[4][64], s_e1[4][64];
    __shared__ int s_src[4][64];
    int wid = threadIdx.x >> 6;
    int lane = threadIdx.x & 63;
    int n = blockIdx.x * 4 + wid;
    if (n >= N) return;
    int start = row_ptr[n], end = row_ptr[n + 1];
    int cnt = end - start;
    float we0 = wp[2], we1 = wp[3];
    float2 ald = al_d[n];
    bool lo = lane < 32;
    int word = lane & 31;
    float accx = 0.f, accy = 0.f, den0 = 0.f, den1 = 0.f;

    if (cnt <= 64) {
        float v0 = -INFINITY, v1 = -INFINITY;
        int sc = 0;
        if (lane < cnt) {
            int2 ce = col[start + lane];
            sc = ce.x;
            float at = __int_as_float(ce.y);
            float2 als = al_s[sc];
            v0 = LRELU(als.x + ald.x + we0 * at);
            v1 = LRELU(als.y + ald.y + we1 * at);
        }
        float m0 = v0, m1 = v1;
        REDMAX(m0) REDMAX(m1)
        float e0 = 0.f, e1 = 0.f;
        if (lane < cnt) {
            e0 = __expf(v0 - m0);
            e1 = __expf(v1 - m1);
        }
        den0 = e0; den1 = e1;
        s_e0[wid][lane] = e0; s_e1[wid][lane] = e1; s_src[wid][lane] = sc;
        // no barrier: same-wave LDS write->read

        const float* s_w = lo ? s_e0[wid] : s_e1[wid];
#pragma unroll 4
        for (int j = 0; j < cnt; j++) {
            float w = s_w[j];
            u32 v = xb2[(size_t)s_src[wid][j] * 32 + word];
            accx += w * bfl(v);
            accy += w * bfh(v);
        }
    } else {
        float m0 = -INFINITY, m1 = -INFINITY;
        for (int i = start + lane; i < end; i += 64) {
            int2 ce = col[i];
            float at = __int_as_float(ce.y);
            float2 als = al_s[ce.x];
            m0 = fmaxf(m0, LRELU(als.x + ald.x + we0 * at));
            m1 = fmaxf(m1, LRELU(als.y + ald.y + we1 * at));
        }
        REDMAX(m0) REDMAX(m1)
        const float* s_w = lo ? s_e0[wid] : s_e1[wid];
        for (int cs = start; cs < end; cs += 64) {
            int i = cs + lane;
            float e0 = 0.f, e1 = 0.f;
            int sc = 0;
            if (i < end) {
                int2 ce = col[i];
                sc = ce.x;
                float at = __int_as_float(ce.y);
                float2 als = al_s[sc];
                e0 = __expf(LRELU(als.x + ald.x + we0 * at) - m0);
                e1 = __expf(LRELU(als.y + ald.y + we1 * at) - m1);
            }
            den0 += e0; den1 += e1;
            s_e0[wid][lane] = e0; s_e1[wid][lane] = e1; s_src[wid][lane] = sc;
            int c2 = min(64, end - cs);
#pragma unroll 4
            for (int j = 0; j < c2; j++) {
                float w = s_w[j];
                u32 v = xb2[(size_t)s_src[wid][j] * 32 + word];
                accx += w * bfl(v);
                accy += w * bfh(v);
            }
        }
    }
    RED(den0) RED(den1)
    float inv = lo ? 1.f / (den0 + 1e-16f) : 1.f / (den1 + 1e-16f);
    float2* o = (float2*)(agg2 + (size_t)n * 128 + (lo ? 0 : 64));
    o[word] = make_float2(accx * inv, accy * inv);
}

// ---------------- layer-2 projection + relu + pooling (fused, LDS-staged W2) ----------------
// W2 staged once per block in LDS (sw[k][c]: k=0..63 head0, 64..127 head1; stride-1 lane reads
// = conflict-free). agg2 row staged per-wave, read back as uniform float4 broadcasts.
// One node per wave; 8 waves/block; LDS ~36.5KB -> 4 blocks/CU.

__global__ __launch_bounds__(512) void proj2_pool2(
        const float* __restrict__ agg2, const float* __restrict__ W2, const float* __restrict__ b2,
        const float* __restrict__ Wlin, const int* __restrict__ batch,
        float* __restrict__ pool_sum, int* __restrict__ pool_cnt, int N) {
    __shared__ float sw[128][64];       // sw[k][c] = W2[(k&63)*128 + (k>>6)*64 + c]
    __shared__ float4 sag4[8][32];      // per-wave agg2 row (128 floats, 16B aligned)
    __shared__ float s_sum[64];
    __shared__ int s_cnt[64];
    int t = threadIdx.x;
    int wid = t >> 6, lane = t & 63;
    if (t < 64) { s_sum[t] = 0.f; s_cnt[t] = 0; }
    for (int i = t; i < 128 * 64; i += 512) {
        int k = i >> 6, c = i & 63;
        sw[k][c] = W2[(k & 63) * 128 + (k >> 6) * 64 + c];
    }
    __syncthreads();

    int n = blockIdx.x * 8 + wid;
    if (n < N) {
        const float* ag = agg2 + (size_t)n * 128;
        float* sagf = (float*)sag4[wid];
        sagf[lane] = ag[lane];          // coalesced global read, LDS write
        sagf[64 + lane] = ag[64 + lane];
        // no barrier: same-wave LDS write->read
        float s0 = 0.f, s1 = 0.f;
#pragma unroll
        for (int k4 = 0; k4 < 64; k4 += 4) {
            float4 a0 = sag4[wid][k4 >> 2];        // uniform broadcast
            float4 a1 = sag4[wid][16 + (k4 >> 2)];
            s0 += a0.x * sw[k4][lane]     + a0.y * sw[k4+1][lane]
                + a0.z * sw[k4+2][lane]   + a0.w * sw[k4+3][lane];
            s1 += a1.x * sw[64+k4][lane]  + a1.y * sw[64+k4+1][lane]
                + a1.z * sw[64+k4+2][lane]+ a1.w * sw[64+k4+3][lane];
        }
        float v = fmaxf(0.5f * (s0 + s1) + b2[lane], 0.f) * Wlin[lane];
        RED(v)
        if (lane == 0) {
            int g = batch[n];
            atomicAdd(&s_sum[g], v);
            atomicAdd(&s_cnt[g], 1);
        }
    }
    __syncthreads();
    if (t < 64 && s_cnt[t] > 0) {
        atomicAdd(&pool_sum[t], s_sum[t]);
        atomicAdd(&pool_cnt[t], s_cnt[t]);
    }
}

__global__ void final_kernel(const float* __restrict__ pool_sum, const int* __restrict__ pool_cnt,
                             const float* __restrict__ blin, float* __restrict__ out) {
    int g = threadIdx.x;
    if (g < 64) out[g] = pool_sum[g] / fmaxf((float)pool_cnt[g], 1.f) + blin[0];
}

// ---------------- launch ----------------

extern "C" void kernel_launch(void* const* d_in, const int* in_sizes, int n_in,
                              void* d_out, int out_size, void* d_ws, size_t ws_size,
                              hipStream_t stream) {
    const float* x     = (const float*)d_in[0];
    const int*   ei    = (const int*)d_in[1];
    const float* eattr = (const float*)d_in[2];
    const int*   batch = (const int*)d_in[3];
    const float* W1  = (const float*)d_in[4];
    const float* as1 = (const float*)d_in[5];
    const float* ad1 = (const float*)d_in[6];
    const float* We1 = (const float*)d_in[7];
    const float* ae1 = (const float*)d_in[8];
    const float* b1  = (const float*)d_in[9];
    const float* W2  = (const float*)d_in[10];
    const float* as2 = (const float*)d_in[11];
    const float* ad2 = (const float*)d_in[12];
    const float* We2 = (const float*)d_in[13];
    const float* ae2 = (const float*)d_in[14];
    const float* b2  = (const float*)d_in[15];
    const float* Wlin = (const float*)d_in[16];
    const float* blin = (const float*)d_in[17];
    float* out = (float*)d_out;

    int N = in_sizes[0] / 5;
    int E = in_sizes[1] / 2;
    size_t EP = (size_t)E + N;
    const int* src0 = ei;
    const int* dst0 = ei + E;
    int B = (N + 255) / 256;

    char* ws = (char*)d_ws;
    size_t off = 0;
    auto alloc = [&](size_t bytes) {
        void* p = ws + off;
        off = (off + bytes + 255) & ~(size_t)255;
        return p;
    };
    unsigned long long* hist = (unsigned long long*)alloc((size_t)N * 8);
    int*    row_ptr  = (int*)   alloc((size_t)(N + 1) * 4);
    int*    pos      = (int*)   alloc((size_t)E * 4);
    int2*   col      = (int2*)  alloc(EP * 8);
    int*    block_sum= (int*)   alloc((size_t)1024 * 4);
    int*    block_off= (int*)   alloc((size_t)1024 * 4);
    float*  wp       = (float*) alloc(280 * 4);
    float2* al_s1    = (float2*)alloc((size_t)N * 8);
    float2* al_d1    = (float2*)alloc((size_t)N * 8);
    uint4*  xb1      = (uint4*) alloc((size_t)N * 16);
    float*  agg1     = (float*) alloc((size_t)N * 10 * 4);
    float2* al_s2    = (float2*)alloc((size_t)N * 8);
    float2* al_d2    = (float2*)alloc((size_t)N * 8);
    u32*    xb2      = (u32*)   alloc((size_t)N * 32 * 4);
    float*  agg2     = (float*) alloc((size_t)N * 128 * 4);
    float*  pool_sum = (float*) alloc(64 * 4);
    int*    pool_cnt = (int*)   alloc(64 * 4);

    hipMemsetAsync(hist, 0, (size_t)N * 8, stream);
    hipMemsetAsync(block_sum, 0, (size_t)1024 * 4, stream);
    hipMemsetAsync(pool_sum, 0, 64 * 4, stream);
    hipMemsetAsync(pool_cnt, 0, 64 * 4, stream);

    hist_pos_kernel<<<(E + 255) / 256, 256, 0, stream>>>(dst0, eattr, hist, pos, E);
    scan_phase1<<<B, 256, 0, stream>>>(hist, block_sum, N);
    scan_phase2<<<1, 1024, 0, stream>>>(block_sum, block_off, row_ptr, B, N);
    scan_phase3<<<B, 256, 0, stream>>>(hist, block_off, row_ptr, col, N);
    place_kernel<<<(E + 255) / 256, 256, 0, stream>>>(src0, dst0, eattr, row_ptr, pos, col, E);
    prep2_kernel<<<1, 256, 0, stream>>>(W1, as1, ad1, We1, ae1, W2, as2, ad2, We2, ae2, wp);

    int eab = (N + 3) / 4;                  // 4 waves per block, wave per node

    // layer 1: aggregate raw 5-dim features, then project
    node_pre1<<<B, 256, 0, stream>>>(x, wp, al_s1, al_d1, xb1, N);
    edge_aggr_L1<<<eab, 256, 0, stream>>>(row_ptr, col, al_s1, al_d1, xb1, wp, agg1, N);
    proj1_kernel<<<eab, 256, 0, stream>>>(agg1, W1, b1, wp, al_s2, al_d2, xb2, N);
    // layer 2: aggregate 64-dim feat1, then project + pool (fused, LDS-staged W2)
    edge_aggr_L2<<<eab, 256, 0, stream>>>(row_ptr, col, al_s2, al_d2, xb2, wp, agg2, N);
    proj2_pool2<<<(N + 7) / 8, 512, 0, stream>>>(agg2, W2, b2, Wlin, batch, pool_sum, pool_cnt, N);
    final_kernel<<<1, 64, 0, stream>>>(pool_sum, pool_cnt, blin, out);
}

// Round 16
// 228.468 us; speedup vs baseline: 1.2349x; 1.0993x over previous
//
#include <hip/hip_runtime.h>
#include <hip/hip_bf16.h>
#include <math.h>

typedef unsigned int u32;

#define LRELU(a) ((a) > 0.f ? (a) : 0.2f * (a))

#define FIX_SCALE 67108864.0f          // 2^26 fixed-point for attr sums
#define FIX_INV   (1.0f / 67108864.0f)
#define CNT_SHIFT 40
#define SUM_MASK  0xFFFFFFFFFFULL

// round-to-nearest-even f32 -> bf16 bits
__device__ __forceinline__ u32 f2bf(float f) {
    u32 u = __float_as_uint(f);
    return (u + 0x7fffu + ((u >> 16) & 1u)) >> 16;
}
__device__ __forceinline__ float bfl(u32 w) { return __uint_as_float(w << 16); }
__device__ __forceinline__ float bfh(u32 w) { return __uint_as_float(w & 0xffff0000u); }

#define RED(x) _Pragma("unroll") for (int m_ = 32; m_ >= 1; m_ >>= 1) x += __shfl_xor(x, m_);
#define REDMAX(x) _Pragma("unroll") for (int m_ = 32; m_ >= 1; m_ >>= 1) x = fmaxf(x, __shfl_xor(x, m_));

// ---------------- CSR build (unchanged; passed) ----------------

__global__ void hist_pos_kernel(const int* __restrict__ dst, const float* __restrict__ eattr,
                                unsigned long long* __restrict__ hist, int* __restrict__ pos, int E) {
    int e = blockIdx.x * blockDim.x + threadIdx.x;
    if (e < E) {
        int d = dst[e];
        unsigned long long v = (1ULL << CNT_SHIFT) |
                               (unsigned long long)(eattr[e] * FIX_SCALE + 0.5f);
        unsigned long long old = atomicAdd(&hist[d], v);
        pos[e] = (int)(old >> CNT_SHIFT);
    }
}

__global__ __launch_bounds__(256) void scan_phase1(const unsigned long long* __restrict__ hist,
                                                   int* __restrict__ block_sum, int N) {
    int t = threadIdx.x;
    int n = blockIdx.x * 256 + t;
    int v = (n < N) ? (int)(hist[n] >> CNT_SHIFT) + 1 : 0;  // +1 self loop
    RED(v)
    __shared__ int ws[4];
    if ((t & 63) == 0) ws[t >> 6] = v;
    __syncthreads();
    if (t == 0) block_sum[blockIdx.x] = ws[0] + ws[1] + ws[2] + ws[3];
}

__global__ __launch_bounds__(1024) void scan_phase2(const int* __restrict__ block_sum,
                                                    int* __restrict__ block_off,
                                                    int* __restrict__ row_ptr, int B, int N) {
    __shared__ int s[1024];
    int t = threadIdx.x;
    int v = (t < B) ? block_sum[t] : 0;
    s[t] = v;
    __syncthreads();
    for (int off = 1; off < 1024; off <<= 1) {
        int u = (t >= off) ? s[t - off] : 0;
        __syncthreads();
        s[t] += u;
        __syncthreads();
    }
    if (t < B) block_off[t] = s[t] - v;
    if (t == 1023) row_ptr[N] = s[1023];
}

__global__ __launch_bounds__(256) void scan_phase3(const unsigned long long* __restrict__ hist,
                                                   const int* __restrict__ block_off,
                                                   int* __restrict__ row_ptr,
                                                   int2* __restrict__ col, int N) {
    int t = threadIdx.x;
    int lane = t & 63;
    int n = blockIdx.x * 256 + t;
    unsigned long long hv = (n < N) ? hist[n] : 0ULL;
    int c = (n < N) ? (int)(hv >> CNT_SHIFT) + 1 : 0;
    int v = c;
#pragma unroll
    for (int m = 1; m < 64; m <<= 1) {
        int u = __shfl_up(v, m);
        if (lane >= m) v += u;
    }
    __shared__ int wsum[4];
    if (lane == 63) wsum[t >> 6] = v;
    __syncthreads();
    int w = t >> 6;
    int wadd = 0;
#pragma unroll
    for (int i = 0; i < 3; i++) wadd += (i < w) ? wsum[i] : 0;
    int base = block_off[blockIdx.x] + wadd + v - c;
    if (n < N) {
        row_ptr[n] = base;
        float asum = (float)(hv & SUM_MASK) * FIX_INV;
        float la = asum / fmaxf((float)(c - 1), 1.f);
        col[base] = make_int2(n, __float_as_int(la));   // self loop first in row
    }
}

__global__ void place_kernel(const int* __restrict__ src, const int* __restrict__ dst,
                             const float* __restrict__ eattr, const int* __restrict__ row_ptr,
                             const int* __restrict__ pos, int2* __restrict__ col, int E) {
    int e = blockIdx.x * blockDim.x + threadIdx.x;
    if (e < E) {
        int d = dst[e];
        col[row_ptr[d] + 1 + pos[e]] = make_int2(src[e], __float_as_int(eattr[e]));
    }
}

// ---------------- prep: we_dot scalars + folded attention vectors w_a = W^T a ----------------
// wp layout: [0..3] we_dot(layer,h); [4..13] w_as1[h][k]; [14..23] w_ad1;
//            [24..151] w_as2[h][k] (2x64); [152..279] w_ad2.

__global__ __launch_bounds__(256) void prep2_kernel(
        const float* __restrict__ W1, const float* __restrict__ as1, const float* __restrict__ ad1,
        const float* __restrict__ We1, const float* __restrict__ ae1,
        const float* __restrict__ W2, const float* __restrict__ as2, const float* __restrict__ ad2,
        const float* __restrict__ We2, const float* __restrict__ ae2,
        float* __restrict__ wp) {
    int t = threadIdx.x;
    int g = t >> 6, lane = t & 63;          // g = layer*2 + h
    const float* We = (g & 2) ? We2 : We1;
    const float* ae = (g & 2) ? ae2 : ae1;
    int h = g & 1;
    float v = We[h * 64 + lane] * ae[h * 64 + lane];
    RED(v)
    if (lane == 0) wp[g] = v;
    if (t < 20) {                            // layer-1 folded vectors (2 heads x 5)
        int dd = t / 10;
        int hh = (t % 10) / 5, k = t % 5;
        const float* a = dd ? ad1 : as1;
        float s = 0.f;
        for (int c = 0; c < 64; c++) s += W1[k * 128 + hh * 64 + c] * a[hh * 64 + c];
        wp[4 + dd * 10 + hh * 5 + k] = s;
    }
    {                                        // layer-2 folded vectors (2 heads x 64) x {s,d}
        int dd = t >> 7;
        int hh = (t >> 6) & 1, k = t & 63;
        const float* a = dd ? ad2 : as2;
        float s = 0.f;
        for (int c = 0; c < 64; c++) s += W2[k * 128 + hh * 64 + c] * a[hh * 64 + c];
        wp[24 + dd * 128 + hh * 64 + k] = s;
    }
}

// ---------------- layer-1 node pre-pass: logits + bf16-packed raw features ----------------

__global__ __launch_bounds__(256) void node_pre1(
        const float* __restrict__ x, const float* __restrict__ wp,
        float2* __restrict__ al_s, float2* __restrict__ al_d, uint4* __restrict__ xb1, int N) {
    int n = blockIdx.x * 256 + threadIdx.x;
    if (n >= N) return;
    float f[5];
#pragma unroll
    for (int k = 0; k < 5; k++) f[k] = x[(size_t)n * 5 + k];
    float s0 = 0.f, s1 = 0.f, d0 = 0.f, d1 = 0.f;
#pragma unroll
    for (int k = 0; k < 5; k++) {
        s0 += f[k] * wp[4 + k];   s1 += f[k] * wp[9 + k];
        d0 += f[k] * wp[14 + k];  d1 += f[k] * wp[19 + k];
    }
    al_s[n] = make_float2(s0, s1);
    al_d[n] = make_float2(d0, d1);
    uint4 p;
    p.x = (f2bf(f[1]) << 16) | f2bf(f[0]);
    p.y = (f2bf(f[3]) << 16) | f2bf(f[2]);
    p.z = f2bf(f[4]);
    p.w = 0;
    xb1[n] = p;
}

// ---------------- layer-1 edge aggregation: gather 16B raw-feature rows ----------------

__global__ __launch_bounds__(256) void edge_aggr_L1(
        const int* __restrict__ row_ptr, const int2* __restrict__ col,
        const float2* __restrict__ al_s, const float2* __restrict__ al_d,
        const uint4* __restrict__ xb1, const float* __restrict__ wp,
        float* __restrict__ agg1, int N) {
    int lane = threadIdx.x & 63;
    int n = blockIdx.x * 4 + (threadIdx.x >> 6);
    if (n >= N) return;
    int start = row_ptr[n], end = row_ptr[n + 1];
    int cnt = end - start;
    float we0 = wp[0], we1 = wp[1];
    float2 ald = al_d[n];
    float a00 = 0.f, a01 = 0.f, a02 = 0.f, a03 = 0.f, a04 = 0.f;
    float a10 = 0.f, a11 = 0.f, a12 = 0.f, a13 = 0.f, a14 = 0.f;
    float den0 = 0.f, den1 = 0.f;

    if (cnt <= 64) {
        float v0 = -INFINITY, v1 = -INFINITY;
        int sc = 0;
        if (lane < cnt) {
            int2 ce = col[start + lane];
            sc = ce.x;
            float at = __int_as_float(ce.y);
            float2 als = al_s[sc];
            v0 = LRELU(als.x + ald.x + we0 * at);
            v1 = LRELU(als.y + ald.y + we1 * at);
        }
        float m0 = v0, m1 = v1;
        REDMAX(m0) REDMAX(m1)
        if (lane < cnt) {
            float e0 = __expf(v0 - m0), e1 = __expf(v1 - m1);
            uint4 p = xb1[sc];
            float f0 = bfl(p.x), f1 = bfh(p.x), f2 = bfl(p.y), f3 = bfh(p.y), f4 = bfl(p.z);
            a00 = e0 * f0; a01 = e0 * f1; a02 = e0 * f2; a03 = e0 * f3; a04 = e0 * f4;
            a10 = e1 * f0; a11 = e1 * f1; a12 = e1 * f2; a13 = e1 * f3; a14 = e1 * f4;
            den0 = e0; den1 = e1;
        }
    } else {
        float m0 = -INFINITY, m1 = -INFINITY;
        for (int i = start + lane; i < end; i += 64) {
            int2 ce = col[i];
            float at = __int_as_float(ce.y);
            float2 als = al_s[ce.x];
            m0 = fmaxf(m0, LRELU(als.x + ald.x + we0 * at));
            m1 = fmaxf(m1, LRELU(als.y + ald.y + we1 * at));
        }
        REDMAX(m0) REDMAX(m1)
        for (int i = start + lane; i < end; i += 64) {
            int2 ce = col[i];
            float at = __int_as_float(ce.y);
            float2 als = al_s[ce.x];
            float e0 = __expf(LRELU(als.x + ald.x + we0 * at) - m0);
            float e1 = __expf(LRELU(als.y + ald.y + we1 * at) - m1);
            uint4 p = xb1[ce.x];
            float f0 = bfl(p.x), f1 = bfh(p.x), f2 = bfl(p.y), f3 = bfh(p.y), f4 = bfl(p.z);
            a00 += e0 * f0; a01 += e0 * f1; a02 += e0 * f2; a03 += e0 * f3; a04 += e0 * f4;
            a10 += e1 * f0; a11 += e1 * f1; a12 += e1 * f2; a13 += e1 * f3; a14 += e1 * f4;
            den0 += e0; den1 += e1;
        }
    }
    RED(a00) RED(a01) RED(a02) RED(a03) RED(a04)
    RED(a10) RED(a11) RED(a12) RED(a13) RED(a14)
    RED(den0) RED(den1)
    if (lane == 0) {
        float i0 = 1.f / (den0 + 1e-16f), i1 = 1.f / (den1 + 1e-16f);
        float* o = agg1 + (size_t)n * 10;
        o[0] = a00 * i0; o[1] = a01 * i0; o[2] = a02 * i0; o[3] = a03 * i0; o[4] = a04 * i0;
        o[5] = a10 * i1; o[6] = a11 * i1; o[7] = a12 * i1; o[8] = a13 * i1; o[9] = a14 * i1;
    }
}

// ---------------- layer-1 projection (post-aggregation) + layer-2 logits + packing ----------

__global__ __launch_bounds__(256) void proj1_kernel(
        const float* __restrict__ agg1, const float* __restrict__ W1, const float* __restrict__ b1,
        const float* __restrict__ wp,
        float2* __restrict__ al_s2, float2* __restrict__ al_d2, u32* __restrict__ xb2, int N) {
    int lane = threadIdx.x & 63;
    int n = blockIdx.x * 4 + (threadIdx.x >> 6);
    if (n >= N) return;
    const float* ag = agg1 + (size_t)n * 10;
    float s0 = 0.f, s1 = 0.f;
#pragma unroll
    for (int k = 0; k < 5; k++) {
        s0 += ag[k] * W1[k * 128 + lane];
        s1 += ag[5 + k] * W1[k * 128 + 64 + lane];
    }
    float h = fmaxf(0.5f * (s0 + s1) + b1[lane], 0.f);
    float r0 = h * wp[24 + lane], r1 = h * wp[88 + lane];
    float r2 = h * wp[152 + lane], r3 = h * wp[216 + lane];
    RED(r0) RED(r1) RED(r2) RED(r3)
    if (lane == 0) {
        al_s2[n] = make_float2(r0, r1);
        al_d2[n] = make_float2(r2, r3);
    }
    float hi = __shfl_down(h, 1);
    if (!(lane & 1)) xb2[(size_t)n * 32 + (lane >> 1)] = (f2bf(hi) << 16) | f2bf(h);
}

// ---------------- layer-2 edge aggregation: gather 128B bf16 feature rows ----------------

__global__ __launch_bounds__(256) void edge_aggr_L2(
        const int* __restrict__ row_ptr, const int2* __restrict__ col,
        const float2* __restrict__ al_s, const float2* __restrict__ al_d,
        const u32* __restrict__ xb2, const float* __restrict__ wp,
        float* __restrict__ agg2, int N) {
    __shared__ float s_e0[4][64], s_e1[4][64];
    __shared__ int s_src[4][64];
    int wid = threadIdx.x >> 6;
    int lane = threadIdx.x & 63;
    int n = blockIdx.x * 4 + wid;
    if (n >= N) return;
    int start = row_ptr[n], end = row_ptr[n + 1];
    int cnt = end - start;
    float we0 = wp[2], we1 = wp[3];
    float2 ald = al_d[n];
    bool lo = lane < 32;
    int word = lane & 31;
    float accx = 0.f, accy = 0.f, den0 = 0.f, den1 = 0.f;

    if (cnt <= 64) {
        float v0 = -INFINITY, v1 = -INFINITY;
        int sc = 0;
        if (lane < cnt) {
            int2 ce = col[start + lane];
            sc = ce.x;
            float at = __int_as_float(ce.y);
            float2 als = al_s[sc];
            v0 = LRELU(als.x + ald.x + we0 * at);
            v1 = LRELU(als.y + ald.y + we1 * at);
        }
        float m0 = v0, m1 = v1;
        REDMAX(m0) REDMAX(m1)
        float e0 = 0.f, e1 = 0.f;
        if (lane < cnt) {
            e0 = __expf(v0 - m0);
            e1 = __expf(v1 - m1);
        }
        den0 = e0; den1 = e1;
        s_e0[wid][lane] = e0; s_e1[wid][lane] = e1; s_src[wid][lane] = sc;
        // no barrier: same-wave LDS write->read

        const float* s_w = lo ? s_e0[wid] : s_e1[wid];
#pragma unroll 4
        for (int j = 0; j < cnt; j++) {
            float w = s_w[j];
            u32 v = xb2[(size_t)s_src[wid][j] * 32 + word];
            accx += w * bfl(v);
            accy += w * bfh(v);
        }
    } else {
        float m0 = -INFINITY, m1 = -INFINITY;
        for (int i = start + lane; i < end; i += 64) {
            int2 ce = col[i];
            float at = __int_as_float(ce.y);
            float2 als = al_s[ce.x];
            m0 = fmaxf(m0, LRELU(als.x + ald.x + we0 * at));
            m1 = fmaxf(m1, LRELU(als.y + ald.y + we1 * at));
        }
        REDMAX(m0) REDMAX(m1)
        const float* s_w = lo ? s_e0[wid] : s_e1[wid];
        for (int cs = start; cs < end; cs += 64) {
            int i = cs + lane;
            float e0 = 0.f, e1 = 0.f;
            int sc = 0;
            if (i < end) {
                int2 ce = col[i];
                sc = ce.x;
                float at = __int_as_float(ce.y);
                float2 als = al_s[sc];
                e0 = __expf(LRELU(als.x + ald.x + we0 * at) - m0);
                e1 = __expf(LRELU(als.y + ald.y + we1 * at) - m1);
            }
            den0 += e0; den1 += e1;
            s_e0[wid][lane] = e0; s_e1[wid][lane] = e1; s_src[wid][lane] = sc;
            int c2 = min(64, end - cs);
#pragma unroll 4
            for (int j = 0; j < c2; j++) {
                float w = s_w[j];
                u32 v = xb2[(size_t)s_src[wid][j] * 32 + word];
                accx += w * bfl(v);
                accy += w * bfh(v);
            }
        }
    }
    RED(den0) RED(den1)
    float inv = lo ? 1.f / (den0 + 1e-16f) : 1.f / (den1 + 1e-16f);
    float2* o = (float2*)(agg2 + (size_t)n * 128 + (lo ? 0 : 64));
    o[word] = make_float2(accx * inv, accy * inv);
}

// ---------------- layer-2 projection + relu + pooling (fused, W2 in REGISTERS) ----------------
// Lane owns output channel c=lane forever: its W2 column (128 values) lives in VGPRs,
// loaded once (coalesced). agg2 row is wave-uniform (readfirstlane) -> ag[k] scalarizes
// to s_load on the scalar pipe. Inner loop: 128 FMA, zero LDS reads.

__global__ __launch_bounds__(256) void proj2_pool3(
        const float* __restrict__ agg2, const float* __restrict__ W2, const float* __restrict__ b2,
        const float* __restrict__ Wlin, const int* __restrict__ batch,
        float* __restrict__ pool_sum, int* __restrict__ pool_cnt, int N) {
    __shared__ float s_sum[64];
    __shared__ int s_cnt[64];
    int t = threadIdx.x;
    int wid = t >> 6, lane = t & 63;
    if (t < 64) { s_sum[t] = 0.f; s_cnt[t] = 0; }
    __syncthreads();

    float w0[64], w1[64];                     // this lane's W2 columns (regs, static idx)
#pragma unroll
    for (int k = 0; k < 64; k++) {
        w0[k] = W2[k * 128 + lane];           // coalesced across lanes
        w1[k] = W2[k * 128 + 64 + lane];
    }
    float bb = b2[lane], wl = Wlin[lane];

    for (int n0 = blockIdx.x * 4 + wid; n0 < N; n0 += gridDim.x * 4) {
        int n = __builtin_amdgcn_readfirstlane(n0);   // force wave-uniform -> s_load path
        const float* ag = agg2 + (size_t)n * 128;
        float s0a = 0.f, s0b = 0.f, s1a = 0.f, s1b = 0.f;
#pragma unroll
        for (int k = 0; k < 64; k += 2) {
            s0a += ag[k] * w0[k];
            s0b += ag[k + 1] * w0[k + 1];
            s1a += ag[64 + k] * w1[k];
            s1b += ag[64 + k + 1] * w1[k + 1];
        }
        float v = fmaxf(0.5f * (s0a + s0b + s1a + s1b) + bb, 0.f) * wl;
        RED(v)
        if (lane == 0) {
            int g = batch[n];
            atomicAdd(&s_sum[g], v);
            atomicAdd(&s_cnt[g], 1);
        }
    }
    __syncthreads();
    if (t < 64 && s_cnt[t] > 0) {
        atomicAdd(&pool_sum[t], s_sum[t]);
        atomicAdd(&pool_cnt[t], s_cnt[t]);
    }
}

__global__ void final_kernel(const float* __restrict__ pool_sum, const int* __restrict__ pool_cnt,
                             const float* __restrict__ blin, float* __restrict__ out) {
    int g = threadIdx.x;
    if (g < 64) out[g] = pool_sum[g] / fmaxf((float)pool_cnt[g], 1.f) + blin[0];
}

// ---------------- launch ----------------

extern "C" void kernel_launch(void* const* d_in, const int* in_sizes, int n_in,
                              void* d_out, int out_size, void* d_ws, size_t ws_size,
                              hipStream_t stream) {
    const float* x     = (const float*)d_in[0];
    const int*   ei    = (const int*)d_in[1];
    const float* eattr = (const float*)d_in[2];
    const int*   batch = (const int*)d_in[3];
    const float* W1  = (const float*)d_in[4];
    const float* as1 = (const float*)d_in[5];
    const float* ad1 = (const float*)d_in[6];
    const float* We1 = (const float*)d_in[7];
    const float* ae1 = (const float*)d_in[8];
    const float* b1  = (const float*)d_in[9];
    const float* W2  = (const float*)d_in[10];
    const float* as2 = (const float*)d_in[11];
    const float* ad2 = (const float*)d_in[12];
    const float* We2 = (const float*)d_in[13];
    const float* ae2 = (const float*)d_in[14];
    const float* b2  = (const float*)d_in[15];
    const float* Wlin = (const float*)d_in[16];
    const float* blin = (const float*)d_in[17];
    float* out = (float*)d_out;

    int N = in_sizes[0] / 5;
    int E = in_sizes[1] / 2;
    size_t EP = (size_t)E + N;
    const int* src0 = ei;
    const int* dst0 = ei + E;
    int B = (N + 255) / 256;

    char* ws = (char*)d_ws;
    size_t off = 0;
    auto alloc = [&](size_t bytes) {
        void* p = ws + off;
        off = (off + bytes + 255) & ~(size_t)255;
        return p;
    };
    unsigned long long* hist = (unsigned long long*)alloc((size_t)N * 8);
    int*    row_ptr  = (int*)   alloc((size_t)(N + 1) * 4);
    int*    pos      = (int*)   alloc((size_t)E * 4);
    int2*   col      = (int2*)  alloc(EP * 8);
    int*    block_sum= (int*)   alloc((size_t)1024 * 4);
    int*    block_off= (int*)   alloc((size_t)1024 * 4);
    float*  wp       = (float*) alloc(280 * 4);
    float2* al_s1    = (float2*)alloc((size_t)N * 8);
    float2* al_d1    = (float2*)alloc((size_t)N * 8);
    uint4*  xb1      = (uint4*) alloc((size_t)N * 16);
    float*  agg1     = (float*) alloc((size_t)N * 10 * 4);
    float2* al_s2    = (float2*)alloc((size_t)N * 8);
    float2* al_d2    = (float2*)alloc((size_t)N * 8);
    u32*    xb2      = (u32*)   alloc((size_t)N * 32 * 4);
    float*  agg2     = (float*) alloc((size_t)N * 128 * 4);
    float*  pool_sum = (float*) alloc(64 * 4);
    int*    pool_cnt = (int*)   alloc(64 * 4);

    hipMemsetAsync(hist, 0, (size_t)N * 8, stream);
    hipMemsetAsync(block_sum, 0, (size_t)1024 * 4, stream);
    hipMemsetAsync(pool_sum, 0, 64 * 4, stream);
    hipMemsetAsync(pool_cnt, 0, 64 * 4, stream);

    hist_pos_kernel<<<(E + 255) / 256, 256, 0, stream>>>(dst0, eattr, hist, pos, E);
    scan_phase1<<<B, 256, 0, stream>>>(hist, block_sum, N);
    scan_phase2<<<1, 1024, 0, stream>>>(block_sum, block_off, row_ptr, B, N);
    scan_phase3<<<B, 256, 0, stream>>>(hist, block_off, row_ptr, col, N);
    place_kernel<<<(E + 255) / 256, 256, 0, stream>>>(src0, dst0, eattr, row_ptr, pos, col, E);
    prep2_kernel<<<1, 256, 0, stream>>>(W1, as1, ad1, We1, ae1, W2, as2, ad2, We2, ae2, wp);

    int eab = (N + 3) / 4;                  // 4 waves per block, wave per node

    // layer 1: aggregate raw 5-dim features, then project
    node_pre1<<<B, 256, 0, stream>>>(x, wp, al_s1, al_d1, xb1, N);
    edge_aggr_L1<<<eab, 256, 0, stream>>>(row_ptr, col, al_s1, al_d1, xb1, wp, agg1, N);
    proj1_kernel<<<eab, 256, 0, stream>>>(agg1, W1, b1, wp, al_s2, al_d2, xb2, N);
    // layer 2: aggregate 64-dim feat1, then project + pool (fused, reg-resident W2)
    edge_aggr_L2<<<eab, 256, 0, stream>>>(row_ptr, col, al_s2, al_d2, xb2, wp, agg2, N);
    proj2_pool3<<<768, 256, 0, stream>>>(agg2, W2, b2, Wlin, batch, pool_sum, pool_cnt, N);
    final_kernel<<<1, 64, 0, stream>>>(pool_sum, pool_cnt, blin, out);
}

// Round 18
// 194.508 us; speedup vs baseline: 1.4505x; 1.1746x over previous
//
#include <hip/hip_runtime.h>
#include <hip/hip_bf16.h>
#include <math.h>

typedef unsigned int u32;
typedef __attribute__((ext_vector_type(8))) short short8v;   // 8 bf16 = 4 VGPRs
typedef __attribute__((ext_vector_type(4))) float f32x4;

#define LRELU(a) ((a) > 0.f ? (a) : 0.2f * (a))

#define FIX_SCALE 67108864.0f          // 2^26 fixed-point for attr sums
#define FIX_INV   (1.0f / 67108864.0f)
#define CNT_SHIFT 40
#define SUM_MASK  0xFFFFFFFFFFULL

// round-to-nearest-even f32 -> bf16 bits
__device__ __forceinline__ u32 f2bf(float f) {
    u32 u = __float_as_uint(f);
    return (u + 0x7fffu + ((u >> 16) & 1u)) >> 16;
}
__device__ __forceinline__ float bfl(u32 w) { return __uint_as_float(w << 16); }
__device__ __forceinline__ float bfh(u32 w) { return __uint_as_float(w & 0xffff0000u); }

#define RED(x) _Pragma("unroll") for (int m_ = 32; m_ >= 1; m_ >>= 1) x += __shfl_xor(x, m_);
#define REDMAX(x) _Pragma("unroll") for (int m_ = 32; m_ >= 1; m_ >>= 1) x = fmaxf(x, __shfl_xor(x, m_));

// ---------------- CSR build (unchanged; passed) ----------------

__global__ void hist_pos_kernel(const int* __restrict__ dst, const float* __restrict__ eattr,
                                unsigned long long* __restrict__ hist, int* __restrict__ pos, int E) {
    int e = blockIdx.x * blockDim.x + threadIdx.x;
    if (e < E) {
        int d = dst[e];
        unsigned long long v = (1ULL << CNT_SHIFT) |
                               (unsigned long long)(eattr[e] * FIX_SCALE + 0.5f);
        unsigned long long old = atomicAdd(&hist[d], v);
        pos[e] = (int)(old >> CNT_SHIFT);
    }
}

__global__ __launch_bounds__(256) void scan_phase1(const unsigned long long* __restrict__ hist,
                                                   int* __restrict__ block_sum, int N) {
    int t = threadIdx.x;
    int n = blockIdx.x * 256 + t;
    int v = (n < N) ? (int)(hist[n] >> CNT_SHIFT) + 1 : 0;  // +1 self loop
    RED(v)
    __shared__ int ws[4];
    if ((t & 63) == 0) ws[t >> 6] = v;
    __syncthreads();
    if (t == 0) block_sum[blockIdx.x] = ws[0] + ws[1] + ws[2] + ws[3];
}

__global__ __launch_bounds__(1024) void scan_phase2(const int* __restrict__ block_sum,
                                                    int* __restrict__ block_off,
                                                    int* __restrict__ row_ptr, int B, int N) {
    __shared__ int s[1024];
    int t = threadIdx.x;
    int v = (t < B) ? block_sum[t] : 0;
    s[t] = v;
    __syncthreads();
    for (int off = 1; off < 1024; off <<= 1) {
        int u = (t >= off) ? s[t - off] : 0;
        __syncthreads();
        s[t] += u;
        __syncthreads();
    }
    if (t < B) block_off[t] = s[t] - v;
    if (t == 1023) row_ptr[N] = s[1023];
}

__global__ __launch_bounds__(256) void scan_phase3(const unsigned long long* __restrict__ hist,
                                                   const int* __restrict__ block_off,
                                                   int* __restrict__ row_ptr,
                                                   int2* __restrict__ col, int N) {
    int t = threadIdx.x;
    int lane = t & 63;
    int n = blockIdx.x * 256 + t;
    unsigned long long hv = (n < N) ? hist[n] : 0ULL;
    int c = (n < N) ? (int)(hv >> CNT_SHIFT) + 1 : 0;
    int v = c;
#pragma unroll
    for (int m = 1; m < 64; m <<= 1) {
        int u = __shfl_up(v, m);
        if (lane >= m) v += u;
    }
    __shared__ int wsum[4];
    if (lane == 63) wsum[t >> 6] = v;
    __syncthreads();
    int w = t >> 6;
    int wadd = 0;
#pragma unroll
    for (int i = 0; i < 3; i++) wadd += (i < w) ? wsum[i] : 0;
    int base = block_off[blockIdx.x] + wadd + v - c;
    if (n < N) {
        row_ptr[n] = base;
        float asum = (float)(hv & SUM_MASK) * FIX_INV;
        float la = asum / fmaxf((float)(c - 1), 1.f);
        col[base] = make_int2(n, __float_as_int(la));   // self loop first in row
    }
}

__global__ void place_kernel(const int* __restrict__ src, const int* __restrict__ dst,
                             const float* __restrict__ eattr, const int* __restrict__ row_ptr,
                             const int* __restrict__ pos, int2* __restrict__ col, int E) {
    int e = blockIdx.x * blockDim.x + threadIdx.x;
    if (e < E) {
        int d = dst[e];
        col[row_ptr[d] + 1 + pos[e]] = make_int2(src[e], __float_as_int(eattr[e]));
    }
}

// ---------------- prep: we_dot scalars + folded attention vectors + bf16 W2b ----------------
// wp layout: [0..3] we_dot(layer,h); [4..13] w_as1[h][k]; [14..23] w_ad1;
//            [24..151] w_as2[h][k] (2x64); [152..279] w_ad2.
// W2b[k][c] (bf16, 128x64) = 0.5*W2 (head-mean folded in; exact exponent shift):
//   k<64 -> 0.5*W2[k][c] (head0), k>=64 -> 0.5*W2[k-64][64+c] (head1).

__global__ __launch_bounds__(256) void prep2_kernel(
        const float* __restrict__ W1, const float* __restrict__ as1, const float* __restrict__ ad1,
        const float* __restrict__ We1, const float* __restrict__ ae1,
        const float* __restrict__ W2, const float* __restrict__ as2, const float* __restrict__ ad2,
        const float* __restrict__ We2, const float* __restrict__ ae2,
        float* __restrict__ wp, unsigned short* __restrict__ W2b) {
    int t = threadIdx.x;
    int g = t >> 6, lane = t & 63;          // g = layer*2 + h
    const float* We = (g & 2) ? We2 : We1;
    const float* ae = (g & 2) ? ae2 : ae1;
    int h = g & 1;
    float v = We[h * 64 + lane] * ae[h * 64 + lane];
    RED(v)
    if (lane == 0) wp[g] = v;
    if (t < 20) {                            // layer-1 folded vectors (2 heads x 5)
        int dd = t / 10;
        int hh = (t % 10) / 5, k = t % 5;
        const float* a = dd ? ad1 : as1;
        float s = 0.f;
        for (int c = 0; c < 64; c++) s += W1[k * 128 + hh * 64 + c] * a[hh * 64 + c];
        wp[4 + dd * 10 + hh * 5 + k] = s;
    }
    {                                        // layer-2 folded vectors (2 heads x 64) x {s,d}
        int dd = t >> 7;
        int hh = (t >> 6) & 1, k = t & 63;
        const float* a = dd ? ad2 : as2;
        float s = 0.f;
        for (int c = 0; c < 64; c++) s += W2[k * 128 + hh * 64 + c] * a[hh * 64 + c];
        wp[24 + dd * 128 + hh * 64 + k] = s;
    }
    for (int i = t; i < 128 * 64; i += 256) {  // W2b bf16, 0.5 head-mean folded (exact)
        int k = i >> 6, c = i & 63;
        W2b[i] = (unsigned short)f2bf(0.5f * W2[(k & 63) * 128 + (k & 64) + c]);
    }
}

// ---------------- layer-1 node pre-pass: logits + bf16-packed raw features ----------------

__global__ __launch_bounds__(256) void node_pre1(
        const float* __restrict__ x, const float* __restrict__ wp,
        float2* __restrict__ al_s, float2* __restrict__ al_d, uint4* __restrict__ xb1, int N) {
    int n = blockIdx.x * 256 + threadIdx.x;
    if (n >= N) return;
    float f[5];
#pragma unroll
    for (int k = 0; k < 5; k++) f[k] = x[(size_t)n * 5 + k];
    float s0 = 0.f, s1 = 0.f, d0 = 0.f, d1 = 0.f;
#pragma unroll
    for (int k = 0; k < 5; k++) {
        s0 += f[k] * wp[4 + k];   s1 += f[k] * wp[9 + k];
        d0 += f[k] * wp[14 + k];  d1 += f[k] * wp[19 + k];
    }
    al_s[n] = make_float2(s0, s1);
    al_d[n] = make_float2(d0, d1);
    uint4 p;
    p.x = (f2bf(f[1]) << 16) | f2bf(f[0]);
    p.y = (f2bf(f[3]) << 16) | f2bf(f[2]);
    p.z = f2bf(f[4]);
    p.w = 0;
    xb1[n] = p;
}

// ---------------- layer-1 edge aggregation: gather 16B raw-feature rows ----------------

__global__ __launch_bounds__(256) void edge_aggr_L1(
        const int* __restrict__ row_ptr, const int2* __restrict__ col,
        const float2* __restrict__ al_s, const float2* __restrict__ al_d,
        const uint4* __restrict__ xb1, const float* __restrict__ wp,
        float* __restrict__ agg1, int N) {
    int lane = threadIdx.x & 63;
    int n = blockIdx.x * 4 + (threadIdx.x >> 6);
    if (n >= N) return;
    int start = row_ptr[n], end = row_ptr[n + 1];
    int cnt = end - start;
    float we0 = wp[0], we1 = wp[1];
    float2 ald = al_d[n];
    float a00 = 0.f, a01 = 0.f, a02 = 0.f, a03 = 0.f, a04 = 0.f;
    float a10 = 0.f, a11 = 0.f, a12 = 0.f, a13 = 0.f, a14 = 0.f;
    float den0 = 0.f, den1 = 0.f;

    if (cnt <= 64) {
        float v0 = -INFINITY, v1 = -INFINITY;
        int sc = 0;
        if (lane < cnt) {
            int2 ce = col[start + lane];
            sc = ce.x;
            float at = __int_as_float(ce.y);
            float2 als = al_s[sc];
            v0 = LRELU(als.x + ald.x + we0 * at);
            v1 = LRELU(als.y + ald.y + we1 * at);
        }
        float m0 = v0, m1 = v1;
        REDMAX(m0) REDMAX(m1)
        if (lane < cnt) {
            float e0 = __expf(v0 - m0), e1 = __expf(v1 - m1);
            uint4 p = xb1[sc];
            float f0 = bfl(p.x), f1 = bfh(p.x), f2 = bfl(p.y), f3 = bfh(p.y), f4 = bfl(p.z);
            a00 = e0 * f0; a01 = e0 * f1; a02 = e0 * f2; a03 = e0 * f3; a04 = e0 * f4;
            a10 = e1 * f0; a11 = e1 * f1; a12 = e1 * f2; a13 = e1 * f3; a14 = e1 * f4;
            den0 = e0; den1 = e1;
        }
    } else {
        float m0 = -INFINITY, m1 = -INFINITY;
        for (int i = start + lane; i < end; i += 64) {
            int2 ce = col[i];
            float at = __int_as_float(ce.y);
            float2 als = al_s[ce.x];
            m0 = fmaxf(m0, LRELU(als.x + ald.x + we0 * at));
            m1 = fmaxf(m1, LRELU(als.y + ald.y + we1 * at));
        }
        REDMAX(m0) REDMAX(m1)
        for (int i = start + lane; i < end; i += 64) {
            int2 ce = col[i];
            float at = __int_as_float(ce.y);
            float2 als = al_s[ce.x];
            float e0 = __expf(LRELU(als.x + ald.x + we0 * at) - m0);
            float e1 = __expf(LRELU(als.y + ald.y + we1 * at) - m1);
            uint4 p = xb1[ce.x];
            float f0 = bfl(p.x), f1 = bfh(p.x), f2 = bfl(p.y), f3 = bfh(p.y), f4 = bfl(p.z);
            a00 += e0 * f0; a01 += e0 * f1; a02 += e0 * f2; a03 += e0 * f3; a04 += e0 * f4;
            a10 += e1 * f0; a11 += e1 * f1; a12 += e1 * f2; a13 += e1 * f3; a14 += e1 * f4;
            den0 += e0; den1 += e1;
        }
    }
    RED(a00) RED(a01) RED(a02) RED(a03) RED(a04)
    RED(a10) RED(a11) RED(a12) RED(a13) RED(a14)
    RED(den0) RED(den1)
    if (lane == 0) {
        float i0 = 1.f / (den0 + 1e-16f), i1 = 1.f / (den1 + 1e-16f);
        float* o = agg1 + (size_t)n * 10;
        o[0] = a00 * i0; o[1] = a01 * i0; o[2] = a02 * i0; o[3] = a03 * i0; o[4] = a04 * i0;
        o[5] = a10 * i1; o[6] = a11 * i1; o[7] = a12 * i1; o[8] = a13 * i1; o[9] = a14 * i1;
    }
}

// ---------------- layer-1 projection (post-aggregation) + layer-2 logits + packing ----------

__global__ __launch_bounds__(256) void proj1_kernel(
        const float* __restrict__ agg1, const float* __restrict__ W1, const float* __restrict__ b1,
        const float* __restrict__ wp,
        float2* __restrict__ al_s2, float2* __restrict__ al_d2, u32* __restrict__ xb2, int N) {
    int lane = threadIdx.x & 63;
    int n = blockIdx.x * 4 + (threadIdx.x >> 6);
    if (n >= N) return;
    const float* ag = agg1 + (size_t)n * 10;
    float s0 = 0.f, s1 = 0.f;
#pragma unroll
    for (int k = 0; k < 5; k++) {
        s0 += ag[k] * W1[k * 128 + lane];
        s1 += ag[5 + k] * W1[k * 128 + 64 + lane];
    }
    float h = fmaxf(0.5f * (s0 + s1) + b1[lane], 0.f);
    float r0 = h * wp[24 + lane], r1 = h * wp[88 + lane];
    float r2 = h * wp[152 + lane], r3 = h * wp[216 + lane];
    RED(r0) RED(r1) RED(r2) RED(r3)
    if (lane == 0) {
        al_s2[n] = make_float2(r0, r1);
        al_d2[n] = make_float2(r2, r3);
    }
    float hi = __shfl_down(h, 1);
    if (!(lane & 1)) xb2[(size_t)n * 32 + (lane >> 1)] = (f2bf(hi) << 16) | f2bf(h);
}

// ---------------- layer-2 edge aggregation: gather 128B bf16 rows; bf16 packed output ------
// agg2b[n] = 64 u32 words = 128 bf16: k 0..63 head0 aggregate, 64..127 head1.

__global__ __launch_bounds__(256) void edge_aggr_L2(
        const int* __restrict__ row_ptr, const int2* __restrict__ col,
        const float2* __restrict__ al_s, const float2* __restrict__ al_d,
        const u32* __restrict__ xb2, const float* __restrict__ wp,
        u32* __restrict__ agg2b, int N) {
    __shared__ float s_e0[4][64], s_e1[4][64];
    __shared__ int s_src[4][64];
    int wid = threadIdx.x >> 6;
    int lane = threadIdx.x & 63;
    int n = blockIdx.x * 4 + wid;
    if (n >= N) return;
    int start = row_ptr[n], end = row_ptr[n + 1];
    int cnt = end - start;
    float we0 = wp[2], we1 = wp[3];
    float2 ald = al_d[n];
    bool lo = lane < 32;
    int word = lane & 31;
    float accx = 0.f, accy = 0.f, den0 = 0.f, den1 = 0.f;

    if (cnt <= 64) {
        float v0 = -INFINITY, v1 = -INFINITY;
        int sc = 0;
        if (lane < cnt) {
            int2 ce = col[start + lane];
            sc = ce.x;
            float at = __int_as_float(ce.y);
            float2 als = al_s[sc];
            v0 = LRELU(als.x + ald.x + we0 * at);
            v1 = LRELU(als.y + ald.y + we1 * at);
        }
        float m0 = v0, m1 = v1;
        REDMAX(m0) REDMAX(m1)
        float e0 = 0.f, e1 = 0.f;
        if (lane < cnt) {
            e0 = __expf(v0 - m0);
            e1 = __expf(v1 - m1);
        }
        den0 = e0; den1 = e1;
        s_e0[wid][lane] = e0; s_e1[wid][lane] = e1; s_src[wid][lane] = sc;
        // no barrier: same-wave LDS write->read

        const float* s_w = lo ? s_e0[wid] : s_e1[wid];
#pragma unroll 4
        for (int j = 0; j < cnt; j++) {
            float w = s_w[j];
            u32 v = xb2[(size_t)s_src[wid][j] * 32 + word];
            accx += w * bfl(v);
            accy += w * bfh(v);
        }
    } else {
        float m0 = -INFINITY, m1 = -INFINITY;
        for (int i = start + lane; i < end; i += 64) {
            int2 ce = col[i];
            float at = __int_as_float(ce.y);
            float2 als = al_s[ce.x];
            m0 = fmaxf(m0, LRELU(als.x + ald.x + we0 * at));
            m1 = fmaxf(m1, LRELU(als.y + ald.y + we1 * at));
        }
        REDMAX(m0) REDMAX(m1)
        const float* s_w = lo ? s_e0[wid] : s_e1[wid];
        for (int cs = start; cs < end; cs += 64) {
            int i = cs + lane;
            float e0 = 0.f, e1 = 0.f;
            int sc = 0;
            if (i < end) {
                int2 ce = col[i];
                sc = ce.x;
                float at = __int_as_float(ce.y);
                float2 als = al_s[sc];
                e0 = __expf(LRELU(als.x + ald.x + we0 * at) - m0);
                e1 = __expf(LRELU(als.y + ald.y + we1 * at) - m1);
            }
            den0 += e0; den1 += e1;
            s_e0[wid][lane] = e0; s_e1[wid][lane] = e1; s_src[wid][lane] = sc;
            int c2 = min(64, end - cs);
#pragma unroll 4
            for (int j = 0; j < c2; j++) {
                float w = s_w[j];
                u32 v = xb2[(size_t)s_src[wid][j] * 32 + word];
                accx += w * bfl(v);
                accy += w * bfh(v);
            }
        }
    }
    RED(den0) RED(den1)
    float inv = lo ? 1.f / (den0 + 1e-16f) : 1.f / (den1 + 1e-16f);
    agg2b[(size_t)n * 64 + (lo ? 0 : 32) + word] =
        (f2bf(accy * inv) << 16) | f2bf(accx * inv);
}

// ---------------- layer-2 projection + relu + pooling: MFMA GEMM [N x128]x[128 x64] ----------
// Wave per 16-node strip. B (0.5*W2 bf16) in 16 register fragments (loaded once). Per strip:
// 4x uint4 A-frag loads + 16x mfma_f32_16x16x32_bf16. Epilogue: bias+relu+Wlin dot,
// 4-step shfl_xor channel reduce, LDS pool bins.
// Layouts (16x16x32): A row=lane&15, k=8*(lane>>4)+r (contig 16B); B col=lane&15, same k;
// C/D col=lane&15, row=(lane>>4)*4+reg  [verified m89 mapping].

__global__ __launch_bounds__(256) void proj2_pool_mfma(
        const u32* __restrict__ agg2b, const unsigned short* __restrict__ W2b,
        const float* __restrict__ b2, const float* __restrict__ Wlin,
        const int* __restrict__ batch,
        float* __restrict__ pool_sum, int* __restrict__ pool_cnt, int N) {
    __shared__ float s_sum[64];
    __shared__ int s_cnt[64];
    int t = threadIdx.x;
    int wid = t >> 6, lane = t & 63;
    if (t < 64) { s_sum[t] = 0.f; s_cnt[t] = 0; }
    __syncthreads();

    int sub = lane >> 4, cc = lane & 15;

    // B fragments: bfrag[tile][kk], element r = W2b[kk*32 + 8*sub + r][tile*16 + cc]
    short8v bfrag[4][4];
#pragma unroll
    for (int tl = 0; tl < 4; tl++)
#pragma unroll
        for (int kk = 0; kk < 4; kk++)
#pragma unroll
            for (int r = 0; r < 8; r++)
                bfrag[tl][kk][r] = (short)W2b[(kk * 32 + 8 * sub + r) * 64 + tl * 16 + cc];

    float b2v[4], wlv[4];
#pragma unroll
    for (int tl = 0; tl < 4; tl++) {
        b2v[tl] = b2[tl * 16 + cc];
        wlv[tl] = Wlin[tl * 16 + cc];
    }

    int nstrips = (N + 15) >> 4;
    for (int strip = blockIdx.x * 4 + wid; strip < nstrips; strip += gridDim.x * 4) {
        int n0 = strip << 4;
        int arow = min(n0 + cc, N - 1);     // lane's A row (clamped in tail strip)
        const uint4* ap = (const uint4*)agg2b;
        short8v a[4];
#pragma unroll
        for (int kk = 0; kk < 4; kk++) {    // row = 16 uint4; kk-block has 4, take sub-th
            uint4 raw = ap[(size_t)arow * 16 + kk * 4 + sub];
            a[kk] = *(const short8v*)&raw;
        }

        f32x4 acc0 = {0.f, 0.f, 0.f, 0.f}, acc1 = acc0, acc2 = acc0, acc3 = acc0;
#pragma unroll
        for (int kk = 0; kk < 4; kk++) {
            acc0 = __builtin_amdgcn_mfma_f32_16x16x32_bf16(a[kk], bfrag[0][kk], acc0, 0, 0, 0);
            acc1 = __builtin_amdgcn_mfma_f32_16x16x32_bf16(a[kk], bfrag[1][kk], acc1, 0, 0, 0);
            acc2 = __builtin_amdgcn_mfma_f32_16x16x32_bf16(a[kk], bfrag[2][kk], acc2, 0, 0, 0);
            acc3 = __builtin_amdgcn_mfma_f32_16x16x32_bf16(a[kk], bfrag[3][kk], acc3, 0, 0, 0);
        }

#pragma unroll
        for (int r = 0; r < 4; r++) {
            float p = fmaxf(acc0[r] + b2v[0], 0.f) * wlv[0]
                    + fmaxf(acc1[r] + b2v[1], 0.f) * wlv[1]
                    + fmaxf(acc2[r] + b2v[2], 0.f) * wlv[2]
                    + fmaxf(acc3[r] + b2v[3], 0.f) * wlv[3];
#pragma unroll
            for (int m = 8; m >= 1; m >>= 1) p += __shfl_xor(p, m);
            if (cc == 0) {
                int node = n0 + sub * 4 + r;
                if (node < N) {
                    int g = batch[node];
                    atomicAdd(&s_sum[g], p);
                    atomicAdd(&s_cnt[g], 1);
                }
            }
        }
    }
    __syncthreads();
    if (t < 64 && s_cnt[t] > 0) {
        atomicAdd(&pool_sum[t], s_sum[t]);
        atomicAdd(&pool_cnt[t], s_cnt[t]);
    }
}

__global__ void final_kernel(const float* __restrict__ pool_sum, const int* __restrict__ pool_cnt,
                             const float* __restrict__ blin, float* __restrict__ out) {
    int g = threadIdx.x;
    if (g < 64) out[g] = pool_sum[g] / fmaxf((float)pool_cnt[g], 1.f) + blin[0];
}

// ---------------- launch ----------------

extern "C" void kernel_launch(void* const* d_in, const int* in_sizes, int n_in,
                              void* d_out, int out_size, void* d_ws, size_t ws_size,
                              hipStream_t stream) {
    const float* x     = (const float*)d_in[0];
    const int*   ei    = (const int*)d_in[1];
    const float* eattr = (const float*)d_in[2];
    const int*   batch = (const int*)d_in[3];
    const float* W1  = (const float*)d_in[4];
    const float* as1 = (const float*)d_in[5];
    const float* ad1 = (const float*)d_in[6];
    const float* We1 = (const float*)d_in[7];
    const float* ae1 = (const float*)d_in[8];
    const float* b1  = (const float*)d_in[9];
    const float* W2  = (const float*)d_in[10];
    const float* as2 = (const float*)d_in[11];
    const float* ad2 = (const float*)d_in[12];
    const float* We2 = (const float*)d_in[13];
    const float* ae2 = (const float*)d_in[14];
    const float* b2  = (const float*)d_in[15];
    const float* Wlin = (const float*)d_in[16];
    const float* blin = (const float*)d_in[17];
    float* out = (float*)d_out;

    int N = in_sizes[0] / 5;
    int E = in_sizes[1] / 2;
    size_t EP = (size_t)E + N;
    const int* src0 = ei;
    const int* dst0 = ei + E;
    int B = (N + 255) / 256;

    char* ws = (char*)d_ws;
    size_t off = 0;
    auto alloc = [&](size_t bytes) {
        void* p = ws + off;
        off = (off + bytes + 255) & ~(size_t)255;
        return p;
    };
    unsigned long long* hist = (unsigned long long*)alloc((size_t)N * 8);
    int*    row_ptr  = (int*)   alloc((size_t)(N + 1) * 4);
    int*    pos      = (int*)   alloc((size_t)E * 4);
    int2*   col      = (int2*)  alloc(EP * 8);
    int*    block_sum= (int*)   alloc((size_t)1024 * 4);
    int*    block_off= (int*)   alloc((size_t)1024 * 4);
    float*  wp       = (float*) alloc(280 * 4);
    unsigned short* W2b = (unsigned short*)alloc((size_t)128 * 64 * 2);
    float2* al_s1    = (float2*)alloc((size_t)N * 8);
    float2* al_d1    = (float2*)alloc((size_t)N * 8);
    uint4*  xb1      = (uint4*) alloc((size_t)N * 16);
    float*  agg1     = (float*) alloc((size_t)N * 10 * 4);
    float2* al_s2    = (float2*)alloc((size_t)N * 8);
    float2* al_d2    = (float2*)alloc((size_t)N * 8);
    u32*    xb2      = (u32*)   alloc((size_t)N * 32 * 4);
    u32*    agg2b    = (u32*)   alloc((size_t)N * 64 * 4);
    float*  pool_sum = (float*) alloc(64 * 4);
    int*    pool_cnt = (int*)   alloc(64 * 4);

    hipMemsetAsync(hist, 0, (size_t)N * 8, stream);
    hipMemsetAsync(block_sum, 0, (size_t)1024 * 4, stream);
    hipMemsetAsync(pool_sum, 0, 64 * 4, stream);
    hipMemsetAsync(pool_cnt, 0, 64 * 4, stream);

    hist_pos_kernel<<<(E + 255) / 256, 256, 0, stream>>>(dst0, eattr, hist, pos, E);
    scan_phase1<<<B, 256, 0, stream>>>(hist, block_sum, N);
    scan_phase2<<<1, 1024, 0, stream>>>(block_sum, block_off, row_ptr, B, N);
    scan_phase3<<<B, 256, 0, stream>>>(hist, block_off, row_ptr, col, N);
    place_kernel<<<(E + 255) / 256, 256, 0, stream>>>(src0, dst0, eattr, row_ptr, pos, col, E);
    prep2_kernel<<<1, 256, 0, stream>>>(W1, as1, ad1, We1, ae1, W2, as2, ad2, We2, ae2, wp, W2b);

    int eab = (N + 3) / 4;                  // 4 waves per block, wave per node

    // layer 1: aggregate raw 5-dim features, then project
    node_pre1<<<B, 256, 0, stream>>>(x, wp, al_s1, al_d1, xb1, N);
    edge_aggr_L1<<<eab, 256, 0, stream>>>(row_ptr, col, al_s1, al_d1, xb1, wp, agg1, N);
    proj1_kernel<<<eab, 256, 0, stream>>>(agg1, W1, b1, wp, al_s2, al_d2, xb2, N);
    // layer 2: aggregate 64-dim feat1 (bf16 out), then MFMA projection + pool
    edge_aggr_L2<<<eab, 256, 0, stream>>>(row_ptr, col, al_s2, al_d2, xb2, wp, agg2b, N);
    int nstrips = (N + 15) / 16;
    proj2_pool_mfma<<<(nstrips + 3) / 4, 256, 0, stream>>>(agg2b, W2b, b2, Wlin, batch,
                                                           pool_sum, pool_cnt, N);
    final_kernel<<<1, 64, 0, stream>>>(pool_sum, pool_cnt, blin, out);
}

// Round 20
// 171.490 us; speedup vs baseline: 1.6452x; 1.1342x over previous
//
#include <hip/hip_runtime.h>
#include <hip/hip_bf16.h>
#include <math.h>

typedef unsigned int u32;
typedef __attribute__((ext_vector_type(8))) short short8v;   // 8 bf16 = 4 VGPRs
typedef __attribute__((ext_vector_type(4))) float f32x4;

#define LRELU(a) ((a) > 0.f ? (a) : 0.2f * (a))

#define FIX_SCALE 67108864.0f          // 2^26 fixed-point for attr sums
#define FIX_INV   (1.0f / 67108864.0f)
#define CNT_SHIFT 40
#define SUM_MASK  0xFFFFFFFFFFULL

// round-to-nearest-even f32 -> bf16 bits
__device__ __forceinline__ u32 f2bf(float f) {
    u32 u = __float_as_uint(f);
    return (u + 0x7fffu + ((u >> 16) & 1u)) >> 16;
}
__device__ __forceinline__ float bfl(u32 w) { return __uint_as_float(w << 16); }
__device__ __forceinline__ float bfh(u32 w) { return __uint_as_float(w & 0xffff0000u); }

#define RED(x) _Pragma("unroll") for (int m_ = 32; m_ >= 1; m_ >>= 1) x += __shfl_xor(x, m_);
#define REDMAX(x) _Pragma("unroll") for (int m_ = 32; m_ >= 1; m_ >>= 1) x = fmaxf(x, __shfl_xor(x, m_));
// 32-lane-segment variants (masks <=16 stay within each half-wave)
#define RED32(x) _Pragma("unroll") for (int m_ = 16; m_ >= 1; m_ >>= 1) x += __shfl_xor(x, m_);
#define REDMAX32(x) _Pragma("unroll") for (int m_ = 16; m_ >= 1; m_ >>= 1) x = fmaxf(x, __shfl_xor(x, m_));

// ---------------- CSR build (unchanged; passed) ----------------

__global__ void hist_pos_kernel(const int* __restrict__ dst, const float* __restrict__ eattr,
                                unsigned long long* __restrict__ hist, int* __restrict__ pos, int E) {
    int e = blockIdx.x * blockDim.x + threadIdx.x;
    if (e < E) {
        int d = dst[e];
        unsigned long long v = (1ULL << CNT_SHIFT) |
                               (unsigned long long)(eattr[e] * FIX_SCALE + 0.5f);
        unsigned long long old = atomicAdd(&hist[d], v);
        pos[e] = (int)(old >> CNT_SHIFT);
    }
}

__global__ __launch_bounds__(256) void scan_phase1(const unsigned long long* __restrict__ hist,
                                                   int* __restrict__ block_sum, int N) {
    int t = threadIdx.x;
    int n = blockIdx.x * 256 + t;
    int v = (n < N) ? (int)(hist[n] >> CNT_SHIFT) + 1 : 0;  // +1 self loop
    RED(v)
    __shared__ int ws[4];
    if ((t & 63) == 0) ws[t >> 6] = v;
    __syncthreads();
    if (t == 0) block_sum[blockIdx.x] = ws[0] + ws[1] + ws[2] + ws[3];
}

__global__ __launch_bounds__(1024) void scan_phase2(const int* __restrict__ block_sum,
                                                    int* __restrict__ block_off,
                                                    int* __restrict__ row_ptr, int B, int N) {
    __shared__ int s[1024];
    int t = threadIdx.x;
    int v = (t < B) ? block_sum[t] : 0;
    s[t] = v;
    __syncthreads();
    for (int off = 1; off < 1024; off <<= 1) {
        int u = (t >= off) ? s[t - off] : 0;
        __syncthreads();
        s[t] += u;
        __syncthreads();
    }
    if (t < B) block_off[t] = s[t] - v;
    if (t == 1023) row_ptr[N] = s[1023];
}

__global__ __launch_bounds__(256) void scan_phase3(const unsigned long long* __restrict__ hist,
                                                   const int* __restrict__ block_off,
                                                   int* __restrict__ row_ptr,
                                                   int2* __restrict__ col, int N) {
    int t = threadIdx.x;
    int lane = t & 63;
    int n = blockIdx.x * 256 + t;
    unsigned long long hv = (n < N) ? hist[n] : 0ULL;
    int c = (n < N) ? (int)(hv >> CNT_SHIFT) + 1 : 0;
    int v = c;
#pragma unroll
    for (int m = 1; m < 64; m <<= 1) {
        int u = __shfl_up(v, m);
        if (lane >= m) v += u;
    }
    __shared__ int wsum[4];
    if (lane == 63) wsum[t >> 6] = v;
    __syncthreads();
    int w = t >> 6;
    int wadd = 0;
#pragma unroll
    for (int i = 0; i < 3; i++) wadd += (i < w) ? wsum[i] : 0;
    int base = block_off[blockIdx.x] + wadd + v - c;
    if (n < N) {
        row_ptr[n] = base;
        float asum = (float)(hv & SUM_MASK) * FIX_INV;
        float la = asum / fmaxf((float)(c - 1), 1.f);
        col[base] = make_int2(n, __float_as_int(la));   // self loop first in row
    }
}

__global__ void place_kernel(const int* __restrict__ src, const int* __restrict__ dst,
                             const float* __restrict__ eattr, const int* __restrict__ row_ptr,
                             const int* __restrict__ pos, int2* __restrict__ col, int E) {
    int e = blockIdx.x * blockDim.x + threadIdx.x;
    if (e < E) {
        int d = dst[e];
        col[row_ptr[d] + 1 + pos[e]] = make_int2(src[e], __float_as_int(eattr[e]));
    }
}

// ---------------- prep: we_dot scalars + folded attention vectors + bf16 W2b ----------------
// wp layout: [0..3] we_dot(layer,h); [4..13] w_as1[h][k]; [14..23] w_ad1;
//            [24..151] w_as2[h][k] (2x64); [152..279] w_ad2.
// W2b[k][c] (bf16, 128x64) = 0.5*W2 (head-mean folded in; exact exponent shift).

__global__ __launch_bounds__(256) void prep2_kernel(
        const float* __restrict__ W1, const float* __restrict__ as1, const float* __restrict__ ad1,
        const float* __restrict__ We1, const float* __restrict__ ae1,
        const float* __restrict__ W2, const float* __restrict__ as2, const float* __restrict__ ad2,
        const float* __restrict__ We2, const float* __restrict__ ae2,
        float* __restrict__ wp, unsigned short* __restrict__ W2b) {
    int t = threadIdx.x;
    int g = t >> 6, lane = t & 63;          // g = layer*2 + h
    const float* We = (g & 2) ? We2 : We1;
    const float* ae = (g & 2) ? ae2 : ae1;
    int h = g & 1;
    float v = We[h * 64 + lane] * ae[h * 64 + lane];
    RED(v)
    if (lane == 0) wp[g] = v;
    if (t < 20) {                            // layer-1 folded vectors (2 heads x 5)
        int dd = t / 10;
        int hh = (t % 10) / 5, k = t % 5;
        const float* a = dd ? ad1 : as1;
        float s = 0.f;
        for (int c = 0; c < 64; c++) s += W1[k * 128 + hh * 64 + c] * a[hh * 64 + c];
        wp[4 + dd * 10 + hh * 5 + k] = s;
    }
    {                                        // layer-2 folded vectors (2 heads x 64) x {s,d}
        int dd = t >> 7;
        int hh = (t >> 6) & 1, k = t & 63;
        const float* a = dd ? ad2 : as2;
        float s = 0.f;
        for (int c = 0; c < 64; c++) s += W2[k * 128 + hh * 64 + c] * a[hh * 64 + c];
        wp[24 + dd * 128 + hh * 64 + k] = s;
    }
    for (int i = t; i < 128 * 64; i += 256) {  // W2b bf16, 0.5 head-mean folded (exact)
        int k = i >> 6, c = i & 63;
        W2b[i] = (unsigned short)f2bf(0.5f * W2[(k & 63) * 128 + (k & 64) + c]);
    }
}

// ---------------- layer-1 node pre-pass: logits + bf16-packed raw features ----------------

__global__ __launch_bounds__(256) void node_pre1(
        const float* __restrict__ x, const float* __restrict__ wp,
        float2* __restrict__ al_s, float2* __restrict__ al_d, uint4* __restrict__ xb1, int N) {
    int n = blockIdx.x * 256 + threadIdx.x;
    if (n >= N) return;
    float f[5];
#pragma unroll
    for (int k = 0; k < 5; k++) f[k] = x[(size_t)n * 5 + k];
    float s0 = 0.f, s1 = 0.f, d0 = 0.f, d1 = 0.f;
#pragma unroll
    for (int k = 0; k < 5; k++) {
        s0 += f[k] * wp[4 + k];   s1 += f[k] * wp[9 + k];
        d0 += f[k] * wp[14 + k];  d1 += f[k] * wp[19 + k];
    }
    al_s[n] = make_float2(s0, s1);
    al_d[n] = make_float2(d0, d1);
    uint4 p;
    p.x = (f2bf(f[1]) << 16) | f2bf(f[0]);
    p.y = (f2bf(f[3]) << 16) | f2bf(f[2]);
    p.z = f2bf(f[4]);
    p.w = 0;
    xb1[n] = p;
}

// ---------------- layer-1 edge aggregation: 2 nodes/wave, 32-lane segments ----------------
// Mean degree ~17 -> 32-lane segments double utilization; P(cnt>32) ~ 1e-4 (Poisson 16).

__global__ __launch_bounds__(256) void edge_aggr_L1(
        const int* __restrict__ row_ptr, const int2* __restrict__ col,
        const float2* __restrict__ al_s, const float2* __restrict__ al_d,
        const uint4* __restrict__ xb1, const float* __restrict__ wp,
        float* __restrict__ agg1, int N) {
    int lane = threadIdx.x & 63;
    int slane = lane & 31;
    int n = blockIdx.x * 8 + ((threadIdx.x >> 5));   // 8 segments per block
    if (n >= N) return;
    int start = row_ptr[n], end = row_ptr[n + 1];
    int cnt = end - start;
    float we0 = wp[0], we1 = wp[1];
    float2 ald = al_d[n];
    float a00 = 0.f, a01 = 0.f, a02 = 0.f, a03 = 0.f, a04 = 0.f;
    float a10 = 0.f, a11 = 0.f, a12 = 0.f, a13 = 0.f, a14 = 0.f;
    float den0 = 0.f, den1 = 0.f;

    if (cnt <= 32) {
        float v0 = -INFINITY, v1 = -INFINITY;
        int sc = 0;
        if (slane < cnt) {
            int2 ce = col[start + slane];
            sc = ce.x;
            float at = __int_as_float(ce.y);
            float2 als = al_s[sc];
            v0 = LRELU(als.x + ald.x + we0 * at);
            v1 = LRELU(als.y + ald.y + we1 * at);
        }
        float m0 = v0, m1 = v1;
        REDMAX32(m0) REDMAX32(m1)
        if (slane < cnt) {
            float e0 = __expf(v0 - m0), e1 = __expf(v1 - m1);
            uint4 p = xb1[sc];
            float f0 = bfl(p.x), f1 = bfh(p.x), f2 = bfl(p.y), f3 = bfh(p.y), f4 = bfl(p.z);
            a00 = e0 * f0; a01 = e0 * f1; a02 = e0 * f2; a03 = e0 * f3; a04 = e0 * f4;
            a10 = e1 * f0; a11 = e1 * f1; a12 = e1 * f2; a13 = e1 * f3; a14 = e1 * f4;
            den0 = e0; den1 = e1;
        }
    } else {
        float m0 = -INFINITY, m1 = -INFINITY;
        for (int i = start + slane; i < end; i += 32) {
            int2 ce = col[i];
            float at = __int_as_float(ce.y);
            float2 als = al_s[ce.x];
            m0 = fmaxf(m0, LRELU(als.x + ald.x + we0 * at));
            m1 = fmaxf(m1, LRELU(als.y + ald.y + we1 * at));
        }
        REDMAX32(m0) REDMAX32(m1)
        for (int i = start + slane; i < end; i += 32) {
            int2 ce = col[i];
            float at = __int_as_float(ce.y);
            float2 als = al_s[ce.x];
            float e0 = __expf(LRELU(als.x + ald.x + we0 * at) - m0);
            float e1 = __expf(LRELU(als.y + ald.y + we1 * at) - m1);
            uint4 p = xb1[ce.x];
            float f0 = bfl(p.x), f1 = bfh(p.x), f2 = bfl(p.y), f3 = bfh(p.y), f4 = bfl(p.z);
            a00 += e0 * f0; a01 += e0 * f1; a02 += e0 * f2; a03 += e0 * f3; a04 += e0 * f4;
            a10 += e1 * f0; a11 += e1 * f1; a12 += e1 * f2; a13 += e1 * f3; a14 += e1 * f4;
            den0 += e0; den1 += e1;
        }
    }
    RED32(a00) RED32(a01) RED32(a02) RED32(a03) RED32(a04)
    RED32(a10) RED32(a11) RED32(a12) RED32(a13) RED32(a14)
    RED32(den0) RED32(den1)
    if (slane == 0) {
        float i0 = 1.f / (den0 + 1e-16f), i1 = 1.f / (den1 + 1e-16f);
        float* o = agg1 + (size_t)n * 10;
        o[0] = a00 * i0; o[1] = a01 * i0; o[2] = a02 * i0; o[3] = a03 * i0; o[4] = a04 * i0;
        o[5] = a10 * i1; o[6] = a11 * i1; o[7] = a12 * i1; o[8] = a13 * i1; o[9] = a14 * i1;
    }
}

// ---------------- layer-1 projection (post-aggregation) + layer-2 logits + packing ----------

__global__ __launch_bounds__(256) void proj1_kernel(
        const float* __restrict__ agg1, const float* __restrict__ W1, const float* __restrict__ b1,
        const float* __restrict__ wp,
        float2* __restrict__ al_s2, float2* __restrict__ al_d2, u32* __restrict__ xb2, int N) {
    int lane = threadIdx.x & 63;
    int n = blockIdx.x * 4 + (threadIdx.x >> 6);
    if (n >= N) return;
    const float* ag = agg1 + (size_t)n * 10;
    float s0 = 0.f, s1 = 0.f;
#pragma unroll
    for (int k = 0; k < 5; k++) {
        s0 += ag[k] * W1[k * 128 + lane];
        s1 += ag[5 + k] * W1[k * 128 + 64 + lane];
    }
    float h = fmaxf(0.5f * (s0 + s1) + b1[lane], 0.f);
    float r0 = h * wp[24 + lane], r1 = h * wp[88 + lane];
    float r2 = h * wp[152 + lane], r3 = h * wp[216 + lane];
    RED(r0) RED(r1) RED(r2) RED(r3)
    if (lane == 0) {
        al_s2[n] = make_float2(r0, r1);
        al_d2[n] = make_float2(r2, r3);
    }
    float hi = __shfl_down(h, 1);
    if (!(lane & 1)) xb2[(size_t)n * 32 + (lane >> 1)] = (f2bf(hi) << 16) | f2bf(h);
}

// ---------------- layer-2 edge aggregation: gather 128B bf16 rows; bf16 packed output ------
// agg2b[n] = 64 u32 words = 128 bf16: k 0..63 head0 aggregate, 64..127 head1.

__global__ __launch_bounds__(256) void edge_aggr_L2(
        const int* __restrict__ row_ptr, const int2* __restrict__ col,
        const float2* __restrict__ al_s, const float2* __restrict__ al_d,
        const u32* __restrict__ xb2, const float* __restrict__ wp,
        u32* __restrict__ agg2b, int N) {
    __shared__ float s_e0[4][64], s_e1[4][64];
    __shared__ int s_src[4][64];
    int wid = threadIdx.x >> 6;
    int lane = threadIdx.x & 63;
    int n = blockIdx.x * 4 + wid;
    if (n >= N) return;
    int start = row_ptr[n], end = row_ptr[n + 1];
    int cnt = end - start;
    float we0 = wp[2], we1 = wp[3];
    float2 ald = al_d[n];
    bool lo = lane < 32;
    int word = lane & 31;
    float accx = 0.f, accy = 0.f, den0 = 0.f, den1 = 0.f;

    if (cnt <= 64) {
        float v0 = -INFINITY, v1 = -INFINITY;
        int sc = 0;
        if (lane < cnt) {
            int2 ce = col[start + lane];
            sc = ce.x;
            float at = __int_as_float(ce.y);
            float2 als = al_s[sc];
            v0 = LRELU(als.x + ald.x + we0 * at);
            v1 = LRELU(als.y + ald.y + we1 * at);
        }
        float m0 = v0, m1 = v1;
        REDMAX(m0) REDMAX(m1)
        float e0 = 0.f, e1 = 0.f;
        if (lane < cnt) {
            e0 = __expf(v0 - m0);
            e1 = __expf(v1 - m1);
        }
        den0 = e0; den1 = e1;
        s_e0[wid][lane] = e0; s_e1[wid][lane] = e1; s_src[wid][lane] = sc;
        // no barrier: same-wave LDS write->read

        const float* s_w = lo ? s_e0[wid] : s_e1[wid];
#pragma unroll 4
        for (int j = 0; j < cnt; j++) {
            float w = s_w[j];
            u32 v = xb2[(size_t)s_src[wid][j] * 32 + word];
            accx += w * bfl(v);
            accy += w * bfh(v);
        }
    } else {
        float m0 = -INFINITY, m1 = -INFINITY;
        for (int i = start + lane; i < end; i += 64) {
            int2 ce = col[i];
            float at = __int_as_float(ce.y);
            float2 als = al_s[ce.x];
            m0 = fmaxf(m0, LRELU(als.x + ald.x + we0 * at));
            m1 = fmaxf(m1, LRELU(als.y + ald.y + we1 * at));
        }
        REDMAX(m0) REDMAX(m1)
        const float* s_w = lo ? s_e0[wid] : s_e1[wid];
        for (int cs = start; cs < end; cs += 64) {
            int i = cs + lane;
            float e0 = 0.f, e1 = 0.f;
            int sc = 0;
            if (i < end) {
                int2 ce = col[i];
                sc = ce.x;
                float at = __int_as_float(ce.y);
                float2 als = al_s[sc];
                e0 = __expf(LRELU(als.x + ald.x + we0 * at) - m0);
                e1 = __expf(LRELU(als.y + ald.y + we1 * at) - m1);
            }
            den0 += e0; den1 += e1;
            s_e0[wid][lane] = e0; s_e1[wid][lane] = e1; s_src[wid][lane] = sc;
            int c2 = min(64, end - cs);
#pragma unroll 4
            for (int j = 0; j < c2; j++) {
                float w = s_w[j];
                u32 v = xb2[(size_t)s_src[wid][j] * 32 + word];
                accx += w * bfl(v);
                accy += w * bfh(v);
            }
        }
    }
    RED(den0) RED(den1)
    float inv = lo ? 1.f / (den0 + 1e-16f) : 1.f / (den1 + 1e-16f);
    agg2b[(size_t)n * 64 + (lo ? 0 : 32) + word] =
        (f2bf(accy * inv) << 16) | f2bf(accx * inv);
}

// ---------------- layer-2 projection + relu + pooling: MFMA GEMM [N x128]x[128 x64] ----------
// Wave per 16-node strip. B (0.5*W2 bf16) in 16 register fragments (loaded once).
// Layouts (16x16x32): A row=lane&15, k=8*(lane>>4)+r; C/D col=lane&15, row=(lane>>4)*4+reg.

__global__ __launch_bounds__(256) void proj2_pool_mfma(
        const u32* __restrict__ agg2b, const unsigned short* __restrict__ W2b,
        const float* __restrict__ b2, const float* __restrict__ Wlin,
        const int* __restrict__ batch,
        float* __restrict__ pool_sum, int* __restrict__ pool_cnt, int N) {
    __shared__ float s_sum[64];
    __shared__ int s_cnt[64];
    int t = threadIdx.x;
    int wid = t >> 6, lane = t & 63;
    if (t < 64) { s_sum[t] = 0.f; s_cnt[t] = 0; }
    __syncthreads();

    int sub = lane >> 4, cc = lane & 15;

    short8v bfrag[4][4];
#pragma unroll
    for (int tl = 0; tl < 4; tl++)
#pragma unroll
        for (int kk = 0; kk < 4; kk++)
#pragma unroll
            for (int r = 0; r < 8; r++)
                bfrag[tl][kk][r] = (short)W2b[(kk * 32 + 8 * sub + r) * 64 + tl * 16 + cc];

    float b2v[4], wlv[4];
#pragma unroll
    for (int tl = 0; tl < 4; tl++) {
        b2v[tl] = b2[tl * 16 + cc];
        wlv[tl] = Wlin[tl * 16 + cc];
    }

    int nstrips = (N + 15) >> 4;
    for (int strip = blockIdx.x * 4 + wid; strip < nstrips; strip += gridDim.x * 4) {
        int n0 = strip << 4;
        int arow = min(n0 + cc, N - 1);     // lane's A row (clamped in tail strip)
        const uint4* ap = (const uint4*)agg2b;
        short8v a[4];
#pragma unroll
        for (int kk = 0; kk < 4; kk++) {    // row = 16 uint4; kk-block has 4, take sub-th
            uint4 raw = ap[(size_t)arow * 16 + kk * 4 + sub];
            a[kk] = *(const short8v*)&raw;
        }

        f32x4 acc0 = {0.f, 0.f, 0.f, 0.f}, acc1 = acc0, acc2 = acc0, acc3 = acc0;
#pragma unroll
        for (int kk = 0; kk < 4; kk++) {
            acc0 = __builtin_amdgcn_mfma_f32_16x16x32_bf16(a[kk], bfrag[0][kk], acc0, 0, 0, 0);
            acc1 = __builtin_amdgcn_mfma_f32_16x16x32_bf16(a[kk], bfrag[1][kk], acc1, 0, 0, 0);
            acc2 = __builtin_amdgcn_mfma_f32_16x16x32_bf16(a[kk], bfrag[2][kk], acc2, 0, 0, 0);
            acc3 = __builtin_amdgcn_mfma_f32_16x16x32_bf16(a[kk], bfrag[3][kk], acc3, 0, 0, 0);
        }

#pragma unroll
        for (int r = 0; r < 4; r++) {
            float p = fmaxf(acc0[r] + b2v[0], 0.f) * wlv[0]
                    + fmaxf(acc1[r] + b2v[1], 0.f) * wlv[1]
                    + fmaxf(acc2[r] + b2v[2], 0.f) * wlv[2]
                    + fmaxf(acc3[r] + b2v[3], 0.f) * wlv[3];
#pragma unroll
            for (int m = 8; m >= 1; m >>= 1) p += __shfl_xor(p, m);
            if (cc == 0) {
                int node = n0 + sub * 4 + r;
                if (node < N) {
                    int g = batch[node];
                    atomicAdd(&s_sum[g], p);
                    atomicAdd(&s_cnt[g], 1);
                }
            }
        }
    }
    __syncthreads();
    if (t < 64 && s_cnt[t] > 0) {
        atomicAdd(&pool_sum[t], s_sum[t]);
        atomicAdd(&pool_cnt[t], s_cnt[t]);
    }
}

__global__ void final_kernel(const float* __restrict__ pool_sum, const int* __restrict__ pool_cnt,
                             const float* __restrict__ blin, float* __restrict__ out) {
    int g = threadIdx.x;
    if (g < 64) out[g] = pool_sum[g] / fmaxf((float)pool_cnt[g], 1.f) + blin[0];
}

// ---------------- launch ----------------

extern "C" void kernel_launch(void* const* d_in, const int* in_sizes, int n_in,
                              void* d_out, int out_size, void* d_ws, size_t ws_size,
                              hipStream_t stream) {
    const float* x     = (const float*)d_in[0];
    const int*   ei    = (const int*)d_in[1];
    const float* eattr = (const float*)d_in[2];
    const int*   batch = (const int*)d_in[3];
    const float* W1  = (const float*)d_in[4];
    const float* as1 = (const float*)d_in[5];
    const float* ad1 = (const float*)d_in[6];
    const float* We1 = (const float*)d_in[7];
    const float* ae1 = (const float*)d_in[8];
    const float* b1  = (const float*)d_in[9];
    const float* W2  = (const float*)d_in[10];
    const float* as2 = (const float*)d_in[11];
    const float* ad2 = (const float*)d_in[12];
    const float* We2 = (const float*)d_in[13];
    const float* ae2 = (const float*)d_in[14];
    const float* b2  = (const float*)d_in[15];
    const float* Wlin = (const float*)d_in[16];
    const float* blin = (const float*)d_in[17];
    float* out = (float*)d_out;

    int N = in_sizes[0] / 5;
    int E = in_sizes[1] / 2;
    size_t EP = (size_t)E + N;
    const int* src0 = ei;
    const int* dst0 = ei + E;
    int B = (N + 255) / 256;

    char* ws = (char*)d_ws;
    size_t off = 0;
    auto alloc = [&](size_t bytes) {
        void* p = ws + off;
        off = (off + bytes + 255) & ~(size_t)255;
        return p;
    };
    unsigned long long* hist = (unsigned long long*)alloc((size_t)N * 8);
    int*    row_ptr  = (int*)   alloc((size_t)(N + 1) * 4);
    int*    pos      = (int*)   alloc((size_t)E * 4);
    int2*   col      = (int2*)  alloc(EP * 8);
    int*    block_sum= (int*)   alloc((size_t)1024 * 4);
    int*    block_off= (int*)   alloc((size_t)1024 * 4);
    float*  wp       = (float*) alloc(280 * 4);
    unsigned short* W2b = (unsigned short*)alloc((size_t)128 * 64 * 2);
    float2* al_s1    = (float2*)alloc((size_t)N * 8);
    float2* al_d1    = (float2*)alloc((size_t)N * 8);
    uint4*  xb1      = (uint4*) alloc((size_t)N * 16);
    float*  agg1     = (float*) alloc((size_t)N * 10 * 4);
    float2* al_s2    = (float2*)alloc((size_t)N * 8);
    float2* al_d2    = (float2*)alloc((size_t)N * 8);
    u32*    xb2      = (u32*)   alloc((size_t)N * 32 * 4);
    u32*    agg2b    = (u32*)   alloc((size_t)N * 64 * 4);
    float*  pool_sum = (float*) alloc(64 * 4);
    int*    pool_cnt = (int*)   alloc(64 * 4);

    hipMemsetAsync(hist, 0, (size_t)N * 8, stream);
    hipMemsetAsync(block_sum, 0, (size_t)1024 * 4, stream);
    hipMemsetAsync(pool_sum, 0, 64 * 4, stream);
    hipMemsetAsync(pool_cnt, 0, 64 * 4, stream);

    hist_pos_kernel<<<(E + 255) / 256, 256, 0, stream>>>(dst0, eattr, hist, pos, E);
    scan_phase1<<<B, 256, 0, stream>>>(hist, block_sum, N);
    scan_phase2<<<1, 1024, 0, stream>>>(block_sum, block_off, row_ptr, B, N);
    scan_phase3<<<B, 256, 0, stream>>>(hist, block_off, row_ptr, col, N);
    place_kernel<<<(E + 255) / 256, 256, 0, stream>>>(src0, dst0, eattr, row_ptr, pos, col, E);
    prep2_kernel<<<1, 256, 0, stream>>>(W1, as1, ad1, We1, ae1, W2, as2, ad2, We2, ae2, wp, W2b);

    int eab = (N + 3) / 4;                  // 4 waves per block, wave per node (L2)
    int eab1 = (N + 7) / 8;                 // 8 segments per block, 2 nodes/wave (L1)

    // layer 1: aggregate raw 5-dim features, then project
    node_pre1<<<B, 256, 0, stream>>>(x, wp, al_s1, al_d1, xb1, N);
    edge_aggr_L1<<<eab1, 256, 0, stream>>>(row_ptr, col, al_s1, al_d1, xb1, wp, agg1, N);
    proj1_kernel<<<eab, 256, 0, stream>>>(agg1, W1, b1, wp, al_s2, al_d2, xb2, N);
    // layer 2: aggregate 64-dim feat1 (bf16 out), then MFMA projection + pool
    edge_aggr_L2<<<eab, 256, 0, stream>>>(row_ptr, col, al_s2, al_d2, xb2, wp, agg2b, N);
    int nstrips = (N + 15) / 16;
    proj2_pool_mfma<<<(nstrips + 3) / 4, 256, 0, stream>>>(agg2b, W2b, b2, Wlin, batch,
                                                           pool_sum, pool_cnt, N);
    final_kernel<<<1, 64, 0, stream>>>(pool_sum, pool_cnt, blin, out);
}

// Round 21
// 162.000 us; speedup vs baseline: 1.7416x; 1.0586x over previous
//
#include <hip/hip_runtime.h>
#include <hip/hip_bf16.h>
#include <math.h>

typedef unsigned int u32;
typedef __attribute__((ext_vector_type(8))) short short8v;   // 8 bf16 = 4 VGPRs
typedef __attribute__((ext_vector_type(4))) float f32x4;

#define LRELU(a) ((a) > 0.f ? (a) : 0.2f * (a))

#define FIX_SCALE 67108864.0f          // 2^26 fixed-point for attr sums
#define FIX_INV   (1.0f / 67108864.0f)
#define CNT_SHIFT 40
#define SUM_MASK  0xFFFFFFFFFFULL

// round-to-nearest-even f32 -> bf16 bits
__device__ __forceinline__ u32 f2bf(float f) {
    u32 u = __float_as_uint(f);
    return (u + 0x7fffu + ((u >> 16) & 1u)) >> 16;
}
__device__ __forceinline__ float bfl(u32 w) { return __uint_as_float(w << 16); }
__device__ __forceinline__ float bfh(u32 w) { return __uint_as_float(w & 0xffff0000u); }

#define RED(x) _Pragma("unroll") for (int m_ = 32; m_ >= 1; m_ >>= 1) x += __shfl_xor(x, m_);
#define REDMAX(x) _Pragma("unroll") for (int m_ = 32; m_ >= 1; m_ >>= 1) x = fmaxf(x, __shfl_xor(x, m_));
// 32-lane-segment variants (masks <=16 stay within each half-wave)
#define RED32(x) _Pragma("unroll") for (int m_ = 16; m_ >= 1; m_ >>= 1) x += __shfl_xor(x, m_);
#define REDMAX32(x) _Pragma("unroll") for (int m_ = 16; m_ >= 1; m_ >>= 1) x = fmaxf(x, __shfl_xor(x, m_));

// ---------------- CSR build (unchanged; passed) ----------------

__global__ void hist_pos_kernel(const int* __restrict__ dst, const float* __restrict__ eattr,
                                unsigned long long* __restrict__ hist, int* __restrict__ pos, int E) {
    int e = blockIdx.x * blockDim.x + threadIdx.x;
    if (e < E) {
        int d = dst[e];
        unsigned long long v = (1ULL << CNT_SHIFT) |
                               (unsigned long long)(eattr[e] * FIX_SCALE + 0.5f);
        unsigned long long old = atomicAdd(&hist[d], v);
        pos[e] = (int)(old >> CNT_SHIFT);
    }
}

__global__ __launch_bounds__(256) void scan_phase1(const unsigned long long* __restrict__ hist,
                                                   int* __restrict__ block_sum, int N) {
    int t = threadIdx.x;
    int n = blockIdx.x * 256 + t;
    int v = (n < N) ? (int)(hist[n] >> CNT_SHIFT) + 1 : 0;  // +1 self loop
    RED(v)
    __shared__ int ws[4];
    if ((t & 63) == 0) ws[t >> 6] = v;
    __syncthreads();
    if (t == 0) block_sum[blockIdx.x] = ws[0] + ws[1] + ws[2] + ws[3];
}

__global__ __launch_bounds__(1024) void scan_phase2(const int* __restrict__ block_sum,
                                                    int* __restrict__ block_off,
                                                    int* __restrict__ row_ptr, int B, int N) {
    __shared__ int s[1024];
    int t = threadIdx.x;
    int v = (t < B) ? block_sum[t] : 0;
    s[t] = v;
    __syncthreads();
    for (int off = 1; off < 1024; off <<= 1) {
        int u = (t >= off) ? s[t - off] : 0;
        __syncthreads();
        s[t] += u;
        __syncthreads();
    }
    if (t < B) block_off[t] = s[t] - v;
    if (t == 1023) row_ptr[N] = s[1023];
}

__global__ __launch_bounds__(256) void scan_phase3(const unsigned long long* __restrict__ hist,
                                                   const int* __restrict__ block_off,
                                                   int* __restrict__ row_ptr,
                                                   int2* __restrict__ col, int N) {
    int t = threadIdx.x;
    int lane = t & 63;
    int n = blockIdx.x * 256 + t;
    unsigned long long hv = (n < N) ? hist[n] : 0ULL;
    int c = (n < N) ? (int)(hv >> CNT_SHIFT) + 1 : 0;
    int v = c;
#pragma unroll
    for (int m = 1; m < 64; m <<= 1) {
        int u = __shfl_up(v, m);
        if (lane >= m) v += u;
    }
    __shared__ int wsum[4];
    if (lane == 63) wsum[t >> 6] = v;
    __syncthreads();
    int w = t >> 6;
    int wadd = 0;
#pragma unroll
    for (int i = 0; i < 3; i++) wadd += (i < w) ? wsum[i] : 0;
    int base = block_off[blockIdx.x] + wadd + v - c;
    if (n < N) {
        row_ptr[n] = base;
        float asum = (float)(hv & SUM_MASK) * FIX_INV;
        float la = asum / fmaxf((float)(c - 1), 1.f);
        col[base] = make_int2(n, __float_as_int(la));   // self loop first in row
    }
}

__global__ void place_kernel(const int* __restrict__ src, const int* __restrict__ dst,
                             const float* __restrict__ eattr, const int* __restrict__ row_ptr,
                             const int* __restrict__ pos, int2* __restrict__ col, int E) {
    int e = blockIdx.x * blockDim.x + threadIdx.x;
    if (e < E) {
        int d = dst[e];
        col[row_ptr[d] + 1 + pos[e]] = make_int2(src[e], __float_as_int(eattr[e]));
    }
}

// ---------------- prep: we_dot scalars + folded attention vectors + bf16 W2b ----------------
// wp layout: [0..3] we_dot(layer,h); [4..13] w_as1[h][k]; [14..23] w_ad1;
//            [24..151] w_as2[h][k] (2x64); [152..279] w_ad2.
// W2b[k][c] (bf16, 128x64) = 0.5*W2 (head-mean folded in; exact exponent shift).

__global__ __launch_bounds__(256) void prep2_kernel(
        const float* __restrict__ W1, const float* __restrict__ as1, const float* __restrict__ ad1,
        const float* __restrict__ We1, const float* __restrict__ ae1,
        const float* __restrict__ W2, const float* __restrict__ as2, const float* __restrict__ ad2,
        const float* __restrict__ We2, const float* __restrict__ ae2,
        float* __restrict__ wp, unsigned short* __restrict__ W2b) {
    int t = threadIdx.x;
    int g = t >> 6, lane = t & 63;          // g = layer*2 + h
    const float* We = (g & 2) ? We2 : We1;
    const float* ae = (g & 2) ? ae2 : ae1;
    int h = g & 1;
    float v = We[h * 64 + lane] * ae[h * 64 + lane];
    RED(v)
    if (lane == 0) wp[g] = v;
    if (t < 20) {                            // layer-1 folded vectors (2 heads x 5)
        int dd = t / 10;
        int hh = (t % 10) / 5, k = t % 5;
        const float* a = dd ? ad1 : as1;
        float s = 0.f;
        for (int c = 0; c < 64; c++) s += W1[k * 128 + hh * 64 + c] * a[hh * 64 + c];
        wp[4 + dd * 10 + hh * 5 + k] = s;
    }
    {                                        // layer-2 folded vectors (2 heads x 64) x {s,d}
        int dd = t >> 7;
        int hh = (t >> 6) & 1, k = t & 63;
        const float* a = dd ? ad2 : as2;
        float s = 0.f;
        for (int c = 0; c < 64; c++) s += W2[k * 128 + hh * 64 + c] * a[hh * 64 + c];
        wp[24 + dd * 128 + hh * 64 + k] = s;
    }
    for (int i = t; i < 128 * 64; i += 256) {  // W2b bf16, 0.5 head-mean folded (exact)
        int k = i >> 6, c = i & 63;
        W2b[i] = (unsigned short)f2bf(0.5f * W2[(k & 63) * 128 + (k & 64) + c]);
    }
}

// ---------------- layer-1 node pre-pass: logits + bf16-packed raw features ----------------

__global__ __launch_bounds__(256) void node_pre1(
        const float* __restrict__ x, const float* __restrict__ wp,
        float2* __restrict__ al_s, float2* __restrict__ al_d, uint4* __restrict__ xb1, int N) {
    int n = blockIdx.x * 256 + threadIdx.x;
    if (n >= N) return;
    float f[5];
#pragma unroll
    for (int k = 0; k < 5; k++) f[k] = x[(size_t)n * 5 + k];
    float s0 = 0.f, s1 = 0.f, d0 = 0.f, d1 = 0.f;
#pragma unroll
    for (int k = 0; k < 5; k++) {
        s0 += f[k] * wp[4 + k];   s1 += f[k] * wp[9 + k];
        d0 += f[k] * wp[14 + k];  d1 += f[k] * wp[19 + k];
    }
    al_s[n] = make_float2(s0, s1);
    al_d[n] = make_float2(d0, d1);
    uint4 p;
    p.x = (f2bf(f[1]) << 16) | f2bf(f[0]);
    p.y = (f2bf(f[3]) << 16) | f2bf(f[2]);
    p.z = f2bf(f[4]);
    p.w = 0;
    xb1[n] = p;
}

// ---------------- layer-1 edge aggregation: 2 nodes/wave, 32-lane segments ----------------
// Mean degree ~17 -> 32-lane segments double utilization; P(cnt>32) ~ 1e-4 (Poisson 16).

__global__ __launch_bounds__(256) void edge_aggr_L1(
        const int* __restrict__ row_ptr, const int2* __restrict__ col,
        const float2* __restrict__ al_s, const float2* __restrict__ al_d,
        const uint4* __restrict__ xb1, const float* __restrict__ wp,
        float* __restrict__ agg1, int N) {
    int lane = threadIdx.x & 63;
    int slane = lane & 31;
    int n = blockIdx.x * 8 + ((threadIdx.x >> 5));   // 8 segments per block
    if (n >= N) return;
    int start = row_ptr[n], end = row_ptr[n + 1];
    int cnt = end - start;
    float we0 = wp[0], we1 = wp[1];
    float2 ald = al_d[n];
    float a00 = 0.f, a01 = 0.f, a02 = 0.f, a03 = 0.f, a04 = 0.f;
    float a10 = 0.f, a11 = 0.f, a12 = 0.f, a13 = 0.f, a14 = 0.f;
    float den0 = 0.f, den1 = 0.f;

    if (cnt <= 32) {
        float v0 = -INFINITY, v1 = -INFINITY;
        int sc = 0;
        if (slane < cnt) {
            int2 ce = col[start + slane];
            sc = ce.x;
            float at = __int_as_float(ce.y);
            float2 als = al_s[sc];
            v0 = LRELU(als.x + ald.x + we0 * at);
            v1 = LRELU(als.y + ald.y + we1 * at);
        }
        float m0 = v0, m1 = v1;
        REDMAX32(m0) REDMAX32(m1)
        if (slane < cnt) {
            float e0 = __expf(v0 - m0), e1 = __expf(v1 - m1);
            uint4 p = xb1[sc];
            float f0 = bfl(p.x), f1 = bfh(p.x), f2 = bfl(p.y), f3 = bfh(p.y), f4 = bfl(p.z);
            a00 = e0 * f0; a01 = e0 * f1; a02 = e0 * f2; a03 = e0 * f3; a04 = e0 * f4;
            a10 = e1 * f0; a11 = e1 * f1; a12 = e1 * f2; a13 = e1 * f3; a14 = e1 * f4;
            den0 = e0; den1 = e1;
        }
    } else {
        float m0 = -INFINITY, m1 = -INFINITY;
        for (int i = start + slane; i < end; i += 32) {
            int2 ce = col[i];
            float at = __int_as_float(ce.y);
            float2 als = al_s[ce.x];
            m0 = fmaxf(m0, LRELU(als.x + ald.x + we0 * at));
            m1 = fmaxf(m1, LRELU(als.y + ald.y + we1 * at));
        }
        REDMAX32(m0) REDMAX32(m1)
        for (int i = start + slane; i < end; i += 32) {
            int2 ce = col[i];
            float at = __int_as_float(ce.y);
            float2 als = al_s[ce.x];
            float e0 = __expf(LRELU(als.x + ald.x + we0 * at) - m0);
            float e1 = __expf(LRELU(als.y + ald.y + we1 * at) - m1);
            uint4 p = xb1[ce.x];
            float f0 = bfl(p.x), f1 = bfh(p.x), f2 = bfl(p.y), f3 = bfh(p.y), f4 = bfl(p.z);
            a00 += e0 * f0; a01 += e0 * f1; a02 += e0 * f2; a03 += e0 * f3; a04 += e0 * f4;
            a10 += e1 * f0; a11 += e1 * f1; a12 += e1 * f2; a13 += e1 * f3; a14 += e1 * f4;
            den0 += e0; den1 += e1;
        }
    }
    RED32(a00) RED32(a01) RED32(a02) RED32(a03) RED32(a04)
    RED32(a10) RED32(a11) RED32(a12) RED32(a13) RED32(a14)
    RED32(den0) RED32(den1)
    if (slane == 0) {
        float i0 = 1.f / (den0 + 1e-16f), i1 = 1.f / (den1 + 1e-16f);
        float* o = agg1 + (size_t)n * 10;
        o[0] = a00 * i0; o[1] = a01 * i0; o[2] = a02 * i0; o[3] = a03 * i0; o[4] = a04 * i0;
        o[5] = a10 * i1; o[6] = a11 * i1; o[7] = a12 * i1; o[8] = a13 * i1; o[9] = a14 * i1;
    }
}

// ---------------- layer-1 projection (post-aggregation) + layer-2 logits + packing ----------

__global__ __launch_bounds__(256) void proj1_kernel(
        const float* __restrict__ agg1, const float* __restrict__ W1, const float* __restrict__ b1,
        const float* __restrict__ wp,
        float2* __restrict__ al_s2, float2* __restrict__ al_d2, u32* __restrict__ xb2, int N) {
    int lane = threadIdx.x & 63;
    int n = blockIdx.x * 4 + (threadIdx.x >> 6);
    if (n >= N) return;
    const float* ag = agg1 + (size_t)n * 10;
    float s0 = 0.f, s1 = 0.f;
#pragma unroll
    for (int k = 0; k < 5; k++) {
        s0 += ag[k] * W1[k * 128 + lane];
        s1 += ag[5 + k] * W1[k * 128 + 64 + lane];
    }
    float h = fmaxf(0.5f * (s0 + s1) + b1[lane], 0.f);
    float r0 = h * wp[24 + lane], r1 = h * wp[88 + lane];
    float r2 = h * wp[152 + lane], r3 = h * wp[216 + lane];
    RED(r0) RED(r1) RED(r2) RED(r3)
    if (lane == 0) {
        al_s2[n] = make_float2(r0, r1);
        al_d2[n] = make_float2(r2, r3);
    }
    float hi = __shfl_down(h, 1);
    if (!(lane & 1)) xb2[(size_t)n * 32 + (lane >> 1)] = (f2bf(hi) << 16) | f2bf(h);
}

// ---------------- layer-2 edge aggregation: 2 nodes/wave, 32-lane segments ----------------
// Lane w owns row word w (channels {2w,2w+1}) and applies BOTH head weights (4 FMA/load):
// halves load instructions (no duplicate word reads) and wave-slots per node.
// agg2b[n] = 64 u32 words = 128 bf16: words 0..31 head0 aggregate, 32..63 head1.

__global__ __launch_bounds__(256) void edge_aggr_L2(
        const int* __restrict__ row_ptr, const int2* __restrict__ col,
        const float2* __restrict__ al_s, const float2* __restrict__ al_d,
        const u32* __restrict__ xb2, const float* __restrict__ wp,
        u32* __restrict__ agg2b, int N) {
    __shared__ float s_e0[8][32], s_e1[8][32];
    __shared__ int s_src[8][32];
    int seg = threadIdx.x >> 5;      // 0..7
    int slane = threadIdx.x & 31;
    int n = blockIdx.x * 8 + seg;
    if (n >= N) return;
    int start = row_ptr[n], end = row_ptr[n + 1];
    int cnt = end - start;
    float we0 = wp[2], we1 = wp[3];
    float2 ald = al_d[n];
    float ax0 = 0.f, ay0 = 0.f, ax1 = 0.f, ay1 = 0.f, den0 = 0.f, den1 = 0.f;

    if (cnt <= 32) {
        float v0 = -INFINITY, v1 = -INFINITY;
        int sc = 0;
        if (slane < cnt) {
            int2 ce = col[start + slane];
            sc = ce.x;
            float at = __int_as_float(ce.y);
            float2 als = al_s[sc];
            v0 = LRELU(als.x + ald.x + we0 * at);
            v1 = LRELU(als.y + ald.y + we1 * at);
        }
        float m0 = v0, m1 = v1;
        REDMAX32(m0) REDMAX32(m1)
        float e0 = 0.f, e1 = 0.f;
        if (slane < cnt) {
            e0 = __expf(v0 - m0);
            e1 = __expf(v1 - m1);
        }
        den0 = e0; den1 = e1;
        s_e0[seg][slane] = e0; s_e1[seg][slane] = e1; s_src[seg][slane] = sc;
        // no barrier: same-wave LDS write->read, lockstep

#pragma unroll 4
        for (int j = 0; j < cnt; j++) {
            float w0 = s_e0[seg][j], w1 = s_e1[seg][j];
            u32 v = xb2[(size_t)s_src[seg][j] * 32 + slane];
            float lo = bfl(v), hi = bfh(v);
            ax0 += w0 * lo; ay0 += w0 * hi;
            ax1 += w1 * lo; ay1 += w1 * hi;
        }
    } else {
        float m0 = -INFINITY, m1 = -INFINITY;
        for (int i = start + slane; i < end; i += 32) {
            int2 ce = col[i];
            float at = __int_as_float(ce.y);
            float2 als = al_s[ce.x];
            m0 = fmaxf(m0, LRELU(als.x + ald.x + we0 * at));
            m1 = fmaxf(m1, LRELU(als.y + ald.y + we1 * at));
        }
        REDMAX32(m0) REDMAX32(m1)
        for (int cs = start; cs < end; cs += 32) {
            int i = cs + slane;
            float e0 = 0.f, e1 = 0.f;
            int sc = 0;
            if (i < end) {
                int2 ce = col[i];
                sc = ce.x;
                float at = __int_as_float(ce.y);
                float2 als = al_s[sc];
                e0 = __expf(LRELU(als.x + ald.x + we0 * at) - m0);
                e1 = __expf(LRELU(als.y + ald.y + we1 * at) - m1);
            }
            den0 += e0; den1 += e1;
            s_e0[seg][slane] = e0; s_e1[seg][slane] = e1; s_src[seg][slane] = sc;
            int c2 = min(32, end - cs);
#pragma unroll 4
            for (int j = 0; j < c2; j++) {
                float w0 = s_e0[seg][j], w1 = s_e1[seg][j];
                u32 v = xb2[(size_t)s_src[seg][j] * 32 + slane];
                float lo = bfl(v), hi = bfh(v);
                ax0 += w0 * lo; ay0 += w0 * hi;
                ax1 += w1 * lo; ay1 += w1 * hi;
            }
        }
    }
    RED32(den0) RED32(den1)
    float i0 = 1.f / (den0 + 1e-16f), i1 = 1.f / (den1 + 1e-16f);
    agg2b[(size_t)n * 64 + slane]      = (f2bf(ay0 * i0) << 16) | f2bf(ax0 * i0);
    agg2b[(size_t)n * 64 + 32 + slane] = (f2bf(ay1 * i1) << 16) | f2bf(ax1 * i1);
}

// ---------------- layer-2 projection + relu + pooling: MFMA GEMM [N x128]x[128 x64] ----------
// Wave per 16-node strip. B (0.5*W2 bf16) in 16 register fragments (loaded once).
// Layouts (16x16x32): A row=lane&15, k=8*(lane>>4)+r; C/D col=lane&15, row=(lane>>4)*4+reg.

__global__ __launch_bounds__(256) void proj2_pool_mfma(
        const u32* __restrict__ agg2b, const unsigned short* __restrict__ W2b,
        const float* __restrict__ b2, const float* __restrict__ Wlin,
        const int* __restrict__ batch,
        float* __restrict__ pool_sum, int* __restrict__ pool_cnt, int N) {
    __shared__ float s_sum[64];
    __shared__ int s_cnt[64];
    int t = threadIdx.x;
    int wid = t >> 6, lane = t & 63;
    if (t < 64) { s_sum[t] = 0.f; s_cnt[t] = 0; }
    __syncthreads();

    int sub = lane >> 4, cc = lane & 15;

    short8v bfrag[4][4];
#pragma unroll
    for (int tl = 0; tl < 4; tl++)
#pragma unroll
        for (int kk = 0; kk < 4; kk++)
#pragma unroll
            for (int r = 0; r < 8; r++)
                bfrag[tl][kk][r] = (short)W2b[(kk * 32 + 8 * sub + r) * 64 + tl * 16 + cc];

    float b2v[4], wlv[4];
#pragma unroll
    for (int tl = 0; tl < 4; tl++) {
        b2v[tl] = b2[tl * 16 + cc];
        wlv[tl] = Wlin[tl * 16 + cc];
    }

    int nstrips = (N + 15) >> 4;
    for (int strip = blockIdx.x * 4 + wid; strip < nstrips; strip += gridDim.x * 4) {
        int n0 = strip << 4;
        int arow = min(n0 + cc, N - 1);     // lane's A row (clamped in tail strip)
        const uint4* ap = (const uint4*)agg2b;
        short8v a[4];
#pragma unroll
        for (int kk = 0; kk < 4; kk++) {    // row = 16 uint4; kk-block has 4, take sub-th
            uint4 raw = ap[(size_t)arow * 16 + kk * 4 + sub];
            a[kk] = *(const short8v*)&raw;
        }

        f32x4 acc0 = {0.f, 0.f, 0.f, 0.f}, acc1 = acc0, acc2 = acc0, acc3 = acc0;
#pragma unroll
        for (int kk = 0; kk < 4; kk++) {
            acc0 = __builtin_amdgcn_mfma_f32_16x16x32_bf16(a[kk], bfrag[0][kk], acc0, 0, 0, 0);
            acc1 = __builtin_amdgcn_mfma_f32_16x16x32_bf16(a[kk], bfrag[1][kk], acc1, 0, 0, 0);
            acc2 = __builtin_amdgcn_mfma_f32_16x16x32_bf16(a[kk], bfrag[2][kk], acc2, 0, 0, 0);
            acc3 = __builtin_amdgcn_mfma_f32_16x16x32_bf16(a[kk], bfrag[3][kk], acc3, 0, 0, 0);
        }

#pragma unroll
        for (int r = 0; r < 4; r++) {
            float p = fmaxf(acc0[r] + b2v[0], 0.f) * wlv[0]
                    + fmaxf(acc1[r] + b2v[1], 0.f) * wlv[1]
                    + fmaxf(acc2[r] + b2v[2], 0.f) * wlv[2]
                    + fmaxf(acc3[r] + b2v[3], 0.f) * wlv[3];
#pragma unroll
            for (int m = 8; m >= 1; m >>= 1) p += __shfl_xor(p, m);
            if (cc == 0) {
                int node = n0 + sub * 4 + r;
                if (node < N) {
                    int g = batch[node];
                    atomicAdd(&s_sum[g], p);
                    atomicAdd(&s_cnt[g], 1);
                }
            }
        }
    }
    __syncthreads();
    if (t < 64 && s_cnt[t] > 0) {
        atomicAdd(&pool_sum[t], s_sum[t]);
        atomicAdd(&pool_cnt[t], s_cnt[t]);
    }
}

__global__ void final_kernel(const float* __restrict__ pool_sum, const int* __restrict__ pool_cnt,
                             const float* __restrict__ blin, float* __restrict__ out) {
    int g = threadIdx.x;
    if (g < 64) out[g] = pool_sum[g] / fmaxf((float)pool_cnt[g], 1.f) + blin[0];
}

// ---------------- launch ----------------

extern "C" void kernel_launch(void* const* d_in, const int* in_sizes, int n_in,
                              void* d_out, int out_size, void* d_ws, size_t ws_size,
                              hipStream_t stream) {
    const float* x     = (const float*)d_in[0];
    const int*   ei    = (const int*)d_in[1];
    const float* eattr = (const float*)d_in[2];
    const int*   batch = (const int*)d_in[3];
    const float* W1  = (const float*)d_in[4];
    const float* as1 = (const float*)d_in[5];
    const float* ad1 = (const float*)d_in[6];
    const float* We1 = (const float*)d_in[7];
    const float* ae1 = (const float*)d_in[8];
    const float* b1  = (const float*)d_in[9];
    const float* W2  = (const float*)d_in[10];
    const float* as2 = (const float*)d_in[11];
    const float* ad2 = (const float*)d_in[12];
    const float* We2 = (const float*)d_in[13];
    const float* ae2 = (const float*)d_in[14];
    const float* b2  = (const float*)d_in[15];
    const float* Wlin = (const float*)d_in[16];
    const float* blin = (const float*)d_in[17];
    float* out = (float*)d_out;

    int N = in_sizes[0] / 5;
    int E = in_sizes[1] / 2;
    size_t EP = (size_t)E + N;
    const int* src0 = ei;
    const int* dst0 = ei + E;
    int B = (N + 255) / 256;

    char* ws = (char*)d_ws;
    size_t off = 0;
    auto alloc = [&](size_t bytes) {
        void* p = ws + off;
        off = (off + bytes + 255) & ~(size_t)255;
        return p;
    };
    unsigned long long* hist = (unsigned long long*)alloc((size_t)N * 8);
    int*    row_ptr  = (int*)   alloc((size_t)(N + 1) * 4);
    int*    pos      = (int*)   alloc((size_t)E * 4);
    int2*   col      = (int2*)  alloc(EP * 8);
    int*    block_sum= (int*)   alloc((size_t)1024 * 4);
    int*    block_off= (int*)   alloc((size_t)1024 * 4);
    float*  wp       = (float*) alloc(280 * 4);
    unsigned short* W2b = (unsigned short*)alloc((size_t)128 * 64 * 2);
    float2* al_s1    = (float2*)alloc((size_t)N * 8);
    float2* al_d1    = (float2*)alloc((size_t)N * 8);
    uint4*  xb1      = (uint4*) alloc((size_t)N * 16);
    float*  agg1     = (float*) alloc((size_t)N * 10 * 4);
    float2* al_s2    = (float2*)alloc((size_t)N * 8);
    float2* al_d2    = (float2*)alloc((size_t)N * 8);
    u32*    xb2      = (u32*)   alloc((size_t)N * 32 * 4);
    u32*    agg2b    = (u32*)   alloc((size_t)N * 64 * 4);
    float*  pool_sum = (float*) alloc(64 * 4);
    int*    pool_cnt = (int*)   alloc(64 * 4);

    hipMemsetAsync(hist, 0, (size_t)N * 8, stream);
    hipMemsetAsync(block_sum, 0, (size_t)1024 * 4, stream);
    hipMemsetAsync(pool_sum, 0, 64 * 4, stream);
    hipMemsetAsync(pool_cnt, 0, 64 * 4, stream);

    hist_pos_kernel<<<(E + 255) / 256, 256, 0, stream>>>(dst0, eattr, hist, pos, E);
    scan_phase1<<<B, 256, 0, stream>>>(hist, block_sum, N);
    scan_phase2<<<1, 1024, 0, stream>>>(block_sum, block_off, row_ptr, B, N);
    scan_phase3<<<B, 256, 0, stream>>>(hist, block_off, row_ptr, col, N);
    place_kernel<<<(E + 255) / 256, 256, 0, stream>>>(src0, dst0, eattr, row_ptr, pos, col, E);
    prep2_kernel<<<1, 256, 0, stream>>>(W1, as1, ad1, We1, ae1, W2, as2, ad2, We2, ae2, wp, W2b);

    int eab = (N + 3) / 4;                  // 4 waves per block (proj1)
    int eab8 = (N + 7) / 8;                 // 8 segments per block, 2 nodes/wave (L1, L2)

    // layer 1: aggregate raw 5-dim features, then project
    node_pre1<<<B, 256, 0, stream>>>(x, wp, al_s1, al_d1, xb1, N);
    edge_aggr_L1<<<eab8, 256, 0, stream>>>(row_ptr, col, al_s1, al_d1, xb1, wp, agg1, N);
    proj1_kernel<<<eab, 256, 0, stream>>>(agg1, W1, b1, wp, al_s2, al_d2, xb2, N);
    // layer 2: aggregate 64-dim feat1 (bf16 out), then MFMA projection + pool
    edge_aggr_L2<<<eab8, 256, 0, stream>>>(row_ptr, col, al_s2, al_d2, xb2, wp, agg2b, N);
    int nstrips = (N + 15) / 16;
    proj2_pool_mfma<<<(nstrips + 3) / 4, 256, 0, stream>>>(agg2b, W2b, b2, Wlin, batch,
                                                           pool_sum, pool_cnt, N);
    final_kernel<<<1, 64, 0, stream>>>(pool_sum, pool_cnt, blin, out);
}

// Round 23
// 152.207 us; speedup vs baseline: 1.8536x; 1.0643x over previous
//
#include <hip/hip_runtime.h>
#include <hip/hip_bf16.h>
#include <math.h>

typedef unsigned int u32;
typedef __attribute__((ext_vector_type(8))) short short8v;   // 8 bf16 = 4 VGPRs
typedef __attribute__((ext_vector_type(4))) float f32x4;

#define LRELU(a) ((a) > 0.f ? (a) : 0.2f * (a))

#define FIX_SCALE 67108864.0f          // 2^26 fixed-point for attr sums
#define FIX_INV   (1.0f / 67108864.0f)
#define CNT_SHIFT 40
#define SUM_MASK  0xFFFFFFFFFFULL

// round-to-nearest-even f32 -> bf16 bits
__device__ __forceinline__ u32 f2bf(float f) {
    u32 u = __float_as_uint(f);
    return (u + 0x7fffu + ((u >> 16) & 1u)) >> 16;
}
__device__ __forceinline__ float bfl(u32 w) { return __uint_as_float(w << 16); }
__device__ __forceinline__ float bfh(u32 w) { return __uint_as_float(w & 0xffff0000u); }

#define RED(x) _Pragma("unroll") for (int m_ = 32; m_ >= 1; m_ >>= 1) x += __shfl_xor(x, m_);
#define REDMAX(x) _Pragma("unroll") for (int m_ = 32; m_ >= 1; m_ >>= 1) x = fmaxf(x, __shfl_xor(x, m_));
// 32-lane-segment variants (masks <=16 stay within each half-wave)
#define RED32(x) _Pragma("unroll") for (int m_ = 16; m_ >= 1; m_ >>= 1) x += __shfl_xor(x, m_);
#define REDMAX32(x) _Pragma("unroll") for (int m_ = 16; m_ >= 1; m_ >>= 1) x = fmaxf(x, __shfl_xor(x, m_));

// ---------------- CSR build (unchanged; passed) ----------------

__global__ void hist_pos_kernel(const int* __restrict__ dst, const float* __restrict__ eattr,
                                unsigned long long* __restrict__ hist, int* __restrict__ pos, int E) {
    int e = blockIdx.x * blockDim.x + threadIdx.x;
    if (e < E) {
        int d = dst[e];
        unsigned long long v = (1ULL << CNT_SHIFT) |
                               (unsigned long long)(eattr[e] * FIX_SCALE + 0.5f);
        unsigned long long old = atomicAdd(&hist[d], v);
        pos[e] = (int)(old >> CNT_SHIFT);
    }
}

__global__ __launch_bounds__(256) void scan_phase1(const unsigned long long* __restrict__ hist,
                                                   int* __restrict__ block_sum, int N) {
    int t = threadIdx.x;
    int n = blockIdx.x * 256 + t;
    int v = (n < N) ? (int)(hist[n] >> CNT_SHIFT) + 1 : 0;  // +1 self loop
    RED(v)
    __shared__ int ws[4];
    if ((t & 63) == 0) ws[t >> 6] = v;
    __syncthreads();
    if (t == 0) block_sum[blockIdx.x] = ws[0] + ws[1] + ws[2] + ws[3];
}

__global__ __launch_bounds__(1024) void scan_phase2(const int* __restrict__ block_sum,
                                                    int* __restrict__ block_off,
                                                    int* __restrict__ row_ptr, int B, int N) {
    __shared__ int s[1024];
    int t = threadIdx.x;
    int v = (t < B) ? block_sum[t] : 0;
    s[t] = v;
    __syncthreads();
    for (int off = 1; off < 1024; off <<= 1) {
        int u = (t >= off) ? s[t - off] : 0;
        __syncthreads();
        s[t] += u;
        __syncthreads();
    }
    if (t < B) block_off[t] = s[t] - v;
    if (t == 1023) row_ptr[N] = s[1023];
}

__global__ __launch_bounds__(256) void scan_phase3(const unsigned long long* __restrict__ hist,
                                                   const int* __restrict__ block_off,
                                                   int* __restrict__ row_ptr,
                                                   int2* __restrict__ col, int N) {
    int t = threadIdx.x;
    int lane = t & 63;
    int n = blockIdx.x * 256 + t;
    unsigned long long hv = (n < N) ? hist[n] : 0ULL;
    int c = (n < N) ? (int)(hv >> CNT_SHIFT) + 1 : 0;
    int v = c;
#pragma unroll
    for (int m = 1; m < 64; m <<= 1) {
        int u = __shfl_up(v, m);
        if (lane >= m) v += u;
    }
    __shared__ int wsum[4];
    if (lane == 63) wsum[t >> 6] = v;
    __syncthreads();
    int w = t >> 6;
    int wadd = 0;
#pragma unroll
    for (int i = 0; i < 3; i++) wadd += (i < w) ? wsum[i] : 0;
    int base = block_off[blockIdx.x] + wadd + v - c;
    if (n < N) {
        row_ptr[n] = base;
        float asum = (float)(hv & SUM_MASK) * FIX_INV;
        float la = asum / fmaxf((float)(c - 1), 1.f);
        col[base] = make_int2(n, __float_as_int(la));   // self loop first in row
    }
}

__global__ void place_kernel(const int* __restrict__ src, const int* __restrict__ dst,
                             const float* __restrict__ eattr, const int* __restrict__ row_ptr,
                             const int* __restrict__ pos, int2* __restrict__ col, int E) {
    int e = blockIdx.x * blockDim.x + threadIdx.x;
    if (e < E) {
        int d = dst[e];
        col[row_ptr[d] + 1 + pos[e]] = make_int2(src[e], __float_as_int(eattr[e]));
    }
}

// ---------------- prep: we_dot scalars + folded attention vectors + bf16 W2b ----------------
// wp layout: [0..3] we_dot(layer,h); [4..13] w_as1[h][k]; [14..23] w_ad1;
//            [24..151] w_as2[h][k] (2x64); [152..279] w_ad2.
// W2b[k][c] (bf16, 128x64) = 0.5*W2 (head-mean folded in; exact exponent shift).

__global__ __launch_bounds__(256) void prep2_kernel(
        const float* __restrict__ W1, const float* __restrict__ as1, const float* __restrict__ ad1,
        const float* __restrict__ We1, const float* __restrict__ ae1,
        const float* __restrict__ W2, const float* __restrict__ as2, const float* __restrict__ ad2,
        const float* __restrict__ We2, const float* __restrict__ ae2,
        float* __restrict__ wp, unsigned short* __restrict__ W2b) {
    int t = threadIdx.x;
    int g = t >> 6, lane = t & 63;          // g = layer*2 + h
    const float* We = (g & 2) ? We2 : We1;
    const float* ae = (g & 2) ? ae2 : ae1;
    int h = g & 1;
    float v = We[h * 64 + lane] * ae[h * 64 + lane];
    RED(v)
    if (lane == 0) wp[g] = v;
    if (t < 20) {                            // layer-1 folded vectors (2 heads x 5)
        int dd = t / 10;
        int hh = (t % 10) / 5, k = t % 5;
        const float* a = dd ? ad1 : as1;
        float s = 0.f;
        for (int c = 0; c < 64; c++) s += W1[k * 128 + hh * 64 + c] * a[hh * 64 + c];
        wp[4 + dd * 10 + hh * 5 + k] = s;
    }
    {                                        // layer-2 folded vectors (2 heads x 64) x {s,d}
        int dd = t >> 7;
        int hh = (t >> 6) & 1, k = t & 63;
        const float* a = dd ? ad2 : as2;
        float s = 0.f;
        for (int c = 0; c < 64; c++) s += W2[k * 128 + hh * 64 + c] * a[hh * 64 + c];
        wp[24 + dd * 128 + hh * 64 + k] = s;
    }
    for (int i = t; i < 128 * 64; i += 256) {  // W2b bf16, 0.5 head-mean folded (exact)
        int k = i >> 6, c = i & 63;
        W2b[i] = (unsigned short)f2bf(0.5f * W2[(k & 63) * 128 + (k & 64) + c]);
    }
}

// ---------------- layer-1 node pre-pass: logits + bf16-packed raw features ----------------

__global__ __launch_bounds__(256) void node_pre1(
        const float* __restrict__ x, const float* __restrict__ wp,
        float2* __restrict__ al_s, float2* __restrict__ al_d, uint4* __restrict__ xb1, int N) {
    int n = blockIdx.x * 256 + threadIdx.x;
    if (n >= N) return;
    float f[5];
#pragma unroll
    for (int k = 0; k < 5; k++) f[k] = x[(size_t)n * 5 + k];
    float s0 = 0.f, s1 = 0.f, d0 = 0.f, d1 = 0.f;
#pragma unroll
    for (int k = 0; k < 5; k++) {
        s0 += f[k] * wp[4 + k];   s1 += f[k] * wp[9 + k];
        d0 += f[k] * wp[14 + k];  d1 += f[k] * wp[19 + k];
    }
    al_s[n] = make_float2(s0, s1);
    al_d[n] = make_float2(d0, d1);
    uint4 p;
    p.x = (f2bf(f[1]) << 16) | f2bf(f[0]);
    p.y = (f2bf(f[3]) << 16) | f2bf(f[2]);
    p.z = f2bf(f[4]);
    p.w = 0;
    xb1[n] = p;
}

// ---------------- FUSED layer-1: edge aggregation + projection + layer-2 logits ------------
// 2 nodes/wave, 32-lane segments. After the RED32 butterfly, ALL lanes hold the full
// aggregate -> proj1 inlined: lane computes channels {2*slane, 2*slane+1} (coalesced
// float2 W1/b1/wp reads), packs its own xb2 word; 4 more RED32s give layer-2 logits.

__global__ __launch_bounds__(256) void edge_proj_L1(
        const int* __restrict__ row_ptr, const int2* __restrict__ col,
        const float2* __restrict__ al_s, const float2* __restrict__ al_d,
        const uint4* __restrict__ xb1, const float* __restrict__ wp,
        const float* __restrict__ W1, const float* __restrict__ b1,
        float2* __restrict__ al_s2, float2* __restrict__ al_d2, u32* __restrict__ xb2, int N) {
    int slane = threadIdx.x & 31;
    int n = blockIdx.x * 8 + (threadIdx.x >> 5);   // 8 segments per block
    if (n >= N) return;
    int start = row_ptr[n], end = row_ptr[n + 1];
    int cnt = end - start;
    float we0 = wp[0], we1 = wp[1];
    float2 ald = al_d[n];
    float a00 = 0.f, a01 = 0.f, a02 = 0.f, a03 = 0.f, a04 = 0.f;
    float a10 = 0.f, a11 = 0.f, a12 = 0.f, a13 = 0.f, a14 = 0.f;
    float den0 = 0.f, den1 = 0.f;

    if (cnt <= 32) {
        float v0 = -INFINITY, v1 = -INFINITY;
        int sc = 0;
        if (slane < cnt) {
            int2 ce = col[start + slane];
            sc = ce.x;
            float at = __int_as_float(ce.y);
            float2 als = al_s[sc];
            v0 = LRELU(als.x + ald.x + we0 * at);
            v1 = LRELU(als.y + ald.y + we1 * at);
        }
        float m0 = v0, m1 = v1;
        REDMAX32(m0) REDMAX32(m1)
        if (slane < cnt) {
            float e0 = __expf(v0 - m0), e1 = __expf(v1 - m1);
            uint4 p = xb1[sc];
            float f0 = bfl(p.x), f1 = bfh(p.x), f2 = bfl(p.y), f3 = bfh(p.y), f4 = bfl(p.z);
            a00 = e0 * f0; a01 = e0 * f1; a02 = e0 * f2; a03 = e0 * f3; a04 = e0 * f4;
            a10 = e1 * f0; a11 = e1 * f1; a12 = e1 * f2; a13 = e1 * f3; a14 = e1 * f4;
            den0 = e0; den1 = e1;
        }
    } else {
        float m0 = -INFINITY, m1 = -INFINITY;
        for (int i = start + slane; i < end; i += 32) {
            int2 ce = col[i];
            float at = __int_as_float(ce.y);
            float2 als = al_s[ce.x];
            m0 = fmaxf(m0, LRELU(als.x + ald.x + we0 * at));
            m1 = fmaxf(m1, LRELU(als.y + ald.y + we1 * at));
        }
        REDMAX32(m0) REDMAX32(m1)
        for (int i = start + slane; i < end; i += 32) {
            int2 ce = col[i];
            float at = __int_as_float(ce.y);
            float2 als = al_s[ce.x];
            float e0 = __expf(LRELU(als.x + ald.x + we0 * at) - m0);
            float e1 = __expf(LRELU(als.y + ald.y + we1 * at) - m1);
            uint4 p = xb1[ce.x];
            float f0 = bfl(p.x), f1 = bfh(p.x), f2 = bfl(p.y), f3 = bfh(p.y), f4 = bfl(p.z);
            a00 += e0 * f0; a01 += e0 * f1; a02 += e0 * f2; a03 += e0 * f3; a04 += e0 * f4;
            a10 += e1 * f0; a11 += e1 * f1; a12 += e1 * f2; a13 += e1 * f3; a14 += e1 * f4;
            den0 += e0; den1 += e1;
        }
    }
    RED32(a00) RED32(a01) RED32(a02) RED32(a03) RED32(a04)
    RED32(a10) RED32(a11) RED32(a12) RED32(a13) RED32(a14)
    RED32(den0) RED32(den1)

    // ---- fused projection: lane owns channels c0=2*slane, c0+1 ----
    float i0 = 1.f / (den0 + 1e-16f), i1 = 1.f / (den1 + 1e-16f);
    float ag0[5] = {a00 * i0, a01 * i0, a02 * i0, a03 * i0, a04 * i0};
    float ag1[5] = {a10 * i1, a11 * i1, a12 * i1, a13 * i1, a14 * i1};
    const float2* W1v = (const float2*)W1;   // row k = 64 float2
    float s0 = 0.f, t0 = 0.f, s1 = 0.f, t1 = 0.f;
#pragma unroll
    for (int k = 0; k < 5; k++) {
        float2 w0 = W1v[k * 64 + slane];        // head0 cols {c0, c0+1}
        float2 w1 = W1v[k * 64 + 32 + slane];   // head1 cols {64+c0, 64+c0+1}
        s0 += ag0[k] * w0.x; t0 += ag0[k] * w0.y;
        s1 += ag1[k] * w1.x; t1 += ag1[k] * w1.y;
    }
    float2 bb = ((const float2*)b1)[slane];
    float h0 = fmaxf(0.5f * (s0 + s1) + bb.x, 0.f);
    float h1 = fmaxf(0.5f * (t0 + t1) + bb.y, 0.f);

    float2 wa = ((const float2*)(wp + 24))[slane];
    float2 wb = ((const float2*)(wp + 88))[slane];
    float2 wc = ((const float2*)(wp + 152))[slane];
    float2 wd = ((const float2*)(wp + 216))[slane];
    float r0 = h0 * wa.x + h1 * wa.y;
    float r1 = h0 * wb.x + h1 * wb.y;
    float r2 = h0 * wc.x + h1 * wc.y;
    float r3 = h0 * wd.x + h1 * wd.y;
    RED32(r0) RED32(r1) RED32(r2) RED32(r3)
    if (slane == 0) {
        al_s2[n] = make_float2(r0, r1);
        al_d2[n] = make_float2(r2, r3);
    }
    xb2[(size_t)n * 32 + slane] = (f2bf(h1) << 16) | f2bf(h0);
}

// ---------------- layer-2 edge aggregation: 2 nodes/wave, 32-lane segments ----------------
// Lane w owns row word w (channels {2w,2w+1}) and applies BOTH head weights (4 FMA/load).
// agg2b[n] = 64 u32 words = 128 bf16: words 0..31 head0 aggregate, 32..63 head1.

__global__ __launch_bounds__(256) void edge_aggr_L2(
        const int* __restrict__ row_ptr, const int2* __restrict__ col,
        const float2* __restrict__ al_s, const float2* __restrict__ al_d,
        const u32* __restrict__ xb2, const float* __restrict__ wp,
        u32* __restrict__ agg2b, int N) {
    __shared__ float s_e0[8][32], s_e1[8][32];
    __shared__ int s_src[8][32];
    int seg = threadIdx.x >> 5;      // 0..7
    int slane = threadIdx.x & 31;
    int n = blockIdx.x * 8 + seg;
    if (n >= N) return;
    int start = row_ptr[n], end = row_ptr[n + 1];
    int cnt = end - start;
    float we0 = wp[2], we1 = wp[3];
    float2 ald = al_d[n];
    float ax0 = 0.f, ay0 = 0.f, ax1 = 0.f, ay1 = 0.f, den0 = 0.f, den1 = 0.f;

    if (cnt <= 32) {
        float v0 = -INFINITY, v1 = -INFINITY;
        int sc = 0;
        if (slane < cnt) {
            int2 ce = col[start + slane];
            sc = ce.x;
            float at = __int_as_float(ce.y);
            float2 als = al_s[sc];
            v0 = LRELU(als.x + ald.x + we0 * at);
            v1 = LRELU(als.y + ald.y + we1 * at);
        }
        float m0 = v0, m1 = v1;
        REDMAX32(m0) REDMAX32(m1)
        float e0 = 0.f, e1 = 0.f;
        if (slane < cnt) {
            e0 = __expf(v0 - m0);
            e1 = __expf(v1 - m1);
        }
        den0 = e0; den1 = e1;
        s_e0[seg][slane] = e0; s_e1[seg][slane] = e1; s_src[seg][slane] = sc;
        // no barrier: same-wave LDS write->read, lockstep

#pragma unroll 4
        for (int j = 0; j < cnt; j++) {
            float w0 = s_e0[seg][j], w1 = s_e1[seg][j];
            u32 v = xb2[(size_t)s_src[seg][j] * 32 + slane];
            float lo = bfl(v), hi = bfh(v);
            ax0 += w0 * lo; ay0 += w0 * hi;
            ax1 += w1 * lo; ay1 += w1 * hi;
        }
    } else {
        float m0 = -INFINITY, m1 = -INFINITY;
        for (int i = start + slane; i < end; i += 32) {
            int2 ce = col[i];
            float at = __int_as_float(ce.y);
            float2 als = al_s[ce.x];
            m0 = fmaxf(m0, LRELU(als.x + ald.x + we0 * at));
            m1 = fmaxf(m1, LRELU(als.y + ald.y + we1 * at));
        }
        REDMAX32(m0) REDMAX32(m1)
        for (int cs = start; cs < end; cs += 32) {
            int i = cs + slane;
            float e0 = 0.f, e1 = 0.f;
            int sc = 0;
            if (i < end) {
                int2 ce = col[i];
                sc = ce.x;
                float at = __int_as_float(ce.y);
                float2 als = al_s[sc];
                e0 = __expf(LRELU(als.x + ald.x + we0 * at) - m0);
                e1 = __expf(LRELU(als.y + ald.y + we1 * at) - m1);
            }
            den0 += e0; den1 += e1;
            s_e0[seg][slane] = e0; s_e1[seg][slane] = e1; s_src[seg][slane] = sc;
            int c2 = min(32, end - cs);
#pragma unroll 4
            for (int j = 0; j < c2; j++) {
                float w0 = s_e0[seg][j], w1 = s_e1[seg][j];
                u32 v = xb2[(size_t)s_src[seg][j] * 32 + slane];
                float lo = bfl(v), hi = bfh(v);
                ax0 += w0 * lo; ay0 += w0 * hi;
                ax1 += w1 * lo; ay1 += w1 * hi;
            }
        }
    }
    RED32(den0) RED32(den1)
    float i0 = 1.f / (den0 + 1e-16f), i1 = 1.f / (den1 + 1e-16f);
    agg2b[(size_t)n * 64 + slane]      = (f2bf(ay0 * i0) << 16) | f2bf(ax0 * i0);
    agg2b[(size_t)n * 64 + 32 + slane] = (f2bf(ay1 * i1) << 16) | f2bf(ax1 * i1);
}

// ---------------- layer-2 projection + relu + pooling: MFMA GEMM [N x128]x[128 x64] ----------
// Wave per 16-node strip. B (0.5*W2 bf16) in 16 register fragments (loaded once).
// Layouts (16x16x32): A row=lane&15, k=8*(lane>>4)+r; C/D col=lane&15, row=(lane>>4)*4+reg.

__global__ __launch_bounds__(256) void proj2_pool_mfma(
        const u32* __restrict__ agg2b, const unsigned short* __restrict__ W2b,
        const float* __restrict__ b2, const float* __restrict__ Wlin,
        const int* __restrict__ batch,
        float* __restrict__ pool_sum, int* __restrict__ pool_cnt, int N) {
    __shared__ float s_sum[64];
    __shared__ int s_cnt[64];
    int t = threadIdx.x;
    int wid = t >> 6, lane = t & 63;
    if (t < 64) { s_sum[t] = 0.f; s_cnt[t] = 0; }
    __syncthreads();

    int sub = lane >> 4, cc = lane & 15;

    short8v bfrag[4][4];
#pragma unroll
    for (int tl = 0; tl < 4; tl++)
#pragma unroll
        for (int kk = 0; kk < 4; kk++)
#pragma unroll
            for (int r = 0; r < 8; r++)
                bfrag[tl][kk][r] = (short)W2b[(kk * 32 + 8 * sub + r) * 64 + tl * 16 + cc];

    float b2v[4], wlv[4];
#pragma unroll
    for (int tl = 0; tl < 4; tl++) {
        b2v[tl] = b2[tl * 16 + cc];
        wlv[tl] = Wlin[tl * 16 + cc];
    }

    int nstrips = (N + 15) >> 4;
    for (int strip = blockIdx.x * 4 + wid; strip < nstrips; strip += gridDim.x * 4) {
        int n0 = strip << 4;
        int arow = min(n0 + cc, N - 1);     // lane's A row (clamped in tail strip)
        const uint4* ap = (const uint4*)agg2b;
        short8v a[4];
#pragma unroll
        for (int kk = 0; kk < 4; kk++) {    // row = 16 uint4; kk-block has 4, take sub-th
            uint4 raw = ap[(size_t)arow * 16 + kk * 4 + sub];
            a[kk] = *(const short8v*)&raw;
        }

        f32x4 acc0 = {0.f, 0.f, 0.f, 0.f}, acc1 = acc0, acc2 = acc0, acc3 = acc0;
#pragma unroll
        for (int kk = 0; kk < 4; kk++) {
            acc0 = __builtin_amdgcn_mfma_f32_16x16x32_bf16(a[kk], bfrag[0][kk], acc0, 0, 0, 0);
            acc1 = __builtin_amdgcn_mfma_f32_16x16x32_bf16(a[kk], bfrag[1][kk], acc1, 0, 0, 0);
            acc2 = __builtin_amdgcn_mfma_f32_16x16x32_bf16(a[kk], bfrag[2][kk], acc2, 0, 0, 0);
            acc3 = __builtin_amdgcn_mfma_f32_16x16x32_bf16(a[kk], bfrag[3][kk], acc3, 0, 0, 0);
        }

#pragma unroll
        for (int r = 0; r < 4; r++) {
            float p = fmaxf(acc0[r] + b2v[0], 0.f) * wlv[0]
                    + fmaxf(acc1[r] + b2v[1], 0.f) * wlv[1]
                    + fmaxf(acc2[r] + b2v[2], 0.f) * wlv[2]
                    + fmaxf(acc3[r] + b2v[3], 0.f) * wlv[3];
#pragma unroll
            for (int m = 8; m >= 1; m >>= 1) p += __shfl_xor(p, m);
            if (cc == 0) {
                int node = n0 + sub * 4 + r;
                if (node < N) {
                    int g = batch[node];
                    atomicAdd(&s_sum[g], p);
                    atomicAdd(&s_cnt[g], 1);
                }
            }
        }
    }
    __syncthreads();
    if (t < 64 && s_cnt[t] > 0) {
        atomicAdd(&pool_sum[t], s_sum[t]);
        atomicAdd(&pool_cnt[t], s_cnt[t]);
    }
}

__global__ void final_kernel(const float* __restrict__ pool_sum, const int* __restrict__ pool_cnt,
                             const float* __restrict__ blin, float* __restrict__ out) {
    int g = threadIdx.x;
    if (g < 64) out[g] = pool_sum[g] / fmaxf((float)pool_cnt[g], 1.f) + blin[0];
}

// ---------------- launch ----------------

extern "C" void kernel_launch(void* const* d_in, const int* in_sizes, int n_in,
                              void* d_out, int out_size, void* d_ws, size_t ws_size,
                              hipStream_t stream) {
    const float* x     = (const float*)d_in[0];
    const int*   ei    = (const int*)d_in[1];
    const float* eattr = (const float*)d_in[2];
    const int*   batch = (const int*)d_in[3];
    const float* W1  = (const float*)d_in[4];
    const float* as1 = (const float*)d_in[5];
    const float* ad1 = (const float*)d_in[6];
    const float* We1 = (const float*)d_in[7];
    const float* ae1 = (const float*)d_in[8];
    const float* b1  = (const float*)d_in[9];
    const float* W2  = (const float*)d_in[10];
    const float* as2 = (const float*)d_in[11];
    const float* ad2 = (const float*)d_in[12];
    const float* We2 = (const float*)d_in[13];
    const float* ae2 = (const float*)d_in[14];
    const float* b2  = (const float*)d_in[15];
    const float* Wlin = (const float*)d_in[16];
    const float* blin = (const float*)d_in[17];
    float* out = (float*)d_out;

    int N = in_sizes[0] / 5;
    int E = in_sizes[1] / 2;
    size_t EP = (size_t)E + N;
    const int* src0 = ei;
    const int* dst0 = ei + E;
    int B = (N + 255) / 256;

    char* ws = (char*)d_ws;
    size_t off = 0;
    auto alloc = [&](size_t bytes) {
        void* p = ws + off;
        off = (off + bytes + 255) & ~(size_t)255;
        return p;
    };
    unsigned long long* hist = (unsigned long long*)alloc((size_t)N * 8);
    int*    row_ptr  = (int*)   alloc((size_t)(N + 1) * 4);
    int*    pos      = (int*)   alloc((size_t)E * 4);
    int2*   col      = (int2*)  alloc(EP * 8);
    int*    block_sum= (int*)   alloc((size_t)1024 * 4);
    int*    block_off= (int*)   alloc((size_t)1024 * 4);
    float*  wp       = (float*) alloc(280 * 4);
    unsigned short* W2b = (unsigned short*)alloc((size_t)128 * 64 * 2);
    float2* al_s1    = (float2*)alloc((size_t)N * 8);
    float2* al_d1    = (float2*)alloc((size_t)N * 8);
    uint4*  xb1      = (uint4*) alloc((size_t)N * 16);
    float2* al_s2    = (float2*)alloc((size_t)N * 8);
    float2* al_d2    = (float2*)alloc((size_t)N * 8);
    u32*    xb2      = (u32*)   alloc((size_t)N * 32 * 4);
    u32*    agg2b    = (u32*)   alloc((size_t)N * 64 * 4);
    float*  pool_sum = (float*) alloc(64 * 4);
    int*    pool_cnt = (int*)   alloc(64 * 4);

    hipMemsetAsync(hist, 0, (size_t)N * 8, stream);
    hipMemsetAsync(block_sum, 0, (size_t)1024 * 4, stream);
    hipMemsetAsync(pool_sum, 0, 64 * 4, stream);
    hipMemsetAsync(pool_cnt, 0, 64 * 4, stream);

    hist_pos_kernel<<<(E + 255) / 256, 256, 0, stream>>>(dst0, eattr, hist, pos, E);
    scan_phase1<<<B, 256, 0, stream>>>(hist, block_sum, N);
    scan_phase2<<<1, 1024, 0, stream>>>(block_sum, block_off, row_ptr, B, N);
    scan_phase3<<<B, 256, 0, stream>>>(hist, block_off, row_ptr, col, N);
    place_kernel<<<(E + 255) / 256, 256, 0, stream>>>(src0, dst0, eattr, row_ptr, pos, col, E);
    prep2_kernel<<<1, 256, 0, stream>>>(W1, as1, ad1, We1, ae1, W2, as2, ad2, We2, ae2, wp, W2b);

    int eab8 = (N + 7) / 8;                 // 8 segments per block, 2 nodes/wave

    // layer 1: aggregate raw 5-dim features + FUSED projection + layer-2 logits
    node_pre1<<<B, 256, 0, stream>>>(x, wp, al_s1, al_d1, xb1, N);
    edge_proj_L1<<<eab8, 256, 0, stream>>>(row_ptr, col, al_s1, al_d1, xb1, wp, W1, b1,
                                           al_s2, al_d2, xb2, N);
    // layer 2: aggregate 64-dim feat1 (bf16 out), then MFMA projection + pool
    edge_aggr_L2<<<eab8, 256, 0, stream>>>(row_ptr, col, al_s2, al_d2, xb2, wp, agg2b, N);
    int nstrips = (N + 15) / 16;
    proj2_pool_mfma<<<(nstrips + 3) / 4, 256, 0, stream>>>(agg2b, W2b, b2, Wlin, batch,
                                                           pool_sum, pool_cnt, N);
    final_kernel<<<1, 64, 0, stream>>>(pool_sum, pool_cnt, blin, out);
}

// Round 26
// 136.666 us; speedup vs baseline: 2.0644x; 1.1137x over previous
//
#include <hip/hip_runtime.h>
#include <hip/hip_bf16.h>
#include <math.h>

typedef unsigned int u32;
typedef __attribute__((ext_vector_type(8))) short short8v;   // 8 bf16 = 4 VGPRs
typedef __attribute__((ext_vector_type(4))) float f32x4;

#define LRELU(a) ((a) > 0.f ? (a) : 0.2f * (a))

#define FIX_SCALE 67108864.0f          // 2^26 fixed-point for attr sums
#define FIX_INV   (1.0f / 67108864.0f)
#define CNT_SHIFT 40
#define SUM_MASK  0xFFFFFFFFFFULL

// round-to-nearest-even f32 -> bf16 bits
__device__ __forceinline__ u32 f2bf(float f) {
    u32 u = __float_as_uint(f);
    return (u + 0x7fffu + ((u >> 16) & 1u)) >> 16;
}
__device__ __forceinline__ float bfl(u32 w) { return __uint_as_float(w << 16); }
__device__ __forceinline__ float bfh(u32 w) { return __uint_as_float(w & 0xffff0000u); }

#define RED(x) _Pragma("unroll") for (int m_ = 32; m_ >= 1; m_ >>= 1) x += __shfl_xor(x, m_);
#define RED32(x) _Pragma("unroll") for (int m_ = 16; m_ >= 1; m_ >>= 1) x += __shfl_xor(x, m_);

// ---------------- fused: CSR hist (+pos) | prep (we_dot, folded vectors, bf16 W2b) ----------
// Blocks [0,HB): one u64 atomic per edge; old value's count field = slot index.
// Block HB: prep work (independent of hist).
// wp layout: [0..3] we_dot(layer,h); [4..13] w_as1; [14..23] w_ad1; [24..151] w_as2; [152..279] w_ad2.
// W2b[k][c] (bf16, 128x64) = 0.5*W2 (head-mean folded; exact exponent shift).

__global__ void hist_prep_kernel(const int* __restrict__ dst, const float* __restrict__ eattr,
                                 unsigned long long* __restrict__ hist, int* __restrict__ pos, int E,
                                 const float* __restrict__ W1, const float* __restrict__ as1,
                                 const float* __restrict__ ad1, const float* __restrict__ We1,
                                 const float* __restrict__ ae1,
                                 const float* __restrict__ W2, const float* __restrict__ as2,
                                 const float* __restrict__ ad2, const float* __restrict__ We2,
                                 const float* __restrict__ ae2,
                                 float* __restrict__ wp, unsigned short* __restrict__ W2b, int HB) {
    int t = threadIdx.x;
    if ((int)blockIdx.x < HB) {
        int e = blockIdx.x * 256 + t;
        if (e < E) {
            int d = dst[e];
            unsigned long long v = (1ULL << CNT_SHIFT) |
                                   (unsigned long long)(eattr[e] * FIX_SCALE + 0.5f);
            unsigned long long old = atomicAdd(&hist[d], v);
            pos[e] = (int)(old >> CNT_SHIFT);
        }
        return;
    }
    // ---- prep block ----
    int g = t >> 6, lane = t & 63;          // g = layer*2 + h
    const float* We = (g & 2) ? We2 : We1;
    const float* ae = (g & 2) ? ae2 : ae1;
    int h = g & 1;
    float v = We[h * 64 + lane] * ae[h * 64 + lane];
    RED(v)
    if (lane == 0) wp[g] = v;
    if (t < 20) {                            // layer-1 folded vectors (2 heads x 5)
        int dd = t / 10;
        int hh = (t % 10) / 5, k = t % 5;
        const float* a = dd ? ad1 : as1;
        float s = 0.f;
        for (int c = 0; c < 64; c++) s += W1[k * 128 + hh * 64 + c] * a[hh * 64 + c];
        wp[4 + dd * 10 + hh * 5 + k] = s;
    }
    {                                        // layer-2 folded vectors (2 heads x 64) x {s,d}
        int dd = t >> 7;
        int hh = (t >> 6) & 1, k = t & 63;
        const float* a = dd ? ad2 : as2;
        float s = 0.f;
        for (int c = 0; c < 64; c++) s += W2[k * 128 + hh * 64 + c] * a[hh * 64 + c];
        wp[24 + dd * 128 + hh * 64 + k] = s;
    }
    for (int i = t; i < 128 * 64; i += 256) {  // W2b bf16, 0.5 head-mean folded (exact)
        int k = i >> 6, c = i & 63;
        W2b[i] = (unsigned short)f2bf(0.5f * W2[(k & 63) * 128 + (k & 64) + c]);
    }
}

// ---------------- fused: scan phase1 | layer-1 node pre-pass --------------------------------
// Blocks [0,B): per-block sums of (cnt+1). Blocks [B,2B): node logits + bf16-packed features.

__global__ __launch_bounds__(256) void scan1_pre_kernel(
        const unsigned long long* __restrict__ hist, int* __restrict__ block_sum, int N, int B,
        const float* __restrict__ x, const float* __restrict__ wp,
        float2* __restrict__ al_s, float2* __restrict__ al_d, uint4* __restrict__ xb1) {
    int t = threadIdx.x;
    if ((int)blockIdx.x < B) {
        int n = blockIdx.x * 256 + t;
        int v = (n < N) ? (int)(hist[n] >> CNT_SHIFT) + 1 : 0;  // +1 self loop
        RED(v)
        __shared__ int ws[4];
        if ((t & 63) == 0) ws[t >> 6] = v;
        __syncthreads();
        if (t == 0) block_sum[blockIdx.x] = ws[0] + ws[1] + ws[2] + ws[3];
        return;
    }
    int n = (blockIdx.x - B) * 256 + t;
    if (n >= N) return;
    float f[5];
#pragma unroll
    for (int k = 0; k < 5; k++) f[k] = x[(size_t)n * 5 + k];
    float s0 = 0.f, s1 = 0.f, d0 = 0.f, d1 = 0.f;
#pragma unroll
    for (int k = 0; k < 5; k++) {
        s0 += f[k] * wp[4 + k];   s1 += f[k] * wp[9 + k];
        d0 += f[k] * wp[14 + k];  d1 += f[k] * wp[19 + k];
    }
    al_s[n] = make_float2(s0, s1);
    al_d[n] = make_float2(d0, d1);
    uint4 p;
    p.x = (f2bf(f[1]) << 16) | f2bf(f[0]);
    p.y = (f2bf(f[3]) << 16) | f2bf(f[2]);
    p.z = f2bf(f[4]);
    p.w = 0;
    xb1[n] = p;
}

__global__ __launch_bounds__(1024) void scan_phase2(const int* __restrict__ block_sum,
                                                    int* __restrict__ block_off,
                                                    int* __restrict__ row_ptr, int B, int N) {
    __shared__ int s[1024];
    int t = threadIdx.x;
    int v = (t < B) ? block_sum[t] : 0;
    s[t] = v;
    __syncthreads();
    for (int off = 1; off < 1024; off <<= 1) {
        int u = (t >= off) ? s[t - off] : 0;
        __syncthreads();
        s[t] += u;
        __syncthreads();
    }
    if (t < B) block_off[t] = s[t] - v;
    if (t == 1023) row_ptr[N] = s[1023];
}

__global__ __launch_bounds__(256) void scan_phase3(const unsigned long long* __restrict__ hist,
                                                   const int* __restrict__ block_off,
                                                   int* __restrict__ row_ptr,
                                                   int2* __restrict__ col, int N) {
    int t = threadIdx.x;
    int lane = t & 63;
    int n = blockIdx.x * 256 + t;
    unsigned long long hv = (n < N) ? hist[n] : 0ULL;
    int c = (n < N) ? (int)(hv >> CNT_SHIFT) + 1 : 0;
    int v = c;
#pragma unroll
    for (int m = 1; m < 64; m <<= 1) {
        int u = __shfl_up(v, m);
        if (lane >= m) v += u;
    }
    __shared__ int wsum[4];
    if (lane == 63) wsum[t >> 6] = v;
    __syncthreads();
    int w = t >> 6;
    int wadd = 0;
#pragma unroll
    for (int i = 0; i < 3; i++) wadd += (i < w) ? wsum[i] : 0;
    int base = block_off[blockIdx.x] + wadd + v - c;
    if (n < N) {
        row_ptr[n] = base;
        float asum = (float)(hv & SUM_MASK) * FIX_INV;
        float la = asum / fmaxf((float)(c - 1), 1.f);
        col[base] = make_int2(n, __float_as_int(la));   // self loop first in row
    }
}

__global__ void place_kernel(const int* __restrict__ src, const int* __restrict__ dst,
                             const float* __restrict__ eattr, const int* __restrict__ row_ptr,
                             const int* __restrict__ pos, int2* __restrict__ col, int E) {
    int e = blockIdx.x * blockDim.x + threadIdx.x;
    if (e < E) {
        int d = dst[e];
        col[row_ptr[d] + 1 + pos[e]] = make_int2(src[e], __float_as_int(eattr[e]));
    }
}

// ---------------- FUSED layer-1: edge aggregation + projection + layer-2 logits ------------
// 2 nodes/wave, 32-lane segments. No max-subtraction (softmax shift-invariant; logits ~O(1)).
// After RED32, all lanes hold the full aggregate -> proj1 inlined (lane = 2 channels).

__global__ __launch_bounds__(256) void edge_proj_L1(
        const int* __restrict__ row_ptr, const int2* __restrict__ col,
        const float2* __restrict__ al_s, const float2* __restrict__ al_d,
        const uint4* __restrict__ xb1, const float* __restrict__ wp,
        const float* __restrict__ W1, const float* __restrict__ b1,
        float2* __restrict__ al_s2, float2* __restrict__ al_d2, u32* __restrict__ xb2, int N) {
    int slane = threadIdx.x & 31;
    int n = blockIdx.x * 8 + (threadIdx.x >> 5);   // 8 segments per block
    if (n >= N) return;
    int start = row_ptr[n], end = row_ptr[n + 1];
    int cnt = end - start;
    float we0 = wp[0], we1 = wp[1];
    float2 ald = al_d[n];
    float a00 = 0.f, a01 = 0.f, a02 = 0.f, a03 = 0.f, a04 = 0.f;
    float a10 = 0.f, a11 = 0.f, a12 = 0.f, a13 = 0.f, a14 = 0.f;
    float den0 = 0.f, den1 = 0.f;

    if (cnt <= 32) {
        if (slane < cnt) {
            int2 ce = col[start + slane];
            int sc = ce.x;
            float at = __int_as_float(ce.y);
            float2 als = al_s[sc];
            float e0 = __expf(LRELU(als.x + ald.x + we0 * at));
            float e1 = __expf(LRELU(als.y + ald.y + we1 * at));
            uint4 p = xb1[sc];
            float f0 = bfl(p.x), f1 = bfh(p.x), f2 = bfl(p.y), f3 = bfh(p.y), f4 = bfl(p.z);
            a00 = e0 * f0; a01 = e0 * f1; a02 = e0 * f2; a03 = e0 * f3; a04 = e0 * f4;
            a10 = e1 * f0; a11 = e1 * f1; a12 = e1 * f2; a13 = e1 * f3; a14 = e1 * f4;
            den0 = e0; den1 = e1;
        }
    } else {
        for (int i = start + slane; i < end; i += 32) {
            int2 ce = col[i];
            float at = __int_as_float(ce.y);
            float2 als = al_s[ce.x];
            float e0 = __expf(LRELU(als.x + ald.x + we0 * at));
            float e1 = __expf(LRELU(als.y + ald.y + we1 * at));
            uint4 p = xb1[ce.x];
            float f0 = bfl(p.x), f1 = bfh(p.x), f2 = bfl(p.y), f3 = bfh(p.y), f4 = bfl(p.z);
            a00 += e0 * f0; a01 += e0 * f1; a02 += e0 * f2; a03 += e0 * f3; a04 += e0 * f4;
            a10 += e1 * f0; a11 += e1 * f1; a12 += e1 * f2; a13 += e1 * f3; a14 += e1 * f4;
            den0 += e0; den1 += e1;
        }
    }
    RED32(a00) RED32(a01) RED32(a02) RED32(a03) RED32(a04)
    RED32(a10) RED32(a11) RED32(a12) RED32(a13) RED32(a14)
    RED32(den0) RED32(den1)

    // ---- fused projection: lane owns channels c0=2*slane, c0+1 ----
    float i0 = 1.f / (den0 + 1e-16f), i1 = 1.f / (den1 + 1e-16f);
    float ag0[5] = {a00 * i0, a01 * i0, a02 * i0, a03 * i0, a04 * i0};
    float ag1[5] = {a10 * i1, a11 * i1, a12 * i1, a13 * i1, a14 * i1};
    const float2* W1v = (const float2*)W1;   // row k = 64 float2
    float s0 = 0.f, t0 = 0.f, s1 = 0.f, t1 = 0.f;
#pragma unroll
    for (int k = 0; k < 5; k++) {
        float2 w0 = W1v[k * 64 + slane];        // head0 cols {c0, c0+1}
        float2 w1 = W1v[k * 64 + 32 + slane];   // head1 cols {64+c0, 64+c0+1}
        s0 += ag0[k] * w0.x; t0 += ag0[k] * w0.y;
        s1 += ag1[k] * w1.x; t1 += ag1[k] * w1.y;
    }
    float2 bb = ((const float2*)b1)[slane];
    float h0 = fmaxf(0.5f * (s0 + s1) + bb.x, 0.f);
    float h1 = fmaxf(0.5f * (t0 + t1) + bb.y, 0.f);

    float2 wa = ((const float2*)(wp + 24))[slane];
    float2 wb = ((const float2*)(wp + 88))[slane];
    float2 wc = ((const float2*)(wp + 152))[slane];
    float2 wd = ((const float2*)(wp + 216))[slane];
    float r0 = h0 * wa.x + h1 * wa.y;
    float r1 = h0 * wb.x + h1 * wb.y;
    float r2 = h0 * wc.x + h1 * wc.y;
    float r3 = h0 * wd.x + h1 * wd.y;
    RED32(r0) RED32(r1) RED32(r2) RED32(r3)
    if (slane == 0) {
        al_s2[n] = make_float2(r0, r1);
        al_d2[n] = make_float2(r2, r3);
    }
    xb2[(size_t)n * 32 + slane] = (f2bf(h1) << 16) | f2bf(h0);
}

// ---------------- layer-2 edge aggregation: 2 nodes/wave, 32-lane segments ----------------
// No max-subtraction. Lane w owns row word w and applies BOTH head weights (4 FMA/load).
// agg2b[n] = 64 u32 words = 128 bf16: words 0..31 head0 aggregate, 32..63 head1.

__global__ __launch_bounds__(256) void edge_aggr_L2(
        const int* __restrict__ row_ptr, const int2* __restrict__ col,
        const float2* __restrict__ al_s, const float2* __restrict__ al_d,
        const u32* __restrict__ xb2, const float* __restrict__ wp,
        u32* __restrict__ agg2b, int N) {
    __shared__ float s_e0[8][32], s_e1[8][32];
    __shared__ int s_src[8][32];
    int seg = threadIdx.x >> 5;      // 0..7
    int slane = threadIdx.x & 31;
    int n = blockIdx.x * 8 + seg;
    if (n >= N) return;
    int start = row_ptr[n], end = row_ptr[n + 1];
    int cnt = end - start;
    float we0 = wp[2], we1 = wp[3];
    float2 ald = al_d[n];
    float ax0 = 0.f, ay0 = 0.f, ax1 = 0.f, ay1 = 0.f, den0 = 0.f, den1 = 0.f;

    if (cnt <= 32) {
        float e0 = 0.f, e1 = 0.f;
        int sc = 0;
        if (slane < cnt) {
            int2 ce = col[start + slane];
            sc = ce.x;
            float at = __int_as_float(ce.y);
            float2 als = al_s[sc];
            e0 = __expf(LRELU(als.x + ald.x + we0 * at));
            e1 = __expf(LRELU(als.y + ald.y + we1 * at));
        }
        den0 = e0; den1 = e1;
        s_e0[seg][slane] = e0; s_e1[seg][slane] = e1; s_src[seg][slane] = sc;
        // no barrier: same-wave LDS write->read, lockstep

#pragma unroll 4
        for (int j = 0; j < cnt; j++) {
            float w0 = s_e0[seg][j], w1 = s_e1[seg][j];
            u32 v = xb2[(size_t)s_src[seg][j] * 32 + slane];
            float lo = bfl(v), hi = bfh(v);
            ax0 += w0 * lo; ay0 += w0 * hi;
            ax1 += w1 * lo; ay1 += w1 * hi;
        }
    } else {
        for (int cs = start; cs < end; cs += 32) {
            int i = cs + slane;
            float e0 = 0.f, e1 = 0.f;
            int sc = 0;
            if (i < end) {
                int2 ce = col[i];
                sc = ce.x;
                float at = __int_as_float(ce.y);
                float2 als = al_s[sc];
                e0 = __expf(LRELU(als.x + ald.x + we0 * at));
                e1 = __expf(LRELU(als.y + ald.y + we1 * at));
            }
            den0 += e0; den1 += e1;
            s_e0[seg][slane] = e0; s_e1[seg][slane] = e1; s_src[seg][slane] = sc;
            int c2 = min(32, end - cs);
#pragma unroll 4
            for (int j = 0; j < c2; j++) {
                float w0 = s_e0[seg][j], w1 = s_e1[seg][j];
                u32 v = xb2[(size_t)s_src[seg][j] * 32 + slane];
                float lo = bfl(v), hi = bfh(v);
                ax0 += w0 * lo; ay0 += w0 * hi;
                ax1 += w1 * lo; ay1 += w1 * hi;
            }
        }
    }
    RED32(den0) RED32(den1)
    float i0 = 1.f / (den0 + 1e-16f), i1 = 1.f / (den1 + 1e-16f);
    agg2b[(size_t)n * 64 + slane]      = (f2bf(ay0 * i0) << 16) | f2bf(ax0 * i0);
    agg2b[(size_t)n * 64 + 32 + slane] = (f2bf(ay1 * i1) << 16) | f2bf(ax1 * i1);
}

// ---------------- layer-2 projection + relu + pooling: MFMA GEMM [N x128]x[128 x64] ----------
// Wave per 16-node strip. B (0.5*W2 bf16) in 16 register fragments (loaded once).
// Layouts (16x16x32): A row=lane&15, k=8*(lane>>4)+r; C/D col=lane&15, row=(lane>>4)*4+reg.

__global__ __launch_bounds__(256) void proj2_pool_mfma(
        const u32* __restrict__ agg2b, const unsigned short* __restrict__ W2b,
        const float* __restrict__ b2, const float* __restrict__ Wlin,
        const int* __restrict__ batch,
        float* __restrict__ pool_sum, int* __restrict__ pool_cnt, int N) {
    __shared__ float s_sum[64];
    __shared__ int s_cnt[64];
    int t = threadIdx.x;
    int wid = t >> 6, lane = t & 63;
    if (t < 64) { s_sum[t] = 0.f; s_cnt[t] = 0; }
    __syncthreads();

    int sub = lane >> 4, cc = lane & 15;

    short8v bfrag[4][4];
#pragma unroll
    for (int tl = 0; tl < 4; tl++)
#pragma unroll
        for (int kk = 0; kk < 4; kk++)
#pragma unroll
            for (int r = 0; r < 8; r++)
                bfrag[tl][kk][r] = (short)W2b[(kk * 32 + 8 * sub + r) * 64 + tl * 16 + cc];

    float b2v[4], wlv[4];
#pragma unroll
    for (int tl = 0; tl < 4; tl++) {
        b2v[tl] = b2[tl * 16 + cc];
        wlv[tl] = Wlin[tl * 16 + cc];
    }

    int nstrips = (N + 15) >> 4;
    for (int strip = blockIdx.x * 4 + wid; strip < nstrips; strip += gridDim.x * 4) {
        int n0 = strip << 4;
        int arow = min(n0 + cc, N - 1);     // lane's A row (clamped in tail strip)
        const uint4* ap = (const uint4*)agg2b;
        short8v a[4];
#pragma unroll
        for (int kk = 0; kk < 4; kk++) {    // row = 16 uint4; kk-block has 4, take sub-th
            uint4 raw = ap[(size_t)arow * 16 + kk * 4 + sub];
            a[kk] = *(const short8v*)&raw;
        }

        f32x4 acc0 = {0.f, 0.f, 0.f, 0.f}, acc1 = acc0, acc2 = acc0, acc3 = acc0;
#pragma unroll
        for (int kk = 0; kk < 4; kk++) {
            acc0 = __builtin_amdgcn_mfma_f32_16x16x32_bf16(a[kk], bfrag[0][kk], acc0, 0, 0, 0);
            acc1 = __builtin_amdgcn_mfma_f32_16x16x32_bf16(a[kk], bfrag[1][kk], acc1, 0, 0, 0);
            acc2 = __builtin_amdgcn_mfma_f32_16x16x32_bf16(a[kk], bfrag[2][kk], acc2, 0, 0, 0);
            acc3 = __builtin_amdgcn_mfma_f32_16x16x32_bf16(a[kk], bfrag[3][kk], acc3, 0, 0, 0);
        }

#pragma unroll
        for (int r = 0; r < 4; r++) {
            float p = fmaxf(acc0[r] + b2v[0], 0.f) * wlv[0]
                    + fmaxf(acc1[r] + b2v[1], 0.f) * wlv[1]
                    + fmaxf(acc2[r] + b2v[2], 0.f) * wlv[2]
                    + fmaxf(acc3[r] + b2v[3], 0.f) * wlv[3];
#pragma unroll
            for (int m = 8; m >= 1; m >>= 1) p += __shfl_xor(p, m);
            if (cc == 0) {
                int node = n0 + sub * 4 + r;
                if (node < N) {
                    int g = batch[node];
                    atomicAdd(&s_sum[g], p);
                    atomicAdd(&s_cnt[g], 1);
                }
            }
        }
    }
    __syncthreads();
    if (t < 64 && s_cnt[t] > 0) {
        atomicAdd(&pool_sum[t], s_sum[t]);
        atomicAdd(&pool_cnt[t], s_cnt[t]);
    }
}

__global__ void final_kernel(const float* __restrict__ pool_sum, const int* __restrict__ pool_cnt,
                             const float* __restrict__ blin, float* __restrict__ out) {
    int g = threadIdx.x;
    if (g < 64) out[g] = pool_sum[g] / fmaxf((float)pool_cnt[g], 1.f) + blin[0];
}

// ---------------- launch ----------------

extern "C" void kernel_launch(void* const* d_in, const int* in_sizes, int n_in,
                              void* d_out, int out_size, void* d_ws, size_t ws_size,
                              hipStream_t stream) {
    const float* x     = (const float*)d_in[0];
    const int*   ei    = (const int*)d_in[1];
    const float* eattr = (const float*)d_in[2];
    const int*   batch = (const int*)d_in[3];
    const float* W1  = (const float*)d_in[4];
    const float* as1 = (const float*)d_in[5];
    const float* ad1 = (const float*)d_in[6];
    const float* We1 = (const float*)d_in[7];
    const float* ae1 = (const float*)d_in[8];
    const float* b1  = (const float*)d_in[9];
    const float* W2  = (const float*)d_in[10];
    const float* as2 = (const float*)d_in[11];
    const float* ad2 = (const float*)d_in[12];
    const float* We2 = (const float*)d_in[13];
    const float* ae2 = (const float*)d_in[14];
    const float* b2  = (const float*)d_in[15];
    const float* Wlin = (const float*)d_in[16];
    const float* blin = (const float*)d_in[17];
    float* out = (float*)d_out;

    int N = in_sizes[0] / 5;
    int E = in_sizes[1] / 2;
    size_t EP = (size_t)E + N;
    const int* src0 = ei;
    const int* dst0 = ei + E;
    int B = (N + 255) / 256;    // node blocks (<=1024)
    int HB = (E + 255) / 256;   // edge blocks

    char* ws = (char*)d_ws;
    size_t off = 0;
    auto alloc = [&](size_t bytes) {
        void* p = ws + off;
        off = (off + bytes + 255) & ~(size_t)255;
        return p;
    };
    // zero region: hist + pool_sum + pool_cnt contiguous -> ONE memset
    unsigned long long* hist = (unsigned long long*)alloc((size_t)N * 8);
    float*  pool_sum = (float*) alloc(64 * 4);
    int*    pool_cnt = (int*)   alloc(64 * 4);
    size_t zero_bytes = off;    // everything above gets zeroed
    int*    row_ptr  = (int*)   alloc((size_t)(N + 1) * 4);
    int*    pos      = (int*)   alloc((size_t)E * 4);
    int2*   col      = (int2*)  alloc(EP * 8);
    int*    block_sum= (int*)   alloc((size_t)1024 * 4);
    int*    block_off= (int*)   alloc((size_t)1024 * 4);
    float*  wp       = (float*) alloc(280 * 4);
    unsigned short* W2b = (unsigned short*)alloc((size_t)128 * 64 * 2);
    float2* al_s1    = (float2*)alloc((size_t)N * 8);
    float2* al_d1    = (float2*)alloc((size_t)N * 8);
    uint4*  xb1      = (uint4*) alloc((size_t)N * 16);
    float2* al_s2    = (float2*)alloc((size_t)N * 8);
    float2* al_d2    = (float2*)alloc((size_t)N * 8);
    u32*    xb2      = (u32*)   alloc((size_t)N * 32 * 4);
    u32*    agg2b    = (u32*)   alloc((size_t)N * 64 * 4);

    hipMemsetAsync(hist, 0, zero_bytes, stream);

    hist_prep_kernel<<<HB + 1, 256, 0, stream>>>(dst0, eattr, hist, pos, E,
                                                 W1, as1, ad1, We1, ae1,
                                                 W2, as2, ad2, We2, ae2, wp, W2b, HB);
    scan1_pre_kernel<<<2 * B, 256, 0, stream>>>(hist, block_sum, N, B, x, wp,
                                                al_s1, al_d1, xb1);
    scan_phase2<<<1, 1024, 0, stream>>>(block_sum, block_off, row_ptr, B, N);
    scan_phase3<<<B, 256, 0, stream>>>(hist, block_off, row_ptr, col, N);
    place_kernel<<<HB, 256, 0, stream>>>(src0, dst0, eattr, row_ptr, pos, col, E);

    int eab8 = (N + 7) / 8;                 // 8 segments per block, 2 nodes/wave

    // layer 1: aggregate raw 5-dim features + FUSED projection + layer-2 logits
    edge_proj_L1<<<eab8, 256, 0, stream>>>(row_ptr, col, al_s1, al_d1, xb1, wp, W1, b1,
                                           al_s2, al_d2, xb2, N);
    // layer 2: aggregate 64-dim feat1 (bf16 out), then MFMA projection + pool
    edge_aggr_L2<<<eab8, 256, 0, stream>>>(row_ptr, col, al_s2, al_d2, xb2, wp, agg2b, N);
    int nstrips = (N + 15) / 16;
    proj2_pool_mfma<<<(nstrips + 3) / 4, 256, 0, stream>>>(agg2b, W2b, b2, Wlin, batch,
                                                           pool_sum, pool_cnt, N);
    final_kernel<<<1, 64, 0, stream>>>(pool_sum, pool_cnt, blin, out);
}